// Round 1
// 11037.803 us; speedup vs baseline: 2.6301x; 2.6301x over previous
//
#include <hip/hip_runtime.h>
#include <hip/hip_bf16.h>
#include <math.h>

using bf16 = __hip_bfloat16;

#define DI static __device__ __forceinline__

constexpr int Bc = 8, Nn = 4096, Gc = 128, Kc = 16, Vc = 64, Mc = 64;
constexpr int Dd = 384, NHh = 8, DHh = 48, FFf = 1536;

typedef __bf16 bf8v __attribute__((ext_vector_type(8)));
typedef float f4v __attribute__((ext_vector_type(4)));

DI float b2f(bf16 h) { return __bfloat162float(h); }
DI __bf16 f2b(float f) { return (__bf16)f; }

// -------------------- dtype autodetect (inputs) --------------------
__global__ __launch_bounds__(256) void detect_kernel(const unsigned int* __restrict__ w, int* __restrict__ flag) {
    __shared__ int sh[256];
    int cnt = 0;
    for (int i = threadIdx.x; i < 16384; i += 256) {
        unsigned int lo = w[i] & 0xffffu;
        int e = (int)((lo >> 7) & 0xffu);
        if (e < 100 || e > 140) cnt++;
    }
    sh[threadIdx.x] = cnt;
    __syncthreads();
    for (int s = 128; s > 0; s >>= 1) {
        if (threadIdx.x < s) sh[threadIdx.x] += sh[threadIdx.x + s];
        __syncthreads();
    }
    if (threadIdx.x == 0) flag[0] = (sh[0] < 2048) ? 1 : 0;
}

DI float ldf(const void* p, size_t i, int isbf) {
    return isbf ? b2f(((const bf16*)p)[i]) : ((const float*)p)[i];
}

__global__ void cvtf_kernel(const void* __restrict__ src, float* __restrict__ dst, size_t n,
                            const int* __restrict__ flag) {
    size_t t = (size_t)blockIdx.x * 256 + threadIdx.x;
    if (t < n) dst[t] = ldf(src, t, flag[0]);
}

// weight transpose+round: src [cnt][K][N] (fp32 or bf16) -> dst [cnt][N][Kpad] bf16, zero-padded K
__global__ void wtr_kernel(const void* __restrict__ src, __bf16* __restrict__ dst,
                           int K, int N, int Kpad, int cnt, const int* __restrict__ flag) {
    size_t t = (size_t)blockIdx.x * 256 + threadIdx.x;
    size_t total = (size_t)cnt * N * Kpad;
    if (t >= total) return;
    int k = (int)(t % Kpad);
    size_t rem = t / Kpad;
    int n = (int)(rem % N);
    int mat = (int)(rem / N);
    float v = (k < K) ? ldf(src, ((size_t)mat * K + k) * N + n, flag[0]) : 0.f;
    dst[t] = f2b(v);
}

__global__ void copyout_kernel(const float* __restrict__ in, float* __restrict__ out, size_t n) {
    size_t t = (size_t)blockIdx.x * 256 + threadIdx.x;
    if (t < n) out[t] = in[t];
}

__global__ void zero_kernel(unsigned char* __restrict__ p, size_t n) {
    size_t t = (size_t)blockIdx.x * 256 + threadIdx.x;
    if (t < n) p[t] = 0;
}

__global__ void add_kernel(const float* __restrict__ a, const float* __restrict__ b,
                           float* __restrict__ o, size_t n) {
    size_t t = (size_t)blockIdx.x * 256 + threadIdx.x;
    if (t < n) o[t] = a[t] + b[t];
}

// -------------------- FPS --------------------
__global__ __launch_bounds__(256) void fps_kernel(const float* __restrict__ pos, float* __restrict__ cent) {
    __shared__ float px[Nn], py[Nn], pz[Nn];
    __shared__ float wv[4];
    __shared__ int wi[4];
    __shared__ int chosen;
    int b = blockIdx.x, tid = threadIdx.x;
    const float* p = pos + (size_t)b * Nn * 3;
    for (int i = tid; i < Nn; i += 256) { px[i] = p[3*i]; py[i] = p[3*i+1]; pz[i] = p[3*i+2]; }
    __syncthreads();
    float cx = px[0], cy = py[0], cz = pz[0];
    if (tid == 0) { float* c0 = cent + (size_t)b * Gc * 3; c0[0] = cx; c0[1] = cy; c0[2] = cz; }
    float mind[16];
#pragma unroll
    for (int j = 0; j < 16; j++) {
        int i = tid + 256 * j;
        float dx = px[i]-cx, dy = py[i]-cy, dz = pz[i]-cz;
        mind[j] = __fadd_rn(__fadd_rn(__fmul_rn(dx,dx), __fmul_rn(dy,dy)), __fmul_rn(dz,dz));
    }
    for (int s = 1; s < Gc; s++) {
        float bv = -1.f; int bi = 0;
#pragma unroll
        for (int j = 0; j < 16; j++) { int i = tid + 256*j; if (mind[j] > bv) { bv = mind[j]; bi = i; } }
        for (int o = 32; o > 0; o >>= 1) {
            float v2 = __shfl_down(bv, o, 64); int i2 = __shfl_down(bi, o, 64);
            if (v2 > bv || (v2 == bv && i2 < bi)) { bv = v2; bi = i2; }
        }
        if ((tid & 63) == 0) { wv[tid >> 6] = bv; wi[tid >> 6] = bi; }
        __syncthreads();
        if (tid == 0) {
            float fv = wv[0]; int fi = wi[0];
            for (int k = 1; k < 4; k++)
                if (wv[k] > fv || (wv[k] == fv && wi[k] < fi)) { fv = wv[k]; fi = wi[k]; }
            chosen = fi;
            float* cs = cent + ((size_t)b * Gc + s) * 3;
            cs[0] = px[fi]; cs[1] = py[fi]; cs[2] = pz[fi];
        }
        __syncthreads();
        int ci = chosen;
        float qx = px[ci], qy = py[ci], qz = pz[ci];
#pragma unroll
        for (int j = 0; j < 16; j++) {
            int i = tid + 256 * j;
            float dx = px[i]-qx, dy = py[i]-qy, dz = pz[i]-qz;
            float d = __fadd_rn(__fadd_rn(__fmul_rn(dx,dx), __fmul_rn(dy,dy)), __fmul_rn(dz,dz));
            if (d < mind[j]) mind[j] = d;
        }
    }
}

// -------------------- brute-force KNN (k=16), tie -> lower index --------------------
__global__ __launch_bounds__(64) void knn16_kernel(const float* __restrict__ q, const float* __restrict__ r,
                                                   int* __restrict__ nidx, int NQ, int NR) {
    __shared__ float dist[4096];
    int blk = blockIdx.x; int b = blk / NQ, qi = blk % NQ;
    int lane = threadIdx.x;
    const float* qp = q + ((size_t)b * NQ + qi) * 3;
    float qx = qp[0], qy = qp[1], qz = qp[2];
    float qq = __fadd_rn(__fadd_rn(__fmul_rn(qx,qx), __fmul_rn(qy,qy)), __fmul_rn(qz,qz));
    const float* rp = r + (size_t)b * NR * 3;
    for (int i = lane; i < NR; i += 64) {
        float rx = rp[3*i], ry = rp[3*i+1], rz = rp[3*i+2];
        float rr = __fadd_rn(__fadd_rn(__fmul_rn(rx,rx), __fmul_rn(ry,ry)), __fmul_rn(rz,rz));
        float dot = __fadd_rn(__fadd_rn(__fmul_rn(qx,rx), __fmul_rn(qy,ry)), __fmul_rn(qz,rz));
        dist[i] = __fadd_rn(__fadd_rn(qq, rr), -2.f * dot);
    }
    __syncthreads();
    int* out = nidx + ((size_t)b * NQ + qi) * Kc;
    for (int sel = 0; sel < Kc; ++sel) {
        float bv = INFINITY; int bi = 0;
        bool has = false;
        for (int i = lane; i < NR; i += 64) {
            float v = dist[i];
            if (!has || v < bv) { bv = v; bi = i; has = true; }
        }
        for (int o = 32; o > 0; o >>= 1) {
            float v2 = __shfl_xor(bv, o, 64); int i2 = __shfl_xor(bi, o, 64);
            if (v2 < bv || (v2 == bv && i2 < bi)) { bv = v2; bi = i2; }
        }
        if (lane == 0) { out[sel] = bi; dist[bi] = INFINITY; }
        __syncthreads();
    }
}

// -------------------- top-3 centers + interp weights --------------------
__global__ __launch_bounds__(64) void knn3_kernel(const float* __restrict__ pos, const float* __restrict__ cent,
                                                  int* __restrict__ idx3, float* __restrict__ w3) {
    int bn = blockIdx.x; int b = bn / Nn;
    int lane = threadIdx.x;
    const float* p = pos + (size_t)bn * 3;
    float px = p[0], py = p[1], pz = p[2];
    float pp = __fadd_rn(__fadd_rn(__fmul_rn(px,px), __fmul_rn(py,py)), __fmul_rn(pz,pz));
    float dv[2]; int di[2];
#pragma unroll
    for (int c = 0; c < 2; c++) {
        int g = lane + 64 * c;
        const float* cp = cent + ((size_t)b * Gc + g) * 3;
        float cx = cp[0], cy = cp[1], cz = cp[2];
        float cc = __fadd_rn(__fadd_rn(__fmul_rn(cx,cx), __fmul_rn(cy,cy)), __fmul_rn(cz,cz));
        float dot = __fadd_rn(__fadd_rn(__fmul_rn(px,cx), __fmul_rn(py,cy)), __fmul_rn(pz,cz));
        dv[c] = __fadd_rn(__fadd_rn(pp, cc), -2.f * dot);
        di[c] = g;
    }
    float od[3]; int oi[3];
#pragma unroll
    for (int r = 0; r < 3; r++) {
        float bv; int bi;
        if (dv[1] < dv[0]) { bv = dv[1]; bi = di[1]; } else { bv = dv[0]; bi = di[0]; }
        for (int o = 32; o > 0; o >>= 1) {
            float v2 = __shfl_xor(bv, o, 64); int i2 = __shfl_xor(bi, o, 64);
            if (v2 < bv || (v2 == bv && i2 < bi)) { bv = v2; bi = i2; }
        }
        od[r] = bv; oi[r] = bi;
        if (di[0] == bi) dv[0] = INFINITY;
        if (di[1] == bi) dv[1] = INFINITY;
    }
    if (lane == 0) {
        float w[3], s = 0.f;
        for (int r = 0; r < 3; r++) { w[r] = 1.f / (fmaxf(od[r], 0.f) + 1e-8f); s += w[r]; }
        for (int r = 0; r < 3; r++) { idx3[(size_t)bn*3 + r] = oi[r]; w3[(size_t)bn*3 + r] = w[r] / s; }
    }
}

// interp for rows [r0, r0+CH): out local (CH,448) bf16, cols 387..447 zero
__global__ void interp_kernel(const float* __restrict__ feats, const float* __restrict__ pos,
                              const int* __restrict__ idx3, const float* __restrict__ w3,
                              __bf16* __restrict__ x448, int r0, int CH) {
    size_t t = (size_t)blockIdx.x * 256 + threadIdx.x;
    size_t total = (size_t)CH * 448;
    if (t >= total) return;
    int c = (int)(t % 448); size_t i = t / 448;
    size_t r = (size_t)r0 + i; int b = (int)(r / Nn);
    float o = 0.f;
    if (c < Dd) {
        for (int k = 0; k < 3; k++)
            o += w3[r*3 + k] * feats[((size_t)b * Gc + idx3[r*3 + k]) * Dd + c];
    } else if (c < 387) {
        o = pos[r*3 + (c - Dd)];
    }
    x448[t] = f2b(o);
}

// -------------------- tokenize helpers --------------------
// rel: [Bc*Gc*Kc][64] bf16, cols 3..63 zero (padded K for GEMM)
__global__ void rel_kernel(const float* __restrict__ pos, const float* __restrict__ cent,
                           const int* __restrict__ nidx, __bf16* __restrict__ rel) {
    int t = blockIdx.x * 256 + threadIdx.x;
    if (t >= Bc * Gc * Kc * 64) return;
    int c = t & 63; int row = t >> 6;
    float v = 0.f;
    if (c < 3) {
        int g = (row / Kc) % Gc; int b = row / (Kc * Gc);
        int pi = nidx[row];
        v = pos[((size_t)b * Nn + pi) * 3 + c] - cent[((size_t)b * Gc + g) * 3 + c];
    }
    rel[t] = f2b(v);
}

__global__ void maxk_f32_kernel(const float* __restrict__ in, float* __restrict__ out, int BG, int C) {
    int t = blockIdx.x * 256 + threadIdx.x;
    if (t >= BG * C) return;
    int c = t % C; int bg = t / C;
    const float* p = in + (size_t)bg * Kc * C + c;
    float m = -INFINITY;
    for (int k = 0; k < Kc; k++) m = fmaxf(m, p[(size_t)k * C]);
    out[t] = m;
}

__global__ void maxk_bf_kernel(const __bf16* __restrict__ in, __bf16* __restrict__ out, int BG, int C) {
    int t = blockIdx.x * 256 + threadIdx.x;
    if (t >= BG * C) return;
    int c = t % C; int bg = t / C;
    const __bf16* p = in + (size_t)bg * Kc * C + c;
    float m = -INFINITY;
    for (int k = 0; k < Kc; k++) m = fmaxf(m, (float)p[(size_t)k * C]);
    out[t] = f2b(m);
}

__global__ void concat_gf_kernel(const __bf16* __restrict__ g, const __bf16* __restrict__ f,
                                 __bf16* __restrict__ cat, int BG) {
    size_t t = (size_t)blockIdx.x * 256 + threadIdx.x;
    size_t total = (size_t)BG * Kc * 512;
    if (t >= total) return;
    int c = (int)(t % 512); size_t bgk = t / 512; size_t bg = bgk / Kc;
    cat[t] = (c < 256) ? g[bg * 256 + c] : f[bgk * 256 + (c - 256)];
}

// -------------------- gather / masks --------------------
__global__ void gather_rows_kernel(const float* __restrict__ in, const int* __restrict__ idx,
                                   float* __restrict__ out, int Ni, int C, int Sin) {
    size_t t = (size_t)blockIdx.x * 256 + threadIdx.x;
    size_t total = (size_t)Bc * Ni * C;
    if (t >= total) return;
    int c = (int)(t % C); size_t bi = t / C; int i = (int)(bi % Ni); int b = (int)(bi / Ni);
    int r = idx[(size_t)b * Ni + i];
    out[t] = in[((size_t)b * Sin + r) * C + c];
}

__global__ void scatter_mask_kernel(const int* __restrict__ nidx, unsigned char* __restrict__ mask,
                                    int Q, int S) {
    int t = blockIdx.x * 256 + threadIdx.x;
    if (t >= Bc * Q * Kc) return;
    int q = (t / Kc) % Q; int b = t / (Kc * Q);
    mask[((size_t)b * Q + q) * S + nidx[t]] = 1;
}

// -------------------- positional encoding (dst = base + pe) --------------------
__global__ void pe_kernel(float* __restrict__ dst, const float* __restrict__ base,
                          const float* __restrict__ xyz, size_t total) {
    size_t t = (size_t)blockIdx.x * 256 + threadIdx.x;
    if (t >= total) return;
    int d = (int)(t % Dd); size_t bs = t / Dd;
    int c = d >> 7;
    int i = d & 127;
    int j = i >> 1;
    float inv = expf(-0.1439115683121279f * (float)j);  // 10000^(-j/64)
    float val = xyz[bs * 3 + c] * inv;
    float pe = (i & 1) ? cosf(val) : sinf(val);
    dst[t] = (base ? base[t] : 0.f) + pe;
}

// -------------------- LayerNorm (no affine), row=384, bf16 out --------------------
__global__ __launch_bounds__(256) void ln_kernel(const float* __restrict__ X, __bf16* __restrict__ Y, int R) {
    int lane = threadIdx.x & 63;
    int row = blockIdx.x * 4 + (threadIdx.x >> 6);
    if (row >= R) return;
    const float* x = X + (size_t)row * Dd;
    float v[6]; float s = 0.f;
#pragma unroll
    for (int j = 0; j < 6; j++) { v[j] = x[lane + 64*j]; s += v[j]; }
#pragma unroll
    for (int o = 32; o > 0; o >>= 1) s += __shfl_xor(s, o, 64);
    float m = s * (1.f / Dd);
    float s2 = 0.f;
#pragma unroll
    for (int j = 0; j < 6; j++) { float d = v[j] - m; s2 += d * d; }
#pragma unroll
    for (int o = 32; o > 0; o >>= 1) s2 += __shfl_xor(s2, o, 64);
    float inv = rsqrtf(s2 * (1.f / Dd) + 1e-5f);
    __bf16* y = Y + (size_t)row * Dd;
#pragma unroll
    for (int j = 0; j < 6; j++) y[lane + 64*j] = f2b((v[j] - m) * inv);
}

// -------------------- MFMA bf16 GEMM, bf16 A [M][K] x bf16 Wt [N][K] --------------------
// Requires M%64==0, N%64==0, K%64==0 (host guarantees via padding). 64x64 tile, 4 waves,
// BK=64 (2 MFMA k-substeps per stage). Vectorized 16B register staging into padded LDS.
// Fused bias(f32)/relu/residual(f32); output fp32 or bf16.
__global__ __launch_bounds__(256) void gemm_kernel(const __bf16* __restrict__ A, const __bf16* __restrict__ Wt,
                                                   const float* __restrict__ bias,
                                                   const float* __restrict__ res, void* __restrict__ Cv,
                                                   int M, int Ncols, int Kk, int relu, int obf) {
    __shared__ __bf16 As[64][72];
    __shared__ __bf16 Bs[64][72];
    const int tid = threadIdx.x;
    const int row0 = blockIdx.y * 64, col0 = blockIdx.x * 64;
    const int w = tid >> 6, lane = tid & 63, m = lane & 15, q = lane >> 4;
    const int srow = tid >> 2, sk = (tid & 3) * 16;
    const __bf16* ap = A + (size_t)(row0 + srow) * Kk + sk;
    const __bf16* wp = Wt + (size_t)(col0 + srow) * Kk + sk;

    f4v acc[4];
#pragma unroll
    for (int r = 0; r < 4; r++) acc[r] = (f4v){0.f, 0.f, 0.f, 0.f};

    for (int k0 = 0; k0 < Kk; k0 += 64) {
        *reinterpret_cast<uint4*>(&As[srow][sk])     = *reinterpret_cast<const uint4*>(ap + k0);
        *reinterpret_cast<uint4*>(&As[srow][sk + 8]) = *reinterpret_cast<const uint4*>(ap + k0 + 8);
        *reinterpret_cast<uint4*>(&Bs[srow][sk])     = *reinterpret_cast<const uint4*>(wp + k0);
        *reinterpret_cast<uint4*>(&Bs[srow][sk + 8]) = *reinterpret_cast<const uint4*>(wp + k0 + 8);
        __syncthreads();
#pragma unroll
        for (int kk = 0; kk < 2; kk++) {
            bf8v bfrag = *reinterpret_cast<bf8v*>(&Bs[w * 16 + m][kk * 32 + q * 8]);
#pragma unroll
            for (int r = 0; r < 4; r++) {
                bf8v afrag = *reinterpret_cast<bf8v*>(&As[r * 16 + m][kk * 32 + q * 8]);
                acc[r] = __builtin_amdgcn_mfma_f32_16x16x32_bf16(afrag, bfrag, acc[r], 0, 0, 0);
            }
        }
        __syncthreads();
    }
    const int gn = col0 + w * 16 + m;
    float bv = bias ? bias[gn] : 0.f;
#pragma unroll
    for (int r = 0; r < 4; r++) {
#pragma unroll
        for (int j = 0; j < 4; j++) {
            int gm = row0 + r * 16 + q * 4 + j;
            float v = acc[r][j] + bv;
            if (relu) v = fmaxf(v, 0.f);
            if (res) v += res[(size_t)gm * Ncols + gn];
            if (obf) ((__bf16*)Cv)[(size_t)gm * Ncols + gn] = f2b(v);
            else     ((float*)Cv)[(size_t)gm * Ncols + gn] = v;
        }
    }
}

// -------------------- fused attention: one wave per (bq,h,qi), bf16 out --------------------
__global__ __launch_bounds__(64) void attn_kernel(const float* __restrict__ Q, const float* __restrict__ Kb,
                                                  const float* __restrict__ Vb,
                                                  const unsigned char* __restrict__ mask,
                                                  __bf16* __restrict__ O, int Sq, int Sk, int b0) {
    int qi = blockIdx.x, h = blockIdx.y, bq = blockIdx.z;
    int bk = bq + b0;
    int lane = threadIdx.x;
    __shared__ float qv[DHh];
    __shared__ float pv[128];
    const size_t qrow = (size_t)bq * Sq + qi;
    if (lane < DHh) qv[lane] = Q[qrow * Dd + h * DHh + lane];
    __syncthreads();
    const float scale = 0.14433756729740643f;  // 1/sqrt(48)
    float lv[2] = {-INFINITY, -INFINITY};
#pragma unroll
    for (int c = 0; c < 2; c++) {
        int s = lane + 64 * c;
        if (s < Sk) {
            const float* kr = Kb + ((size_t)bk * Sk + s) * Dd + h * DHh;
            float d = 0.f;
#pragma unroll
            for (int t = 0; t < DHh; t++) d += qv[t] * kr[t];
            d *= scale;
            if (mask && !mask[qrow * Sk + s]) d = -1e9f;
            lv[c] = d;
        }
    }
    float mx = fmaxf(lv[0], lv[1]);
    for (int o = 32; o > 0; o >>= 1) mx = fmaxf(mx, __shfl_xor(mx, o, 64));
    float sum = 0.f;
#pragma unroll
    for (int c = 0; c < 2; c++) {
        int s = lane + 64 * c;
        if (s < Sk) { float e = expf(lv[c] - mx); pv[s] = e; sum += e; }
    }
    for (int o = 32; o > 0; o >>= 1) sum += __shfl_xor(sum, o, 64);
    float inv = 1.f / sum;
    __syncthreads();
    if (lane < DHh) {
        float acc = 0.f;
        const float* vb = Vb + (size_t)bk * Sk * Dd + h * DHh + lane;
        for (int s = 0; s < Sk; s++) acc += pv[s] * vb[(size_t)s * Dd];
        O[qrow * Dd + h * DHh + lane] = f2b(acc * inv);
    }
}

// -------------------- decoder q init --------------------
__global__ void dec_init_kernel(const float* __restrict__ mtok, const float* __restrict__ vout,
                                const float* __restrict__ cpe, const int* __restrict__ mski,
                                const int* __restrict__ visi, float* __restrict__ x) {
    size_t t = (size_t)blockIdx.x * 256 + threadIdx.x;
    size_t total = (size_t)Bc * Gc * Dd;
    if (t >= total) return;
    int d = (int)(t % Dd); size_t bi = t / Dd; int i = (int)(bi % Gc); int b = (int)(bi / Gc);
    float base; int ci;
    if (i < Mc) { base = mtok[d]; ci = mski[b * Mc + i]; }
    else        { base = vout[((size_t)b * Vc + (i - Mc)) * Dd + d]; ci = visi[b * Vc + (i - Mc)]; }
    x[t] = base + cpe[((size_t)b * Gc + ci) * Dd + d];
}

// -------------------- smooth-L1 partial reduce --------------------
__global__ __launch_bounds__(256) void sl1_kernel(const float* __restrict__ tgt, const float* __restrict__ dec,
                                                  float* __restrict__ acc, int slot) {
    __shared__ float sh[256];
    size_t t = (size_t)blockIdx.x * 256 + threadIdx.x;
    const size_t total = (size_t)Bc * Mc * Dd;
    float v = 0.f;
    if (t < total) {
        int d = (int)(t % Dd); size_t rem = t / Dd; int i = (int)(rem % Mc); int b = (int)(rem / Mc);
        float p = dec[((size_t)b * Gc + i) * Dd + d];
        float a = fabsf(p - tgt[t]);
        v = (a < 2.f) ? 0.25f * a * a : (a - 1.f);
    }
    sh[threadIdx.x] = v;
    __syncthreads();
    for (int s = 128; s > 0; s >>= 1) {
        if (threadIdx.x < s) sh[threadIdx.x] += sh[threadIdx.x + s];
        __syncthreads();
    }
    if (threadIdx.x == 0) atomicAdd(&acc[slot], sh[0]);
}

__global__ void mae_finalize_kernel(const float* __restrict__ acc, float* __restrict__ out) {
    const float inv = 1.f / (float)(Bc * Mc * Dd);
    *out = 0.5f * (acc[0] * inv) + 0.5f * (acc[1] * inv);
}

// ==================== host orchestration ====================
extern "C" void kernel_launch(void* const* d_in, const int* in_sizes, int n_in,
                              void* d_out, int out_size, void* d_ws, size_t ws_size,
                              hipStream_t stream) {
    (void)in_sizes; (void)n_in; (void)out_size;
    const void* pos_src = d_in[0];
    const void* pos_tgt = d_in[1];
    const int* vis_s = (const int*)d_in[2];
    const int* msk_s = (const int*)d_in[3];
    const int* vis_t = (const int*)d_in[4];
    const int* msk_t = (const int*)d_in[5];
    const void *tw1 = d_in[6], *tb1 = d_in[7], *tw2 = d_in[8], *tb2 = d_in[9];
    const void *tw3 = d_in[10], *tb3 = d_in[11], *tw4 = d_in[12], *tb4 = d_in[13];
    const void *mtok = d_in[14];
    const void *cxw = d_in[15], *cff1 = d_in[16], *cff2 = d_in[17];
    const void *esa = d_in[18], *eca = d_in[19], *eff1 = d_in[20], *eff2 = d_in[21];
    const void *dca = d_in[22], *dff1 = d_in[23], *dff2 = d_in[24];
    const void *uw1 = d_in[25], *ub1 = d_in[26], *uw2 = d_in[27], *ub2 = d_in[28];
    float* out = (float*)d_out;                      // fp32 output
    char* ws = (char*)d_ws;

    const size_t DD = (size_t)Dd * Dd;
    const size_t DF = (size_t)Dd * FFf;

    // ---- bf16 transposed weight arena (element offsets) ----
    size_t wo = 0;
    auto walloc = [&](size_t e) -> size_t { size_t r = wo; wo += e; return r; };
    const size_t wt_t1 = walloc((size_t)128 * 64);          // [128][64]   (K=3 padded)
    const size_t wt_t2 = walloc((size_t)256 * 128);
    const size_t wt_t3 = walloc((size_t)512 * 512);
    const size_t wt_t4 = walloc((size_t)384 * 512);
    const size_t wt_cx = walloc((size_t)8 * DD);
    const size_t wt_cf1 = walloc(DF);                       // [1536][384]
    const size_t wt_cf2 = walloc(DF);                       // [384][1536]
    const size_t wt_es = walloc((size_t)16 * DD);
    const size_t wt_ec = walloc((size_t)16 * DD);
    const size_t wt_ef1 = walloc((size_t)4 * DF);
    const size_t wt_ef2 = walloc((size_t)4 * DF);
    const size_t wt_dc = walloc((size_t)8 * DD);
    const size_t wt_df1 = walloc((size_t)2 * DF);
    const size_t wt_df2 = walloc((size_t)2 * DF);
    const size_t wt_u1 = walloc((size_t)384 * 448);         // [384][448] (K=387 padded)
    const size_t wt_u2 = walloc((size_t)384 * 384);

    // ---- persistent workspace layout ----
    size_t o = 0;
    auto alloc = [&](size_t bytes) -> size_t { size_t r = o; o += (bytes + 255) & ~(size_t)255; return r; };
    const size_t flagO = alloc(256);
    const size_t wtO = alloc(wo * 2);                       // bf16 weights
    const size_t bsO = alloc(2048 * 4);                     // fp32 biases
    const size_t mtokO = alloc(Dd * 4);
    const size_t posf_s = alloc((size_t)Bc*Nn*3*4), posf_t = alloc((size_t)Bc*Nn*3*4);
    const size_t cent_s = alloc((size_t)Bc*Gc*3*4), cent_t = alloc((size_t)Bc*Gc*3*4);
    const size_t cpe_s = alloc((size_t)Bc*Gc*Dd*4), cpe_t = alloc((size_t)Bc*Gc*Dd*4);
    const size_t tok_s = alloc((size_t)Bc*Gc*Dd*4), tok_t = alloc((size_t)Bc*Gc*Dd*4);
    const size_t vtok_s = alloc((size_t)Bc*Vc*Dd*4), vtok_t = alloc((size_t)Bc*Vc*Dd*4);
    const size_t lnS = alloc((size_t)Bc*Gc*Dd*4), lnT = alloc((size_t)Bc*Gc*Dd*4);
    const size_t qb = alloc((size_t)Bc*Gc*Dd*4), kb = alloc((size_t)Bc*Gc*Dd*4);
    const size_t vb = alloc((size_t)Bc*Gc*Dd*4), cx = alloc((size_t)Bc*Gc*Dd*4);
    const size_t decx_s = alloc((size_t)Bc*Gc*Dd*4), decx_t = alloc((size_t)Bc*Gc*Dd*4);
    const size_t memb = alloc((size_t)Bc*Gc*Dd*4), lnm = alloc((size_t)Bc*Gc*Dd*4);
    const size_t kl0 = alloc((size_t)Bc*Gc*Dd*4), vl0 = alloc((size_t)Bc*Gc*Dd*4);
    const size_t kl1 = alloc((size_t)Bc*Gc*Dd*4), vl1 = alloc((size_t)Bc*Gc*Dd*4);
    const size_t relb = alloc((size_t)Bc*Gc*Kc*64*2);       // bf16, K padded to 64
    const size_t tbs = alloc((size_t)Bc*Mc*Dd*4), tbt = alloc((size_t)Bc*Mc*Dd*4);
    const size_t mfull_s = alloc((size_t)Bc*Gc*Gc), mfull_t = alloc((size_t)Bc*Gc*Gc);
    const size_t mvis_s = alloc((size_t)Bc*Vc*Vc), mvis_t = alloc((size_t)Bc*Vc*Vc);
    const size_t nidxb = alloc((size_t)Bc*Gc*Kc*4);
    const size_t idx3b = alloc((size_t)Bc*Nn*3*4), w3b = alloc((size_t)Bc*Nn*3*4);
    const size_t vis3_s = alloc((size_t)Bc*Vc*3*4), vis3_t = alloc((size_t)Bc*Vc*3*4);
    const size_t accb = alloc(64);

    // ---- chunk size selection based on ws_size ----
    // per-row bytes: Acb 896 (bf16x448) + Xc 1536 + Lc 1536 + T1 2048 + T2 2048 + Hh 6144 = 14208
    int CH = 256;
    {
        const int cands[5] = {4096, 2048, 1024, 512, 256};
        for (int ci = 0; ci < 5; ci++) {
            size_t need = o + (size_t)cands[ci] * 14208 + 8 * 256;
            if (need <= ws_size) { CH = cands[ci]; break; }
        }
    }
    const size_t AcbO = alloc((size_t)CH*448*2);
    const size_t XcO  = alloc((size_t)CH*384*4);
    const size_t LcO  = alloc((size_t)CH*384*4);
    const size_t T1O  = alloc((size_t)CH*512*4);
    const size_t T2O  = alloc((size_t)CH*512*4);
    const size_t HhO  = alloc((size_t)CH*FFf*4);

    auto F = [&](size_t off) -> float* { return (float*)(ws + off); };
    auto I = [&](size_t off) -> int* { return (int*)(ws + off); };
    auto U = [&](size_t off) -> unsigned char* { return (unsigned char*)(ws + off); };
    auto Bf = [&](size_t off) -> __bf16* { return (__bf16*)(ws + off); };
    auto ew = [](size_t n) -> dim3 { return dim3((unsigned)((n + 255) / 256)); };
    const int* flag = I(flagO);
    __bf16* WT = Bf(wtO);
    float* BF = F(bsO);
    // bias fp32 arena offsets
    const int b_t1 = 0, b_t2 = 128, b_t3 = 384, b_t4 = 896, b_u1 = 1280, b_u2 = 1664;

    auto gemm = [&](const __bf16* A, const __bf16* W, const float* bias, const float* res, void* C,
                    int M, int Ncol, int Kk, int relu, int obf) {
        dim3 g((unsigned)(Ncol / 64), (unsigned)(M / 64));
        gemm_kernel<<<g, 256, 0, stream>>>(A, W, bias, res, C, M, Ncol, Kk, relu, obf);
    };
    auto ln = [&](const float* X, __bf16* Y, int R) {
        ln_kernel<<<dim3((R + 3) / 4), 256, 0, stream>>>(X, Y, R);
    };
    auto attn = [&](const float* Qp, const float* Kp, const float* Vp, const unsigned char* mask,
                    __bf16* Op, int Sq, int Sk, int nb, int b0) {
        attn_kernel<<<dim3(Sq, NHh, nb), 64, 0, stream>>>(Qp, Kp, Vp, mask, Op, Sq, Sk, b0);
    };
    float *qbuf = F(qb), *kbuf = F(kb), *vbuf = F(vb);
    __bf16* ctxb = Bf(cx);
    auto attn_block = [&](float* x, const __bf16* qln, const __bf16* kln, const __bf16* w4,
                          const unsigned char* mask, int S) {
        gemm(qln, w4,          nullptr, nullptr, qbuf, Bc*S, Dd, Dd, 0, 0);
        gemm(kln, w4 + DD,     nullptr, nullptr, kbuf, Bc*S, Dd, Dd, 0, 0);
        gemm(kln, w4 + 2*DD,   nullptr, nullptr, vbuf, Bc*S, Dd, Dd, 0, 0);
        attn(qbuf, kbuf, vbuf, mask, ctxb, S, S, Bc, 0);
        gemm(ctxb, w4 + 3*DD,  nullptr, x, x, Bc*S, Dd, Dd, 0, 0);
    };
    auto ffn = [&](float* x, const __bf16* w1t, const __bf16* w2t, int R) {
        ln(x, Bf(lnS), R);
        for (int r0 = 0; r0 < R; r0 += CH) {
            int rc = (R - r0 < CH) ? (R - r0) : CH;
            gemm(Bf(lnS) + (size_t)r0*Dd, w1t, nullptr, nullptr, Bf(HhO), rc, FFf, Dd, 1, 1);
            gemm(Bf(HhO), w2t, nullptr, x + (size_t)r0*Dd, x + (size_t)r0*Dd, rc, Dd, FFf, 0, 0);
        }
    };
    auto cross_enc = [&](float* xs, float* xt, const unsigned char* ms, const unsigned char* mt, int S) {
        ln(xs, Bf(lnS), Bc*S); attn_block(xs, Bf(lnS), Bf(lnS), WT + wt_cx, ms, S);
        ln(xt, Bf(lnT), Bc*S); attn_block(xt, Bf(lnT), Bf(lnT), WT + wt_cx, mt, S);
        ln(xs, Bf(lnS), Bc*S); ln(xt, Bf(lnT), Bc*S);
        attn_block(xs, Bf(lnS), Bf(lnT), WT + wt_cx + 4*DD, nullptr, S);
        attn_block(xt, Bf(lnT), Bf(lnS), WT + wt_cx + 4*DD, nullptr, S);
        ffn(xs, WT + wt_cf1, WT + wt_cf2, Bc*S);
        ffn(xt, WT + wt_cf1, WT + wt_cf2, Bc*S);
    };
    auto decoder4 = [&](float* x, const float* memin, const float* cpem) {
        add_kernel<<<ew((size_t)Bc*Gc*Dd), 256, 0, stream>>>(memin, cpem, F(memb), (size_t)Bc*Gc*Dd);
        ln(F(memb), Bf(lnm), Bc*Gc);
        for (int l = 0; l < 4; l++) {
            ln(x, Bf(lnT), Bc*Gc);
            attn_block(x, Bf(lnT), Bf(lnT), WT + wt_es + (size_t)l*4*DD, nullptr, Gc);
            ln(x, Bf(lnT), Bc*Gc);
            attn_block(x, Bf(lnT), Bf(lnm), WT + wt_ec + (size_t)l*4*DD, nullptr, Gc);
            ffn(x, WT + wt_ef1 + (size_t)l*DF, WT + wt_ef2 + (size_t)l*DF, Bc*Gc);
        }
    };
    auto tokenize = [&](const float* posf, float* cent, float* tok) {
        fps_kernel<<<dim3(Bc), 256, 0, stream>>>(posf, cent);
        knn16_kernel<<<dim3(Bc*Gc), 64, 0, stream>>>(cent, posf, I(nidxb), Gc, Nn);
        rel_kernel<<<ew((size_t)Bc*Gc*Kc*64), 256, 0, stream>>>(posf, cent, I(nidxb), Bf(relb));
        const int GC = CH / Kc;             // groups per chunk
        __bf16* Hh0 = Bf(HhO);                        // cat (RC x 512) bf16
        __bf16* Hh1 = Bf(HhO) + (size_t)CH * 512;     // hb  (RC x 512) bf16
        for (int g0 = 0; g0 < Bc*Gc; g0 += GC) {
            const int RC = GC * Kc;
            gemm(Bf(relb) + (size_t)g0*Kc*64, WT + wt_t1, BF + b_t1, nullptr, Bf(T1O), RC, 128, 64, 1, 1);
            gemm(Bf(T1O), WT + wt_t2, BF + b_t2, nullptr, Bf(T2O), RC, 256, 128, 0, 1);
            maxk_bf_kernel<<<ew((size_t)GC*256), 256, 0, stream>>>(Bf(T2O), Bf(XcO), GC, 256);
            concat_gf_kernel<<<ew((size_t)RC*512), 256, 0, stream>>>(Bf(XcO), Bf(T2O), Hh0, GC);
            gemm(Hh0, WT + wt_t3, BF + b_t3, nullptr, Hh1, RC, 512, 512, 1, 1);
            gemm(Hh1, WT + wt_t4, BF + b_t4, nullptr, F(XcO), RC, Dd, 512, 0, 0);
            maxk_f32_kernel<<<ew((size_t)GC*Dd), 256, 0, stream>>>(F(XcO), tok + (size_t)g0*Dd, GC, Dd);
        }
    };
    auto dense_side = [&](const float* posf, const float* cent, const float* feats,
                          const float* cpe_side, float* outp) {
        knn3_kernel<<<dim3(Bc*Nn), 64, 0, stream>>>(posf, cent, I(idx3b), F(w3b));
        add_kernel<<<ew((size_t)Bc*Gc*Dd), 256, 0, stream>>>(feats, cpe_side, F(memb), (size_t)Bc*Gc*Dd);
        ln(F(memb), Bf(lnm), Bc*Gc);
        gemm(Bf(lnm), WT + wt_dc + 1*DD, nullptr, nullptr, F(kl0), Bc*Gc, Dd, Dd, 0, 0);
        gemm(Bf(lnm), WT + wt_dc + 2*DD, nullptr, nullptr, F(vl0), Bc*Gc, Dd, Dd, 0, 0);
        gemm(Bf(lnm), WT + wt_dc + 5*DD, nullptr, nullptr, F(kl1), Bc*Gc, Dd, Dd, 0, 0);
        gemm(Bf(lnm), WT + wt_dc + 6*DD, nullptr, nullptr, F(vl1), Bc*Gc, Dd, Dd, 0, 0);
        const float* kvo[2][2] = {{F(kl0), F(vl0)}, {F(kl1), F(vl1)}};
        for (int b = 0; b < Bc; b++) {
            for (int c0 = 0; c0 < Nn; c0 += CH) {
                const int r0 = b * Nn + c0;
                interp_kernel<<<ew((size_t)CH*448), 256, 0, stream>>>(feats, posf, I(idx3b), F(w3b), Bf(AcbO), r0, CH);
                gemm(Bf(AcbO), WT + wt_u1, BF + b_u1, nullptr, Bf(LcO), CH, Dd, 448, 1, 1);
                gemm(Bf(LcO), WT + wt_u2, BF + b_u2, nullptr, F(T1O), CH, Dd, Dd, 1, 0);
                pe_kernel<<<ew((size_t)CH*Dd), 256, 0, stream>>>(F(XcO), F(T1O), posf + (size_t)r0*3, (size_t)CH*Dd);
                for (int l = 0; l < 2; l++) {
                    ln(F(XcO), Bf(LcO), CH);
                    gemm(Bf(LcO), WT + wt_dc + (size_t)l*4*DD, nullptr, nullptr, F(T1O), CH, Dd, Dd, 0, 0);
                    attn(F(T1O), kvo[l][0], kvo[l][1], nullptr, Bf(T2O), CH, Gc, 1, b);
                    gemm(Bf(T2O), WT + wt_dc + (size_t)l*4*DD + 3*DD, nullptr, F(XcO), F(XcO), CH, Dd, Dd, 0, 0);
                    ln(F(XcO), Bf(LcO), CH);
                    gemm(Bf(LcO), WT + wt_df1 + (size_t)l*DF, nullptr, nullptr, Bf(HhO), CH, FFf, Dd, 1, 1);
                    gemm(Bf(HhO), WT + wt_df2 + (size_t)l*DF, nullptr, F(XcO), F(XcO), CH, Dd, FFf, 0, 0);
                }
                copyout_kernel<<<ew((size_t)CH*Dd), 256, 0, stream>>>(F(XcO), outp + (size_t)r0*Dd, (size_t)CH*Dd);
            }
        }
    };

    // ---- pipeline ----
    detect_kernel<<<dim3(1), 256, 0, stream>>>((const unsigned int*)pos_src, I(flagO));
    cvtf_kernel<<<ew((size_t)Bc*Nn*3), 256, 0, stream>>>(pos_src, F(posf_s), (size_t)Bc*Nn*3, flag);
    cvtf_kernel<<<ew((size_t)Bc*Nn*3), 256, 0, stream>>>(pos_tgt, F(posf_t), (size_t)Bc*Nn*3, flag);
    cvtf_kernel<<<dim3(2), 256, 0, stream>>>(mtok, F(mtokO), (size_t)Dd, flag);

    // weights -> bf16 transposed [N][Kpad]
    auto wtr = [&](const void* src, size_t dstOff, int K, int N, int Kpad, int cnt) {
        wtr_kernel<<<ew((size_t)cnt * N * Kpad), 256, 0, stream>>>(src, WT + dstOff, K, N, Kpad, cnt, flag);
    };
    wtr(tw1, wt_t1, 3, 128, 64, 1);
    wtr(tw2, wt_t2, 128, 256, 128, 1);
    wtr(tw3, wt_t3, 512, 512, 512, 1);
    wtr(tw4, wt_t4, 512, 384, 512, 1);
    wtr(cxw, wt_cx, 384, 384, 384, 8);
    wtr(cff1, wt_cf1, 384, 1536, 384, 1);
    wtr(cff2, wt_cf2, 1536, 384, 1536, 1);
    wtr(esa, wt_es, 384, 384, 384, 16);
    wtr(eca, wt_ec, 384, 384, 384, 16);
    wtr(eff1, wt_ef1, 384, 1536, 384, 4);
    wtr(eff2, wt_ef2, 1536, 384, 1536, 4);
    wtr(dca, wt_dc, 384, 384, 384, 8);
    wtr(dff1, wt_df1, 384, 1536, 384, 2);
    wtr(dff2, wt_df2, 1536, 384, 1536, 2);
    wtr(uw1, wt_u1, 387, 384, 448, 1);
    wtr(uw2, wt_u2, 384, 384, 384, 1);
    // biases -> fp32
    cvtf_kernel<<<ew(128), 256, 0, stream>>>(tb1, BF + b_t1, 128, flag);
    cvtf_kernel<<<ew(256), 256, 0, stream>>>(tb2, BF + b_t2, 256, flag);
    cvtf_kernel<<<ew(512), 256, 0, stream>>>(tb3, BF + b_t3, 512, flag);
    cvtf_kernel<<<ew(384), 256, 0, stream>>>(tb4, BF + b_t4, 384, flag);
    cvtf_kernel<<<ew(384), 256, 0, stream>>>(ub1, BF + b_u1, 384, flag);
    cvtf_kernel<<<ew(384), 256, 0, stream>>>(ub2, BF + b_u2, 384, flag);

    tokenize(F(posf_s), F(cent_s), F(tok_s));
    tokenize(F(posf_t), F(cent_t), F(tok_t));

    pe_kernel<<<ew((size_t)Bc*Gc*Dd), 256, 0, stream>>>(F(cpe_s), nullptr, F(cent_s), (size_t)Bc*Gc*Dd);
    pe_kernel<<<ew((size_t)Bc*Gc*Dd), 256, 0, stream>>>(F(cpe_t), nullptr, F(cent_t), (size_t)Bc*Gc*Dd);

    gather_rows_kernel<<<ew((size_t)Bc*Vc*Dd), 256, 0, stream>>>(F(tok_s), vis_s, F(vtok_s), Vc, Dd, Gc);
    gather_rows_kernel<<<ew((size_t)Bc*Vc*Dd), 256, 0, stream>>>(F(tok_t), vis_t, F(vtok_t), Vc, Dd, Gc);
    gather_rows_kernel<<<ew((size_t)Bc*Vc*3), 256, 0, stream>>>(F(cent_s), vis_s, F(vis3_s), Vc, 3, Gc);
    gather_rows_kernel<<<ew((size_t)Bc*Vc*3), 256, 0, stream>>>(F(cent_t), vis_t, F(vis3_t), Vc, 3, Gc);

    zero_kernel<<<ew((size_t)Bc*Gc*Gc), 256, 0, stream>>>(U(mfull_s), (size_t)Bc*Gc*Gc);
    knn16_kernel<<<dim3(Bc*Gc), 64, 0, stream>>>(F(cent_s), F(cent_s), I(nidxb), Gc, Gc);
    scatter_mask_kernel<<<ew((size_t)Bc*Gc*Kc), 256, 0, stream>>>(I(nidxb), U(mfull_s), Gc, Gc);
    zero_kernel<<<ew((size_t)Bc*Gc*Gc), 256, 0, stream>>>(U(mfull_t), (size_t)Bc*Gc*Gc);
    knn16_kernel<<<dim3(Bc*Gc), 64, 0, stream>>>(F(cent_t), F(cent_t), I(nidxb), Gc, Gc);
    scatter_mask_kernel<<<ew((size_t)Bc*Gc*Kc), 256, 0, stream>>>(I(nidxb), U(mfull_t), Gc, Gc);
    zero_kernel<<<ew((size_t)Bc*Vc*Vc), 256, 0, stream>>>(U(mvis_s), (size_t)Bc*Vc*Vc);
    knn16_kernel<<<dim3(Bc*Vc), 64, 0, stream>>>(F(vis3_s), F(vis3_s), I(nidxb), Vc, Vc);
    scatter_mask_kernel<<<ew((size_t)Bc*Vc*Kc), 256, 0, stream>>>(I(nidxb), U(mvis_s), Vc, Vc);
    zero_kernel<<<ew((size_t)Bc*Vc*Vc), 256, 0, stream>>>(U(mvis_t), (size_t)Bc*Vc*Vc);
    knn16_kernel<<<dim3(Bc*Vc), 64, 0, stream>>>(F(vis3_t), F(vis3_t), I(nidxb), Vc, Vc);
    scatter_mask_kernel<<<ew((size_t)Bc*Vc*Kc), 256, 0, stream>>>(I(nidxb), U(mvis_t), Vc, Vc);

    cross_enc(F(vtok_s), F(vtok_t), U(mvis_s), U(mvis_t), Vc);
    cross_enc(F(tok_s), F(tok_t), U(mfull_s), U(mfull_t), Gc);

    dec_init_kernel<<<ew((size_t)Bc*Gc*Dd), 256, 0, stream>>>(F(mtokO), F(vtok_s), F(cpe_s), msk_s, vis_s, F(decx_s));
    dec_init_kernel<<<ew((size_t)Bc*Gc*Dd), 256, 0, stream>>>(F(mtokO), F(vtok_t), F(cpe_t), msk_t, vis_t, F(decx_t));
    decoder4(F(decx_s), F(tok_t), F(cpe_t));
    decoder4(F(decx_t), F(tok_s), F(cpe_s));

    zero_kernel<<<dim3(1), 256, 0, stream>>>(U(accb), 64);
    gather_rows_kernel<<<ew((size_t)Bc*Mc*Dd), 256, 0, stream>>>(F(tok_s), msk_s, F(tbs), Mc, Dd, Gc);
    gather_rows_kernel<<<ew((size_t)Bc*Mc*Dd), 256, 0, stream>>>(F(tok_t), msk_t, F(tbt), Mc, Dd, Gc);
    sl1_kernel<<<ew((size_t)Bc*Mc*Dd), 256, 0, stream>>>(F(tbs), F(decx_s), F(accb), 0);
    sl1_kernel<<<ew((size_t)Bc*Mc*Dd), 256, 0, stream>>>(F(tbt), F(decx_t), F(accb), 1);

    dense_side(F(posf_s), F(cent_s), F(tok_s), F(cpe_s), out);
    dense_side(F(posf_t), F(cent_t), F(tok_t), F(cpe_t), out + (size_t)Bc*Nn*Dd);

    mae_finalize_kernel<<<dim3(1), 1, 0, stream>>>(F(accb), out + (size_t)2*Bc*Nn*Dd);
}

// Round 2
// 9026.292 us; speedup vs baseline: 3.2162x; 1.2229x over previous
//
#include <hip/hip_runtime.h>
#include <hip/hip_bf16.h>
#include <math.h>

using bf16 = __hip_bfloat16;

#define DI static __device__ __forceinline__

constexpr int Bc = 8, Nn = 4096, Gc = 128, Kc = 16, Vc = 64, Mc = 64;
constexpr int Dd = 384, NHh = 8, DHh = 48, FFf = 1536;

typedef __bf16 bf8v __attribute__((ext_vector_type(8)));
typedef float f4v __attribute__((ext_vector_type(4)));

DI float b2f(bf16 h) { return __bfloat162float(h); }
DI __bf16 f2b(float f) { return (__bf16)f; }

// -------------------- dtype autodetect (inputs) --------------------
__global__ __launch_bounds__(256) void detect_kernel(const unsigned int* __restrict__ w, int* __restrict__ flag) {
    __shared__ int sh[256];
    int cnt = 0;
    for (int i = threadIdx.x; i < 16384; i += 256) {
        unsigned int lo = w[i] & 0xffffu;
        int e = (int)((lo >> 7) & 0xffu);
        if (e < 100 || e > 140) cnt++;
    }
    sh[threadIdx.x] = cnt;
    __syncthreads();
    for (int s = 128; s > 0; s >>= 1) {
        if (threadIdx.x < s) sh[threadIdx.x] += sh[threadIdx.x + s];
        __syncthreads();
    }
    if (threadIdx.x == 0) flag[0] = (sh[0] < 2048) ? 1 : 0;
}

DI float ldf(const void* p, size_t i, int isbf) {
    return isbf ? b2f(((const bf16*)p)[i]) : ((const float*)p)[i];
}

__global__ void cvtf_kernel(const void* __restrict__ src, float* __restrict__ dst, size_t n,
                            const int* __restrict__ flag) {
    size_t t = (size_t)blockIdx.x * 256 + threadIdx.x;
    if (t < n) dst[t] = ldf(src, t, flag[0]);
}

// weight transpose+round: src [cnt][K][N] (fp32 or bf16) -> dst [cnt][N][Kpad] bf16, zero-padded K
__global__ void wtr_kernel(const void* __restrict__ src, __bf16* __restrict__ dst,
                           int K, int N, int Kpad, int cnt, const int* __restrict__ flag) {
    size_t t = (size_t)blockIdx.x * 256 + threadIdx.x;
    size_t total = (size_t)cnt * N * Kpad;
    if (t >= total) return;
    int k = (int)(t % Kpad);
    size_t rem = t / Kpad;
    int n = (int)(rem % N);
    int mat = (int)(rem / N);
    float v = (k < K) ? ldf(src, ((size_t)mat * K + k) * N + n, flag[0]) : 0.f;
    dst[t] = f2b(v);
}

__global__ void copyout_kernel(const float* __restrict__ in, float* __restrict__ out, size_t n) {
    size_t t = (size_t)blockIdx.x * 256 + threadIdx.x;
    if (t < n) out[t] = in[t];
}

__global__ void zero_kernel(unsigned char* __restrict__ p, size_t n) {
    size_t t = (size_t)blockIdx.x * 256 + threadIdx.x;
    if (t < n) p[t] = 0;
}

__global__ void add_kernel(const float* __restrict__ a, const float* __restrict__ b,
                           float* __restrict__ o, size_t n) {
    size_t t = (size_t)blockIdx.x * 256 + threadIdx.x;
    if (t < n) o[t] = a[t] + b[t];
}

// -------------------- FPS (both sides in one dispatch: 16 blocks) --------------------
__global__ __launch_bounds__(256) void fps_kernel(const float* __restrict__ pos_a, const float* __restrict__ pos_b,
                                                  float* __restrict__ cent_a, float* __restrict__ cent_b) {
    __shared__ float px[Nn], py[Nn], pz[Nn];
    __shared__ float wv[4];
    __shared__ int wi[4];
    __shared__ int chosen;
    int side = blockIdx.x >> 3, b = blockIdx.x & 7, tid = threadIdx.x;
    const float* pos = side ? pos_b : pos_a;
    float* cent = side ? cent_b : cent_a;
    const float* p = pos + (size_t)b * Nn * 3;
    for (int i = tid; i < Nn; i += 256) { px[i] = p[3*i]; py[i] = p[3*i+1]; pz[i] = p[3*i+2]; }
    __syncthreads();
    float cx = px[0], cy = py[0], cz = pz[0];
    if (tid == 0) { float* c0 = cent + (size_t)b * Gc * 3; c0[0] = cx; c0[1] = cy; c0[2] = cz; }
    float mind[16];
#pragma unroll
    for (int j = 0; j < 16; j++) {
        int i = tid + 256 * j;
        float dx = px[i]-cx, dy = py[i]-cy, dz = pz[i]-cz;
        mind[j] = __fadd_rn(__fadd_rn(__fmul_rn(dx,dx), __fmul_rn(dy,dy)), __fmul_rn(dz,dz));
    }
    for (int s = 1; s < Gc; s++) {
        float bv = -1.f; int bi = 0;
#pragma unroll
        for (int j = 0; j < 16; j++) { int i = tid + 256*j; if (mind[j] > bv) { bv = mind[j]; bi = i; } }
        for (int o = 32; o > 0; o >>= 1) {
            float v2 = __shfl_down(bv, o, 64); int i2 = __shfl_down(bi, o, 64);
            if (v2 > bv || (v2 == bv && i2 < bi)) { bv = v2; bi = i2; }
        }
        if ((tid & 63) == 0) { wv[tid >> 6] = bv; wi[tid >> 6] = bi; }
        __syncthreads();
        if (tid == 0) {
            float fv = wv[0]; int fi = wi[0];
            for (int k = 1; k < 4; k++)
                if (wv[k] > fv || (wv[k] == fv && wi[k] < fi)) { fv = wv[k]; fi = wi[k]; }
            chosen = fi;
            float* cs = cent + ((size_t)b * Gc + s) * 3;
            cs[0] = px[fi]; cs[1] = py[fi]; cs[2] = pz[fi];
        }
        __syncthreads();
        int ci = chosen;
        float qx = px[ci], qy = py[ci], qz = pz[ci];
#pragma unroll
        for (int j = 0; j < 16; j++) {
            int i = tid + 256 * j;
            float dx = px[i]-qx, dy = py[i]-qy, dz = pz[i]-qz;
            float d = __fadd_rn(__fadd_rn(__fmul_rn(dx,dx), __fmul_rn(dy,dy)), __fmul_rn(dz,dz));
            if (d < mind[j]) mind[j] = d;
        }
    }
}

// -------------------- brute-force KNN (k=16), tie -> lower index --------------------
__global__ __launch_bounds__(64) void knn16_kernel(const float* __restrict__ q, const float* __restrict__ r,
                                                   int* __restrict__ nidx, int NQ, int NR) {
    __shared__ float dist[4096];
    int blk = blockIdx.x; int b = blk / NQ, qi = blk % NQ;
    int lane = threadIdx.x;
    const float* qp = q + ((size_t)b * NQ + qi) * 3;
    float qx = qp[0], qy = qp[1], qz = qp[2];
    float qq = __fadd_rn(__fadd_rn(__fmul_rn(qx,qx), __fmul_rn(qy,qy)), __fmul_rn(qz,qz));
    const float* rp = r + (size_t)b * NR * 3;
    for (int i = lane; i < NR; i += 64) {
        float rx = rp[3*i], ry = rp[3*i+1], rz = rp[3*i+2];
        float rr = __fadd_rn(__fadd_rn(__fmul_rn(rx,rx), __fmul_rn(ry,ry)), __fmul_rn(rz,rz));
        float dot = __fadd_rn(__fadd_rn(__fmul_rn(qx,rx), __fmul_rn(qy,ry)), __fmul_rn(qz,rz));
        dist[i] = __fadd_rn(__fadd_rn(qq, rr), -2.f * dot);
    }
    __syncthreads();
    int* out = nidx + ((size_t)b * NQ + qi) * Kc;
    for (int sel = 0; sel < Kc; ++sel) {
        float bv = INFINITY; int bi = 0;
        bool has = false;
        for (int i = lane; i < NR; i += 64) {
            float v = dist[i];
            if (!has || v < bv) { bv = v; bi = i; has = true; }
        }
        for (int o = 32; o > 0; o >>= 1) {
            float v2 = __shfl_xor(bv, o, 64); int i2 = __shfl_xor(bi, o, 64);
            if (v2 < bv || (v2 == bv && i2 < bi)) { bv = v2; bi = i2; }
        }
        if (lane == 0) { out[sel] = bi; dist[bi] = INFINITY; }
        __syncthreads();
    }
}

// -------------------- top-3 centers + interp weights --------------------
__global__ __launch_bounds__(64) void knn3_kernel(const float* __restrict__ pos, const float* __restrict__ cent,
                                                  int* __restrict__ idx3, float* __restrict__ w3) {
    int bn = blockIdx.x; int b = bn / Nn;
    int lane = threadIdx.x;
    const float* p = pos + (size_t)bn * 3;
    float px = p[0], py = p[1], pz = p[2];
    float pp = __fadd_rn(__fadd_rn(__fmul_rn(px,px), __fmul_rn(py,py)), __fmul_rn(pz,pz));
    float dv[2]; int di[2];
#pragma unroll
    for (int c = 0; c < 2; c++) {
        int g = lane + 64 * c;
        const float* cp = cent + ((size_t)b * Gc + g) * 3;
        float cx = cp[0], cy = cp[1], cz = cp[2];
        float cc = __fadd_rn(__fadd_rn(__fmul_rn(cx,cx), __fmul_rn(cy,cy)), __fmul_rn(cz,cz));
        float dot = __fadd_rn(__fadd_rn(__fmul_rn(px,cx), __fmul_rn(py,cy)), __fmul_rn(pz,cz));
        dv[c] = __fadd_rn(__fadd_rn(pp, cc), -2.f * dot);
        di[c] = g;
    }
    float od[3]; int oi[3];
#pragma unroll
    for (int r = 0; r < 3; r++) {
        float bv; int bi;
        if (dv[1] < dv[0]) { bv = dv[1]; bi = di[1]; } else { bv = dv[0]; bi = di[0]; }
        for (int o = 32; o > 0; o >>= 1) {
            float v2 = __shfl_xor(bv, o, 64); int i2 = __shfl_xor(bi, o, 64);
            if (v2 < bv || (v2 == bv && i2 < bi)) { bv = v2; bi = i2; }
        }
        od[r] = bv; oi[r] = bi;
        if (di[0] == bi) dv[0] = INFINITY;
        if (di[1] == bi) dv[1] = INFINITY;
    }
    if (lane == 0) {
        float w[3], s = 0.f;
        for (int r = 0; r < 3; r++) { w[r] = 1.f / (fmaxf(od[r], 0.f) + 1e-8f); s += w[r]; }
        for (int r = 0; r < 3; r++) { idx3[(size_t)bn*3 + r] = oi[r]; w3[(size_t)bn*3 + r] = w[r] / s; }
    }
}

// interp for rows [r0, r0+CH): out local (CH,448) bf16, cols 387..447 zero
__global__ void interp_kernel(const float* __restrict__ feats, const float* __restrict__ pos,
                              const int* __restrict__ idx3, const float* __restrict__ w3,
                              __bf16* __restrict__ x448, int r0, int CH) {
    size_t t = (size_t)blockIdx.x * 256 + threadIdx.x;
    size_t total = (size_t)CH * 448;
    if (t >= total) return;
    int c = (int)(t % 448); size_t i = t / 448;
    size_t r = (size_t)r0 + i; int b = (int)(r / Nn);
    float o = 0.f;
    if (c < Dd) {
        for (int k = 0; k < 3; k++)
            o += w3[r*3 + k] * feats[((size_t)b * Gc + idx3[r*3 + k]) * Dd + c];
    } else if (c < 387) {
        o = pos[r*3 + (c - Dd)];
    }
    x448[t] = f2b(o);
}

// -------------------- tokenize helpers --------------------
// rel: [Bc*Gc*Kc][64] bf16, cols 3..63 zero (padded K for GEMM)
__global__ void rel_kernel(const float* __restrict__ pos, const float* __restrict__ cent,
                           const int* __restrict__ nidx, __bf16* __restrict__ rel) {
    int t = blockIdx.x * 256 + threadIdx.x;
    if (t >= Bc * Gc * Kc * 64) return;
    int c = t & 63; int row = t >> 6;
    float v = 0.f;
    if (c < 3) {
        int g = (row / Kc) % Gc; int b = row / (Kc * Gc);
        int pi = nidx[row];
        v = pos[((size_t)b * Nn + pi) * 3 + c] - cent[((size_t)b * Gc + g) * 3 + c];
    }
    rel[t] = f2b(v);
}

__global__ void maxk_f32_kernel(const float* __restrict__ in, float* __restrict__ out, int BG, int C) {
    int t = blockIdx.x * 256 + threadIdx.x;
    if (t >= BG * C) return;
    int c = t % C; int bg = t / C;
    const float* p = in + (size_t)bg * Kc * C + c;
    float m = -INFINITY;
    for (int k = 0; k < Kc; k++) m = fmaxf(m, p[(size_t)k * C]);
    out[t] = m;
}

__global__ void maxk_bf_kernel(const __bf16* __restrict__ in, __bf16* __restrict__ out, int BG, int C) {
    int t = blockIdx.x * 256 + threadIdx.x;
    if (t >= BG * C) return;
    int c = t % C; int bg = t / C;
    const __bf16* p = in + (size_t)bg * Kc * C + c;
    float m = -INFINITY;
    for (int k = 0; k < Kc; k++) m = fmaxf(m, (float)p[(size_t)k * C]);
    out[t] = f2b(m);
}

__global__ void concat_gf_kernel(const __bf16* __restrict__ g, const __bf16* __restrict__ f,
                                 __bf16* __restrict__ cat, int BG) {
    size_t t = (size_t)blockIdx.x * 256 + threadIdx.x;
    size_t total = (size_t)BG * Kc * 512;
    if (t >= total) return;
    int c = (int)(t % 512); size_t bgk = t / 512; size_t bg = bgk / Kc;
    cat[t] = (c < 256) ? g[bg * 256 + c] : f[bgk * 256 + (c - 256)];
}

// -------------------- gather / masks --------------------
__global__ void gather_rows_kernel(const float* __restrict__ in, const int* __restrict__ idx,
                                   float* __restrict__ out, int Ni, int C, int Sin) {
    size_t t = (size_t)blockIdx.x * 256 + threadIdx.x;
    size_t total = (size_t)Bc * Ni * C;
    if (t >= total) return;
    int c = (int)(t % C); size_t bi = t / C; int i = (int)(bi % Ni); int b = (int)(bi / Ni);
    int r = idx[(size_t)b * Ni + i];
    out[t] = in[((size_t)b * Sin + r) * C + c];
}

__global__ void scatter_mask_kernel(const int* __restrict__ nidx, unsigned char* __restrict__ mask,
                                    int Q, int S) {
    int t = blockIdx.x * 256 + threadIdx.x;
    if (t >= Bc * Q * Kc) return;
    int q = (t / Kc) % Q; int b = t / (Kc * Q);
    mask[((size_t)b * Q + q) * S + nidx[t]] = 1;
}

// -------------------- positional encoding (dst = base + pe) --------------------
__global__ void pe_kernel(float* __restrict__ dst, const float* __restrict__ base,
                          const float* __restrict__ xyz, size_t total) {
    size_t t = (size_t)blockIdx.x * 256 + threadIdx.x;
    if (t >= total) return;
    int d = (int)(t % Dd); size_t bs = t / Dd;
    int c = d >> 7;
    int i = d & 127;
    int j = i >> 1;
    float inv = expf(-0.1439115683121279f * (float)j);  // 10000^(-j/64)
    float val = xyz[bs * 3 + c] * inv;
    float pe = (i & 1) ? cosf(val) : sinf(val);
    dst[t] = (base ? base[t] : 0.f) + pe;
}

// -------------------- LayerNorm (no affine), row=384, bf16 out --------------------
__global__ __launch_bounds__(256) void ln_kernel(const float* __restrict__ X, __bf16* __restrict__ Y, int R) {
    int lane = threadIdx.x & 63;
    int row = blockIdx.x * 4 + (threadIdx.x >> 6);
    if (row >= R) return;
    const float* x = X + (size_t)row * Dd;
    float v[6]; float s = 0.f;
#pragma unroll
    for (int j = 0; j < 6; j++) { v[j] = x[lane + 64*j]; s += v[j]; }
#pragma unroll
    for (int o = 32; o > 0; o >>= 1) s += __shfl_xor(s, o, 64);
    float m = s * (1.f / Dd);
    float s2 = 0.f;
#pragma unroll
    for (int j = 0; j < 6; j++) { float d = v[j] - m; s2 += d * d; }
#pragma unroll
    for (int o = 32; o > 0; o >>= 1) s2 += __shfl_xor(s2, o, 64);
    float inv = rsqrtf(s2 * (1.f / Dd) + 1e-5f);
    __bf16* y = Y + (size_t)row * Dd;
#pragma unroll
    for (int j = 0; j < 6; j++) y[lane + 64*j] = f2b((v[j] - m) * inv);
}

// -------------------- MFMA bf16 GEMM, 128x128 tile, bf16 A [M][K] x bf16 Wt [N][K] --------------------
// Requires M%128==0, N%128==0, K%64==0 (host guarantees via padding). 4 waves, each computes a
// 64x64 quadrant (4x4 fragments of 16x16x32). BK=64, vectorized 16B register staging, padded LDS.
// Fused bias(f32)/relu/residual(f32); output fp32 or bf16.
__global__ __launch_bounds__(256) void gemm_kernel(const __bf16* __restrict__ A, const __bf16* __restrict__ Wt,
                                                   const float* __restrict__ bias,
                                                   const float* __restrict__ res, void* __restrict__ Cv,
                                                   int M, int Ncols, int Kk, int relu, int obf) {
    __shared__ __bf16 As[128][72];
    __shared__ __bf16 Bs[128][72];
    const int tid = threadIdx.x;
    const int row0 = blockIdx.y * 128, col0 = blockIdx.x * 128;
    const int w = tid >> 6, lane = tid & 63, m = lane & 15, q = lane >> 4;
    const int wr = w >> 1, wc = w & 1;
    const int srow = tid >> 1, sk = (tid & 1) * 32;
    const __bf16* ap = A + (size_t)(row0 + srow) * Kk + sk;
    const __bf16* wp = Wt + (size_t)(col0 + srow) * Kk + sk;

    f4v acc[4][4];
#pragma unroll
    for (int r = 0; r < 4; r++)
#pragma unroll
        for (int n = 0; n < 4; n++) acc[r][n] = (f4v){0.f, 0.f, 0.f, 0.f};

    for (int k0 = 0; k0 < Kk; k0 += 64) {
#pragma unroll
        for (int i = 0; i < 4; i++) {
            *reinterpret_cast<uint4*>(&As[srow][sk + 8*i]) = *reinterpret_cast<const uint4*>(ap + k0 + 8*i);
            *reinterpret_cast<uint4*>(&Bs[srow][sk + 8*i]) = *reinterpret_cast<const uint4*>(wp + k0 + 8*i);
        }
        __syncthreads();
#pragma unroll
        for (int kk = 0; kk < 2; kk++) {
            bf8v bfr[4], afr[4];
#pragma unroll
            for (int n = 0; n < 4; n++) bfr[n] = *reinterpret_cast<bf8v*>(&Bs[wc*64 + n*16 + m][kk*32 + q*8]);
#pragma unroll
            for (int r = 0; r < 4; r++) afr[r] = *reinterpret_cast<bf8v*>(&As[wr*64 + r*16 + m][kk*32 + q*8]);
#pragma unroll
            for (int r = 0; r < 4; r++)
#pragma unroll
                for (int n = 0; n < 4; n++)
                    acc[r][n] = __builtin_amdgcn_mfma_f32_16x16x32_bf16(afr[r], bfr[n], acc[r][n], 0, 0, 0);
        }
        __syncthreads();
    }
#pragma unroll
    for (int n = 0; n < 4; n++) {
        const int gn = col0 + wc*64 + n*16 + m;
        float bv = bias ? bias[gn] : 0.f;
#pragma unroll
        for (int r = 0; r < 4; r++) {
#pragma unroll
            for (int j = 0; j < 4; j++) {
                int gm = row0 + wr*64 + r*16 + q*4 + j;
                float v = acc[r][n][j] + bv;
                if (relu) v = fmaxf(v, 0.f);
                if (res) v += res[(size_t)gm * Ncols + gn];
                if (obf) ((__bf16*)Cv)[(size_t)gm * Ncols + gn] = f2b(v);
                else     ((float*)Cv)[(size_t)gm * Ncols + gn] = v;
            }
        }
    }
}

// -------------------- fused attention: one wave per (bq,h,qi), strided Q/KV, bf16 out --------------------
__global__ __launch_bounds__(64) void attn_kernel(const float* __restrict__ Q, const float* __restrict__ Kb,
                                                  const float* __restrict__ Vb,
                                                  const unsigned char* __restrict__ mask,
                                                  __bf16* __restrict__ O, int Sq, int Sk, int b0,
                                                  int ldq, int ldkv) {
    int qi = blockIdx.x, h = blockIdx.y, bq = blockIdx.z;
    int bk = bq + b0;
    int lane = threadIdx.x;
    __shared__ float qv[DHh];
    __shared__ float pv[128];
    const size_t qrow = (size_t)bq * Sq + qi;
    if (lane < DHh) qv[lane] = Q[qrow * ldq + h * DHh + lane];
    __syncthreads();
    const float scale = 0.14433756729740643f;  // 1/sqrt(48)
    float lv[2] = {-INFINITY, -INFINITY};
#pragma unroll
    for (int c = 0; c < 2; c++) {
        int s = lane + 64 * c;
        if (s < Sk) {
            const float* kr = Kb + ((size_t)bk * Sk + s) * ldkv + h * DHh;
            float d = 0.f;
#pragma unroll
            for (int t = 0; t < DHh; t++) d += qv[t] * kr[t];
            d *= scale;
            if (mask && !mask[qrow * Sk + s]) d = -1e9f;
            lv[c] = d;
        }
    }
    float mx = fmaxf(lv[0], lv[1]);
    for (int o = 32; o > 0; o >>= 1) mx = fmaxf(mx, __shfl_xor(mx, o, 64));
    float sum = 0.f;
#pragma unroll
    for (int c = 0; c < 2; c++) {
        int s = lane + 64 * c;
        if (s < Sk) { float e = expf(lv[c] - mx); pv[s] = e; sum += e; }
    }
    for (int o = 32; o > 0; o >>= 1) sum += __shfl_xor(sum, o, 64);
    float inv = 1.f / sum;
    __syncthreads();
    if (lane < DHh) {
        float acc = 0.f;
        const float* vb = Vb + ((size_t)bk * Sk) * ldkv + h * DHh + lane;
        for (int s = 0; s < Sk; s++) acc += pv[s] * vb[(size_t)s * ldkv];
        O[qrow * Dd + h * DHh + lane] = f2b(acc * inv);
    }
}

// -------------------- decoder q init --------------------
__global__ void dec_init_kernel(const float* __restrict__ mtok, const float* __restrict__ vout,
                                const float* __restrict__ cpe, const int* __restrict__ mski,
                                const int* __restrict__ visi, float* __restrict__ x) {
    size_t t = (size_t)blockIdx.x * 256 + threadIdx.x;
    size_t total = (size_t)Bc * Gc * Dd;
    if (t >= total) return;
    int d = (int)(t % Dd); size_t bi = t / Dd; int i = (int)(bi % Gc); int b = (int)(bi / Gc);
    float base; int ci;
    if (i < Mc) { base = mtok[d]; ci = mski[b * Mc + i]; }
    else        { base = vout[((size_t)b * Vc + (i - Mc)) * Dd + d]; ci = visi[b * Vc + (i - Mc)]; }
    x[t] = base + cpe[((size_t)b * Gc + ci) * Dd + d];
}

// -------------------- smooth-L1 partial reduce --------------------
__global__ __launch_bounds__(256) void sl1_kernel(const float* __restrict__ tgt, const float* __restrict__ dec,
                                                  float* __restrict__ acc, int slot) {
    __shared__ float sh[256];
    size_t t = (size_t)blockIdx.x * 256 + threadIdx.x;
    const size_t total = (size_t)Bc * Mc * Dd;
    float v = 0.f;
    if (t < total) {
        int d = (int)(t % Dd); size_t rem = t / Dd; int i = (int)(rem % Mc); int b = (int)(rem / Mc);
        float p = dec[((size_t)b * Gc + i) * Dd + d];
        float a = fabsf(p - tgt[t]);
        v = (a < 2.f) ? 0.25f * a * a : (a - 1.f);
    }
    sh[threadIdx.x] = v;
    __syncthreads();
    for (int s = 128; s > 0; s >>= 1) {
        if (threadIdx.x < s) sh[threadIdx.x] += sh[threadIdx.x + s];
        __syncthreads();
    }
    if (threadIdx.x == 0) atomicAdd(&acc[slot], sh[0]);
}

__global__ void mae_finalize_kernel(const float* __restrict__ acc, float* __restrict__ out) {
    const float inv = 1.f / (float)(Bc * Mc * Dd);
    *out = 0.5f * (acc[0] * inv) + 0.5f * (acc[1] * inv);
}

// ==================== host orchestration ====================
extern "C" void kernel_launch(void* const* d_in, const int* in_sizes, int n_in,
                              void* d_out, int out_size, void* d_ws, size_t ws_size,
                              hipStream_t stream) {
    (void)in_sizes; (void)n_in; (void)out_size;
    const void* pos_src = d_in[0];
    const void* pos_tgt = d_in[1];
    const int* vis_s = (const int*)d_in[2];
    const int* msk_s = (const int*)d_in[3];
    const int* vis_t = (const int*)d_in[4];
    const int* msk_t = (const int*)d_in[5];
    const void *tw1 = d_in[6], *tb1 = d_in[7], *tw2 = d_in[8], *tb2 = d_in[9];
    const void *tw3 = d_in[10], *tb3 = d_in[11], *tw4 = d_in[12], *tb4 = d_in[13];
    const void *mtok = d_in[14];
    const void *cxw = d_in[15], *cff1 = d_in[16], *cff2 = d_in[17];
    const void *esa = d_in[18], *eca = d_in[19], *eff1 = d_in[20], *eff2 = d_in[21];
    const void *dca = d_in[22], *dff1 = d_in[23], *dff2 = d_in[24];
    const void *uw1 = d_in[25], *ub1 = d_in[26], *uw2 = d_in[27], *ub2 = d_in[28];
    float* out = (float*)d_out;                      // fp32 output
    char* ws = (char*)d_ws;

    const size_t DD = (size_t)Dd * Dd;
    const size_t DF = (size_t)Dd * FFf;

    // ---- bf16 transposed weight arena (element offsets) ----
    size_t wo = 0;
    auto walloc = [&](size_t e) -> size_t { size_t r = wo; wo += e; return r; };
    const size_t wt_t1 = walloc((size_t)128 * 64);          // [128][64]   (K=3 padded)
    const size_t wt_t2 = walloc((size_t)256 * 128);
    const size_t wt_t3 = walloc((size_t)512 * 512);
    const size_t wt_t4 = walloc((size_t)384 * 512);
    const size_t wt_cx = walloc((size_t)8 * DD);
    const size_t wt_cf1 = walloc(DF);                       // [1536][384]
    const size_t wt_cf2 = walloc(DF);                       // [384][1536]
    const size_t wt_es = walloc((size_t)16 * DD);
    const size_t wt_ec = walloc((size_t)16 * DD);
    const size_t wt_ef1 = walloc((size_t)4 * DF);
    const size_t wt_ef2 = walloc((size_t)4 * DF);
    const size_t wt_dc = walloc((size_t)8 * DD);
    const size_t wt_df1 = walloc((size_t)2 * DF);
    const size_t wt_df2 = walloc((size_t)2 * DF);
    const size_t wt_u1 = walloc((size_t)384 * 448);         // [384][448] (K=387 padded)
    const size_t wt_u2 = walloc((size_t)384 * 384);

    // ---- persistent workspace layout ----
    size_t o = 0;
    auto alloc = [&](size_t bytes) -> size_t { size_t r = o; o += (bytes + 255) & ~(size_t)255; return r; };
    const size_t flagO = alloc(256);
    const size_t wtO = alloc(wo * 2);                       // bf16 weights
    const size_t bsO = alloc(2048 * 4);                     // fp32 biases
    const size_t mtokO = alloc(Dd * 4);
    const size_t posf_s = alloc((size_t)Bc*Nn*3*4), posf_t = alloc((size_t)Bc*Nn*3*4);
    const size_t cent_s = alloc((size_t)Bc*Gc*3*4), cent_t = alloc((size_t)Bc*Gc*3*4);
    const size_t cpe_s = alloc((size_t)Bc*Gc*Dd*4), cpe_t = alloc((size_t)Bc*Gc*Dd*4);
    const size_t tok_s = alloc((size_t)Bc*Gc*Dd*4), tok_t = alloc((size_t)Bc*Gc*Dd*4);
    const size_t vtok_s = alloc((size_t)Bc*Vc*Dd*4), vtok_t = alloc((size_t)Bc*Vc*Dd*4);
    const size_t lnS = alloc((size_t)Bc*Gc*Dd*4), lnT = alloc((size_t)Bc*Gc*Dd*4);
    const size_t qb = alloc((size_t)Bc*Gc*Dd*4);
    const size_t qkvb = alloc((size_t)Bc*Gc*1152*4);        // fused qkv / kv projections
    const size_t kvl0 = alloc((size_t)Bc*Gc*768*4), kvl1 = alloc((size_t)Bc*Gc*768*4);
    const size_t cx = alloc((size_t)Bc*Gc*Dd*4);
    const size_t decx_s = alloc((size_t)Bc*Gc*Dd*4), decx_t = alloc((size_t)Bc*Gc*Dd*4);
    const size_t memb = alloc((size_t)Bc*Gc*Dd*4), lnm = alloc((size_t)Bc*Gc*Dd*4);
    const size_t relb = alloc((size_t)Bc*Gc*Kc*64*2);       // bf16, K padded to 64
    const size_t tbs = alloc((size_t)Bc*Mc*Dd*4), tbt = alloc((size_t)Bc*Mc*Dd*4);
    const size_t mfull_s = alloc((size_t)Bc*Gc*Gc), mfull_t = alloc((size_t)Bc*Gc*Gc);
    const size_t mvis_s = alloc((size_t)Bc*Vc*Vc), mvis_t = alloc((size_t)Bc*Vc*Vc);
    const size_t nidxb = alloc((size_t)Bc*Gc*Kc*4);
    const size_t idx3b = alloc((size_t)Bc*Nn*3*4), w3b = alloc((size_t)Bc*Nn*3*4);
    const size_t vis3_s = alloc((size_t)Bc*Vc*3*4), vis3_t = alloc((size_t)Bc*Vc*3*4);
    const size_t accb = alloc(64);

    // ---- scratch arena ----
    const size_t arenaO = o;
    const size_t arena_bytes = (ws_size > arenaO) ? (ws_size - arenaO) : 0;
    // dense-path rows-per-pass: per-row bytes = Acb 896 + Xc 1536 + Lc 768 + T1 1536 + T2 768 + Hh 3072 = 8576
    int RP = 128;
    {
        const int cands[9] = {32768, 16384, 8192, 4096, 2048, 1024, 512, 256, 128};
        for (int ci = 0; ci < 9; ci++) {
            if ((size_t)cands[ci] * 8576 + 4096 <= arena_bytes) { RP = cands[ci]; break; }
        }
    }
    // dense-path arena offsets (bytes from arenaO)
    size_t ao = arenaO;
    auto aalloc = [&](size_t bytes) -> size_t { size_t r = ao; ao += (bytes + 255) & ~(size_t)255; return r; };
    const size_t AcbO = aalloc((size_t)RP*448*2);
    const size_t XcO  = aalloc((size_t)RP*384*4);
    const size_t LcO  = aalloc((size_t)RP*384*2);
    const size_t T1O  = aalloc((size_t)RP*384*4);
    const size_t T2O  = aalloc((size_t)RP*384*2);
    const size_t HhO  = aalloc((size_t)RP*1536*2);
    // tokenize groups-per-pass: per-group bytes = 16*(256+512+1024+1024+1536)+512 = 70128
    int TC = (int)(arena_bytes / 70200);
    TC &= ~7; if (TC > 1024) TC = 1024; if (TC < 8) TC = 8;
    size_t to = arenaO;
    auto talloc = [&](size_t bytes) -> size_t { size_t r = to; to += (bytes + 255) & ~(size_t)255; return r; };
    const size_t tk1O = talloc((size_t)TC*16*128*2);
    const size_t tk2O = talloc((size_t)TC*16*256*2);
    const size_t tgmO = talloc((size_t)TC*256*2);
    const size_t tcatO = talloc((size_t)TC*16*512*2);
    const size_t thbO = talloc((size_t)TC*16*512*2);
    const size_t t4oO = talloc((size_t)TC*16*384*4);

    auto F = [&](size_t off) -> float* { return (float*)(ws + off); };
    auto I = [&](size_t off) -> int* { return (int*)(ws + off); };
    auto U = [&](size_t off) -> unsigned char* { return (unsigned char*)(ws + off); };
    auto Bf = [&](size_t off) -> __bf16* { return (__bf16*)(ws + off); };
    auto ew = [](size_t n) -> dim3 { return dim3((unsigned)((n + 255) / 256)); };
    const int* flag = I(flagO);
    __bf16* WT = Bf(wtO);
    float* BF = F(bsO);
    const int b_t1 = 0, b_t2 = 128, b_t3 = 384, b_t4 = 896, b_u1 = 1280, b_u2 = 1664;

    auto gemm = [&](const __bf16* A, const __bf16* W, const float* bias, const float* res, void* C,
                    int M, int Ncol, int Kk, int relu, int obf) {
        dim3 g((unsigned)(Ncol / 128), (unsigned)(M / 128));
        gemm_kernel<<<g, 256, 0, stream>>>(A, W, bias, res, C, M, Ncol, Kk, relu, obf);
    };
    auto ln = [&](const float* X, __bf16* Y, int R) {
        ln_kernel<<<dim3((R + 3) / 4), 256, 0, stream>>>(X, Y, R);
    };
    auto attn = [&](const float* Qp, const float* Kp, const float* Vp, const unsigned char* mask,
                    __bf16* Op, int Sq, int Sk, int nb, int b0, int ldq, int ldkv) {
        attn_kernel<<<dim3(Sq, NHh, nb), 64, 0, stream>>>(Qp, Kp, Vp, mask, Op, Sq, Sk, b0, ldq, ldkv);
    };
    __bf16* ctxb = Bf(cx);
    auto attn_block = [&](float* x, const __bf16* qln, const __bf16* kln, const __bf16* w4,
                          const unsigned char* mask, int S) {
        if (qln == kln) {
            gemm(qln, w4, nullptr, nullptr, F(qkvb), Bc*S, 1152, Dd, 0, 0);
            attn(F(qkvb), F(qkvb) + 384, F(qkvb) + 768, mask, ctxb, S, S, Bc, 0, 1152, 1152);
        } else {
            gemm(qln, w4, nullptr, nullptr, F(qb), Bc*S, Dd, Dd, 0, 0);
            gemm(kln, w4 + DD, nullptr, nullptr, F(qkvb), Bc*S, 768, Dd, 0, 0);
            attn(F(qb), F(qkvb), F(qkvb) + 384, mask, ctxb, S, S, Bc, 0, Dd, 768);
        }
        gemm(ctxb, w4 + 3*DD, nullptr, x, x, Bc*S, Dd, Dd, 0, 0);
    };
    auto ffn = [&](float* x, const __bf16* w1t, const __bf16* w2t, int R) {
        ln(x, Bf(lnS), R);
        for (int r0 = 0; r0 < R; r0 += RP) {
            int rc = (R - r0 < RP) ? (R - r0) : RP;
            gemm(Bf(lnS) + (size_t)r0*Dd, w1t, nullptr, nullptr, Bf(HhO), rc, FFf, Dd, 1, 1);
            gemm(Bf(HhO), w2t, nullptr, x + (size_t)r0*Dd, x + (size_t)r0*Dd, rc, Dd, FFf, 0, 0);
        }
    };
    auto cross_enc = [&](float* xs, float* xt, const unsigned char* ms, const unsigned char* mt, int S) {
        ln(xs, Bf(lnS), Bc*S); attn_block(xs, Bf(lnS), Bf(lnS), WT + wt_cx, ms, S);
        ln(xt, Bf(lnT), Bc*S); attn_block(xt, Bf(lnT), Bf(lnT), WT + wt_cx, mt, S);
        ln(xs, Bf(lnS), Bc*S); ln(xt, Bf(lnT), Bc*S);
        attn_block(xs, Bf(lnS), Bf(lnT), WT + wt_cx + 4*DD, nullptr, S);
        attn_block(xt, Bf(lnT), Bf(lnS), WT + wt_cx + 4*DD, nullptr, S);
        ffn(xs, WT + wt_cf1, WT + wt_cf2, Bc*S);
        ffn(xt, WT + wt_cf1, WT + wt_cf2, Bc*S);
    };
    auto decoder4 = [&](float* x, const float* memin, const float* cpem) {
        add_kernel<<<ew((size_t)Bc*Gc*Dd), 256, 0, stream>>>(memin, cpem, F(memb), (size_t)Bc*Gc*Dd);
        ln(F(memb), Bf(lnm), Bc*Gc);
        for (int l = 0; l < 4; l++) {
            ln(x, Bf(lnT), Bc*Gc);
            attn_block(x, Bf(lnT), Bf(lnT), WT + wt_es + (size_t)l*4*DD, nullptr, Gc);
            ln(x, Bf(lnT), Bc*Gc);
            attn_block(x, Bf(lnT), Bf(lnm), WT + wt_ec + (size_t)l*4*DD, nullptr, Gc);
            ffn(x, WT + wt_ef1 + (size_t)l*DF, WT + wt_ef2 + (size_t)l*DF, Bc*Gc);
        }
    };
    auto tokenize = [&](const float* posf, const float* cent, float* tok) {
        knn16_kernel<<<dim3(Bc*Gc), 64, 0, stream>>>(cent, posf, I(nidxb), Gc, Nn);
        rel_kernel<<<ew((size_t)Bc*Gc*Kc*64), 256, 0, stream>>>(posf, cent, I(nidxb), Bf(relb));
        for (int g0 = 0; g0 < Bc*Gc; g0 += TC) {
            const int gc = (Bc*Gc - g0 < TC) ? (Bc*Gc - g0) : TC;
            const int RC = gc * Kc;
            gemm(Bf(relb) + (size_t)g0*Kc*64, WT + wt_t1, BF + b_t1, nullptr, Bf(tk1O), RC, 128, 64, 1, 1);
            gemm(Bf(tk1O), WT + wt_t2, BF + b_t2, nullptr, Bf(tk2O), RC, 256, 128, 0, 1);
            maxk_bf_kernel<<<ew((size_t)gc*256), 256, 0, stream>>>(Bf(tk2O), Bf(tgmO), gc, 256);
            concat_gf_kernel<<<ew((size_t)RC*512), 256, 0, stream>>>(Bf(tgmO), Bf(tk2O), Bf(tcatO), gc);
            gemm(Bf(tcatO), WT + wt_t3, BF + b_t3, nullptr, Bf(thbO), RC, 512, 512, 1, 1);
            gemm(Bf(thbO), WT + wt_t4, BF + b_t4, nullptr, F(t4oO), RC, Dd, 512, 0, 0);
            maxk_f32_kernel<<<ew((size_t)gc*Dd), 256, 0, stream>>>(F(t4oO), tok + (size_t)g0*Dd, gc, Dd);
        }
    };
    auto dense_side = [&](const float* posf, const float* cent, const float* feats,
                          const float* cpe_side, float* outp) {
        knn3_kernel<<<dim3(Bc*Nn), 64, 0, stream>>>(posf, cent, I(idx3b), F(w3b));
        add_kernel<<<ew((size_t)Bc*Gc*Dd), 256, 0, stream>>>(feats, cpe_side, F(memb), (size_t)Bc*Gc*Dd);
        ln(F(memb), Bf(lnm), Bc*Gc);
        gemm(Bf(lnm), WT + wt_dc + 0*4*DD + DD, nullptr, nullptr, F(kvl0), Bc*Gc, 768, Dd, 0, 0);
        gemm(Bf(lnm), WT + wt_dc + 1*4*DD + DD, nullptr, nullptr, F(kvl1), Bc*Gc, 768, Dd, 0, 0);
        const size_t kvo[2] = {kvl0, kvl1};
        const int R = Bc * Nn;
        for (int r0 = 0; r0 < R; r0 += RP) {
            const int sq = (RP < Nn) ? RP : Nn;
            const int nb = (RP < Nn) ? 1 : RP / Nn;
            const int b0 = r0 / Nn;
            interp_kernel<<<ew((size_t)RP*448), 256, 0, stream>>>(feats, posf, I(idx3b), F(w3b), Bf(AcbO), r0, RP);
            gemm(Bf(AcbO), WT + wt_u1, BF + b_u1, nullptr, Bf(LcO), RP, Dd, 448, 1, 1);
            gemm(Bf(LcO), WT + wt_u2, BF + b_u2, nullptr, F(T1O), RP, Dd, Dd, 1, 0);
            pe_kernel<<<ew((size_t)RP*Dd), 256, 0, stream>>>(F(XcO), F(T1O), posf + (size_t)r0*3, (size_t)RP*Dd);
            for (int l = 0; l < 2; l++) {
                ln(F(XcO), Bf(LcO), RP);
                gemm(Bf(LcO), WT + wt_dc + (size_t)l*4*DD, nullptr, nullptr, F(T1O), RP, Dd, Dd, 0, 0);
                attn(F(T1O), F(kvo[l]), F(kvo[l]) + 384, nullptr, Bf(T2O), sq, Gc, nb, b0, Dd, 768);
                gemm(Bf(T2O), WT + wt_dc + (size_t)l*4*DD + 3*DD, nullptr, F(XcO), F(XcO), RP, Dd, Dd, 0, 0);
                ln(F(XcO), Bf(LcO), RP);
                gemm(Bf(LcO), WT + wt_df1 + (size_t)l*DF, nullptr, nullptr, Bf(HhO), RP, FFf, Dd, 1, 1);
                gemm(Bf(HhO), WT + wt_df2 + (size_t)l*DF, nullptr, F(XcO), F(XcO), RP, Dd, FFf, 0, 0);
            }
            copyout_kernel<<<ew((size_t)RP*Dd), 256, 0, stream>>>(F(XcO), outp + (size_t)r0*Dd, (size_t)RP*Dd);
        }
    };

    // ---- pipeline ----
    detect_kernel<<<dim3(1), 256, 0, stream>>>((const unsigned int*)pos_src, I(flagO));
    cvtf_kernel<<<ew((size_t)Bc*Nn*3), 256, 0, stream>>>(pos_src, F(posf_s), (size_t)Bc*Nn*3, flag);
    cvtf_kernel<<<ew((size_t)Bc*Nn*3), 256, 0, stream>>>(pos_tgt, F(posf_t), (size_t)Bc*Nn*3, flag);
    cvtf_kernel<<<dim3(2), 256, 0, stream>>>(mtok, F(mtokO), (size_t)Dd, flag);

    // weights -> bf16 transposed [N][Kpad]
    auto wtr = [&](const void* src, size_t dstOff, int K, int N, int Kpad, int cnt) {
        wtr_kernel<<<ew((size_t)cnt * N * Kpad), 256, 0, stream>>>(src, WT + dstOff, K, N, Kpad, cnt, flag);
    };
    wtr(tw1, wt_t1, 3, 128, 64, 1);
    wtr(tw2, wt_t2, 128, 256, 128, 1);
    wtr(tw3, wt_t3, 512, 512, 512, 1);
    wtr(tw4, wt_t4, 512, 384, 512, 1);
    wtr(cxw, wt_cx, 384, 384, 384, 8);
    wtr(cff1, wt_cf1, 384, 1536, 384, 1);
    wtr(cff2, wt_cf2, 1536, 384, 1536, 1);
    wtr(esa, wt_es, 384, 384, 384, 16);
    wtr(eca, wt_ec, 384, 384, 384, 16);
    wtr(eff1, wt_ef1, 384, 1536, 384, 4);
    wtr(eff2, wt_ef2, 1536, 384, 1536, 4);
    wtr(dca, wt_dc, 384, 384, 384, 8);
    wtr(dff1, wt_df1, 384, 1536, 384, 2);
    wtr(dff2, wt_df2, 1536, 384, 1536, 2);
    wtr(uw1, wt_u1, 387, 384, 448, 1);
    wtr(uw2, wt_u2, 384, 384, 384, 1);
    // biases -> fp32
    cvtf_kernel<<<ew(128), 256, 0, stream>>>(tb1, BF + b_t1, 128, flag);
    cvtf_kernel<<<ew(256), 256, 0, stream>>>(tb2, BF + b_t2, 256, flag);
    cvtf_kernel<<<ew(512), 256, 0, stream>>>(tb3, BF + b_t3, 512, flag);
    cvtf_kernel<<<ew(384), 256, 0, stream>>>(tb4, BF + b_t4, 384, flag);
    cvtf_kernel<<<ew(384), 256, 0, stream>>>(ub1, BF + b_u1, 384, flag);
    cvtf_kernel<<<ew(384), 256, 0, stream>>>(ub2, BF + b_u2, 384, flag);

    fps_kernel<<<dim3(16), 256, 0, stream>>>(F(posf_s), F(posf_t), F(cent_s), F(cent_t));
    tokenize(F(posf_s), F(cent_s), F(tok_s));
    tokenize(F(posf_t), F(cent_t), F(tok_t));

    pe_kernel<<<ew((size_t)Bc*Gc*Dd), 256, 0, stream>>>(F(cpe_s), nullptr, F(cent_s), (size_t)Bc*Gc*Dd);
    pe_kernel<<<ew((size_t)Bc*Gc*Dd), 256, 0, stream>>>(F(cpe_t), nullptr, F(cent_t), (size_t)Bc*Gc*Dd);

    gather_rows_kernel<<<ew((size_t)Bc*Vc*Dd), 256, 0, stream>>>(F(tok_s), vis_s, F(vtok_s), Vc, Dd, Gc);
    gather_rows_kernel<<<ew((size_t)Bc*Vc*Dd), 256, 0, stream>>>(F(tok_t), vis_t, F(vtok_t), Vc, Dd, Gc);
    gather_rows_kernel<<<ew((size_t)Bc*Vc*3), 256, 0, stream>>>(F(cent_s), vis_s, F(vis3_s), Vc, 3, Gc);
    gather_rows_kernel<<<ew((size_t)Bc*Vc*3), 256, 0, stream>>>(F(cent_t), vis_t, F(vis3_t), Vc, 3, Gc);

    zero_kernel<<<ew((size_t)Bc*Gc*Gc), 256, 0, stream>>>(U(mfull_s), (size_t)Bc*Gc*Gc);
    knn16_kernel<<<dim3(Bc*Gc), 64, 0, stream>>>(F(cent_s), F(cent_s), I(nidxb), Gc, Gc);
    scatter_mask_kernel<<<ew((size_t)Bc*Gc*Kc), 256, 0, stream>>>(I(nidxb), U(mfull_s), Gc, Gc);
    zero_kernel<<<ew((size_t)Bc*Gc*Gc), 256, 0, stream>>>(U(mfull_t), (size_t)Bc*Gc*Gc);
    knn16_kernel<<<dim3(Bc*Gc), 64, 0, stream>>>(F(cent_t), F(cent_t), I(nidxb), Gc, Gc);
    scatter_mask_kernel<<<ew((size_t)Bc*Gc*Kc), 256, 0, stream>>>(I(nidxb), U(mfull_t), Gc, Gc);
    zero_kernel<<<ew((size_t)Bc*Vc*Vc), 256, 0, stream>>>(U(mvis_s), (size_t)Bc*Vc*Vc);
    knn16_kernel<<<dim3(Bc*Vc), 64, 0, stream>>>(F(vis3_s), F(vis3_s), I(nidxb), Vc, Vc);
    scatter_mask_kernel<<<ew((size_t)Bc*Vc*Kc), 256, 0, stream>>>(I(nidxb), U(mvis_s), Vc, Vc);
    zero_kernel<<<ew((size_t)Bc*Vc*Vc), 256, 0, stream>>>(U(mvis_t), (size_t)Bc*Vc*Vc);
    knn16_kernel<<<dim3(Bc*Vc), 64, 0, stream>>>(F(vis3_t), F(vis3_t), I(nidxb), Vc, Vc);
    scatter_mask_kernel<<<ew((size_t)Bc*Vc*Kc), 256, 0, stream>>>(I(nidxb), U(mvis_t), Vc, Vc);

    cross_enc(F(vtok_s), F(vtok_t), U(mvis_s), U(mvis_t), Vc);
    cross_enc(F(tok_s), F(tok_t), U(mfull_s), U(mfull_t), Gc);

    dec_init_kernel<<<ew((size_t)Bc*Gc*Dd), 256, 0, stream>>>(F(mtokO), F(vtok_s), F(cpe_s), msk_s, vis_s, F(decx_s));
    dec_init_kernel<<<ew((size_t)Bc*Gc*Dd), 256, 0, stream>>>(F(mtokO), F(vtok_t), F(cpe_t), msk_t, vis_t, F(decx_t));
    decoder4(F(decx_s), F(tok_t), F(cpe_t));
    decoder4(F(decx_t), F(tok_s), F(cpe_s));

    zero_kernel<<<dim3(1), 256, 0, stream>>>(U(accb), 64);
    gather_rows_kernel<<<ew((size_t)Bc*Mc*Dd), 256, 0, stream>>>(F(tok_s), msk_s, F(tbs), Mc, Dd, Gc);
    gather_rows_kernel<<<ew((size_t)Bc*Mc*Dd), 256, 0, stream>>>(F(tok_t), msk_t, F(tbt), Mc, Dd, Gc);
    sl1_kernel<<<ew((size_t)Bc*Mc*Dd), 256, 0, stream>>>(F(tbs), F(decx_s), F(accb), 0);
    sl1_kernel<<<ew((size_t)Bc*Mc*Dd), 256, 0, stream>>>(F(tbt), F(decx_t), F(accb), 1);

    dense_side(F(posf_s), F(cent_s), F(tok_s), F(cpe_s), out);
    dense_side(F(posf_t), F(cent_t), F(tok_t), F(cpe_t), out + (size_t)Bc*Nn*Dd);

    mae_finalize_kernel<<<dim3(1), 1, 0, stream>>>(F(accb), out + (size_t)2*Bc*Nn*Dd);
}

// Round 3
// 3602.067 us; speedup vs baseline: 8.0594x; 2.5059x over previous
//
#include <hip/hip_runtime.h>
#include <hip/hip_bf16.h>
#include <math.h>

using bf16 = __hip_bfloat16;

#define DI static __device__ __forceinline__

constexpr int Bc = 8, Nn = 4096, Gc = 128, Kc = 16, Vc = 64, Mc = 64;
constexpr int Dd = 384, NHh = 8, DHh = 48, FFf = 1536;

typedef __bf16 bf8v __attribute__((ext_vector_type(8)));
typedef float f4v __attribute__((ext_vector_type(4)));

DI float b2f(bf16 h) { return __bfloat162float(h); }
DI __bf16 f2b(float f) { return (__bf16)f; }

// -------------------- dtype autodetect (inputs) --------------------
__global__ __launch_bounds__(256) void detect_kernel(const unsigned int* __restrict__ w, int* __restrict__ flag) {
    __shared__ int sh[256];
    int cnt = 0;
    for (int i = threadIdx.x; i < 16384; i += 256) {
        unsigned int lo = w[i] & 0xffffu;
        int e = (int)((lo >> 7) & 0xffu);
        if (e < 100 || e > 140) cnt++;
    }
    sh[threadIdx.x] = cnt;
    __syncthreads();
    for (int s = 128; s > 0; s >>= 1) {
        if (threadIdx.x < s) sh[threadIdx.x] += sh[threadIdx.x + s];
        __syncthreads();
    }
    if (threadIdx.x == 0) flag[0] = (sh[0] < 2048) ? 1 : 0;
}

DI float ldf(const void* p, size_t i, int isbf) {
    return isbf ? b2f(((const bf16*)p)[i]) : ((const float*)p)[i];
}

__global__ void cvtf_kernel(const void* __restrict__ src, float* __restrict__ dst, size_t n,
                            const int* __restrict__ flag) {
    size_t t = (size_t)blockIdx.x * 256 + threadIdx.x;
    if (t < n) dst[t] = ldf(src, t, flag[0]);
}

// weight transpose+round: src [cnt][K][N] -> dst [cnt][N][Kpad] bf16, zero-padded K
__global__ void wtr_kernel(const void* __restrict__ src, __bf16* __restrict__ dst,
                           int K, int N, int Kpad, int cnt, const int* __restrict__ flag) {
    size_t t = (size_t)blockIdx.x * 256 + threadIdx.x;
    size_t total = (size_t)cnt * N * Kpad;
    if (t >= total) return;
    int k = (int)(t % Kpad);
    size_t rem = t / Kpad;
    int n = (int)(rem % N);
    int mat = (int)(rem / N);
    float v = (k < K) ? ldf(src, ((size_t)mat * K + k) * N + n, flag[0]) : 0.f;
    dst[t] = f2b(v);
}

__global__ void zero_kernel(unsigned char* __restrict__ p, size_t n) {
    size_t t = (size_t)blockIdx.x * 256 + threadIdx.x;
    if (t < n) p[t] = 0;
}

__global__ void add_kernel(const float* __restrict__ a, const float* __restrict__ b,
                           float* __restrict__ o, size_t n) {
    size_t t = (size_t)blockIdx.x * 256 + threadIdx.x;
    if (t < n) o[t] = a[t] + b[t];
}

// -------------------- FPS (both sides in one dispatch: 16 blocks) --------------------
__global__ __launch_bounds__(256) void fps_kernel(const float* __restrict__ pos_a, const float* __restrict__ pos_b,
                                                  float* __restrict__ cent_a, float* __restrict__ cent_b) {
    __shared__ float px[Nn], py[Nn], pz[Nn];
    __shared__ float wv[4];
    __shared__ int wi[4];
    __shared__ int chosen;
    int side = blockIdx.x >> 3, b = blockIdx.x & 7, tid = threadIdx.x;
    const float* pos = side ? pos_b : pos_a;
    float* cent = side ? cent_b : cent_a;
    const float* p = pos + (size_t)b * Nn * 3;
    for (int i = tid; i < Nn; i += 256) { px[i] = p[3*i]; py[i] = p[3*i+1]; pz[i] = p[3*i+2]; }
    __syncthreads();
    float cx = px[0], cy = py[0], cz = pz[0];
    if (tid == 0) { float* c0 = cent + (size_t)b * Gc * 3; c0[0] = cx; c0[1] = cy; c0[2] = cz; }
    float mind[16];
#pragma unroll
    for (int j = 0; j < 16; j++) {
        int i = tid + 256 * j;
        float dx = px[i]-cx, dy = py[i]-cy, dz = pz[i]-cz;
        mind[j] = __fadd_rn(__fadd_rn(__fmul_rn(dx,dx), __fmul_rn(dy,dy)), __fmul_rn(dz,dz));
    }
    for (int s = 1; s < Gc; s++) {
        float bv = -1.f; int bi = 0;
#pragma unroll
        for (int j = 0; j < 16; j++) { int i = tid + 256*j; if (mind[j] > bv) { bv = mind[j]; bi = i; } }
        for (int o = 32; o > 0; o >>= 1) {
            float v2 = __shfl_down(bv, o, 64); int i2 = __shfl_down(bi, o, 64);
            if (v2 > bv || (v2 == bv && i2 < bi)) { bv = v2; bi = i2; }
        }
        if ((tid & 63) == 0) { wv[tid >> 6] = bv; wi[tid >> 6] = bi; }
        __syncthreads();
        if (tid == 0) {
            float fv = wv[0]; int fi = wi[0];
            for (int k = 1; k < 4; k++)
                if (wv[k] > fv || (wv[k] == fv && wi[k] < fi)) { fv = wv[k]; fi = wi[k]; }
            chosen = fi;
            float* cs = cent + ((size_t)b * Gc + s) * 3;
            cs[0] = px[fi]; cs[1] = py[fi]; cs[2] = pz[fi];
        }
        __syncthreads();
        int ci = chosen;
        float qx = px[ci], qy = py[ci], qz = pz[ci];
#pragma unroll
        for (int j = 0; j < 16; j++) {
            int i = tid + 256 * j;
            float dx = px[i]-qx, dy = py[i]-qy, dz = pz[i]-qz;
            float d = __fadd_rn(__fadd_rn(__fmul_rn(dx,dx), __fmul_rn(dy,dy)), __fmul_rn(dz,dz));
            if (d < mind[j]) mind[j] = d;
        }
    }
}

// -------------------- brute-force KNN (k=16), tie -> lower index --------------------
__global__ __launch_bounds__(64) void knn16_kernel(const float* __restrict__ q, const float* __restrict__ r,
                                                   int* __restrict__ nidx, int NQ, int NR) {
    __shared__ float dist[4096];
    int blk = blockIdx.x; int b = blk / NQ, qi = blk % NQ;
    int lane = threadIdx.x;
    const float* qp = q + ((size_t)b * NQ + qi) * 3;
    float qx = qp[0], qy = qp[1], qz = qp[2];
    float qq = __fadd_rn(__fadd_rn(__fmul_rn(qx,qx), __fmul_rn(qy,qy)), __fmul_rn(qz,qz));
    const float* rp = r + (size_t)b * NR * 3;
    for (int i = lane; i < NR; i += 64) {
        float rx = rp[3*i], ry = rp[3*i+1], rz = rp[3*i+2];
        float rr = __fadd_rn(__fadd_rn(__fmul_rn(rx,rx), __fmul_rn(ry,ry)), __fmul_rn(rz,rz));
        float dot = __fadd_rn(__fadd_rn(__fmul_rn(qx,rx), __fmul_rn(qy,ry)), __fmul_rn(qz,rz));
        dist[i] = __fadd_rn(__fadd_rn(qq, rr), -2.f * dot);
    }
    __syncthreads();
    int* out = nidx + ((size_t)b * NQ + qi) * Kc;
    for (int sel = 0; sel < Kc; ++sel) {
        float bv = INFINITY; int bi = 0;
        bool has = false;
        for (int i = lane; i < NR; i += 64) {
            float v = dist[i];
            if (!has || v < bv) { bv = v; bi = i; has = true; }
        }
        for (int o = 32; o > 0; o >>= 1) {
            float v2 = __shfl_xor(bv, o, 64); int i2 = __shfl_xor(bi, o, 64);
            if (v2 < bv || (v2 == bv && i2 < bi)) { bv = v2; bi = i2; }
        }
        if (lane == 0) { out[sel] = bi; dist[bi] = INFINITY; }
        __syncthreads();
    }
}

// -------------------- top-3 centers + interp weights --------------------
__global__ __launch_bounds__(64) void knn3_kernel(const float* __restrict__ pos, const float* __restrict__ cent,
                                                  int* __restrict__ idx3, float* __restrict__ w3) {
    int bn = blockIdx.x; int b = bn / Nn;
    int lane = threadIdx.x;
    const float* p = pos + (size_t)bn * 3;
    float px = p[0], py = p[1], pz = p[2];
    float pp = __fadd_rn(__fadd_rn(__fmul_rn(px,px), __fmul_rn(py,py)), __fmul_rn(pz,pz));
    float dv[2]; int di[2];
#pragma unroll
    for (int c = 0; c < 2; c++) {
        int g = lane + 64 * c;
        const float* cp = cent + ((size_t)b * Gc + g) * 3;
        float cx = cp[0], cy = cp[1], cz = cp[2];
        float cc = __fadd_rn(__fadd_rn(__fmul_rn(cx,cx), __fmul_rn(cy,cy)), __fmul_rn(cz,cz));
        float dot = __fadd_rn(__fadd_rn(__fmul_rn(px,cx), __fmul_rn(py,cy)), __fmul_rn(pz,cz));
        dv[c] = __fadd_rn(__fadd_rn(pp, cc), -2.f * dot);
        di[c] = g;
    }
    float od[3]; int oi[3];
#pragma unroll
    for (int r = 0; r < 3; r++) {
        float bv; int bi;
        if (dv[1] < dv[0]) { bv = dv[1]; bi = di[1]; } else { bv = dv[0]; bi = di[0]; }
        for (int o = 32; o > 0; o >>= 1) {
            float v2 = __shfl_xor(bv, o, 64); int i2 = __shfl_xor(bi, o, 64);
            if (v2 < bv || (v2 == bv && i2 < bi)) { bv = v2; bi = i2; }
        }
        od[r] = bv; oi[r] = bi;
        if (di[0] == bi) dv[0] = INFINITY;
        if (di[1] == bi) dv[1] = INFINITY;
    }
    if (lane == 0) {
        float w[3], s = 0.f;
        for (int r = 0; r < 3; r++) { w[r] = 1.f / (fmaxf(od[r], 0.f) + 1e-8f); s += w[r]; }
        for (int r = 0; r < 3; r++) { idx3[(size_t)bn*3 + r] = oi[r]; w3[(size_t)bn*3 + r] = w[r] / s; }
    }
}

// interp for rows [r0, r0+CH): out local (CH,448) bf16, cols 387..447 zero. b = global row / Nn (16 batches)
__global__ void interp_kernel(const float* __restrict__ feats, const float* __restrict__ pos,
                              const int* __restrict__ idx3, const float* __restrict__ w3,
                              __bf16* __restrict__ x448, int r0, int CH) {
    size_t t = (size_t)blockIdx.x * 256 + threadIdx.x;
    size_t total = (size_t)CH * 448;
    if (t >= total) return;
    int c = (int)(t % 448); size_t i = t / 448;
    size_t r = (size_t)r0 + i; int b = (int)(r / Nn);
    float o = 0.f;
    if (c < Dd) {
        for (int k = 0; k < 3; k++)
            o += w3[r*3 + k] * feats[((size_t)b * Gc + idx3[r*3 + k]) * Dd + c];
    } else if (c < 387) {
        o = pos[r*3 + (c - Dd)];
    }
    x448[t] = f2b(o);
}

// -------------------- tokenize helpers --------------------
// rel: [nb*Gc*Kc][64] bf16, cols 3..63 zero (padded K for GEMM)
__global__ void rel_kernel(const float* __restrict__ pos, const float* __restrict__ cent,
                           const int* __restrict__ nidx, __bf16* __restrict__ rel, int nb) {
    int t = blockIdx.x * 256 + threadIdx.x;
    if (t >= nb * Gc * Kc * 64) return;
    int c = t & 63; int row = t >> 6;
    float v = 0.f;
    if (c < 3) {
        int g = (row / Kc) % Gc; int b = row / (Kc * Gc);
        int pi = nidx[row];
        v = pos[((size_t)b * Nn + pi) * 3 + c] - cent[((size_t)b * Gc + g) * 3 + c];
    }
    rel[t] = f2b(v);
}

__global__ void maxk_f32_kernel(const float* __restrict__ in, float* __restrict__ out, int BG, int C) {
    int t = blockIdx.x * 256 + threadIdx.x;
    if (t >= BG * C) return;
    int c = t % C; int bg = t / C;
    const float* p = in + (size_t)bg * Kc * C + c;
    float m = -INFINITY;
    for (int k = 0; k < Kc; k++) m = fmaxf(m, p[(size_t)k * C]);
    out[t] = m;
}

__global__ void maxk_bf_kernel(const __bf16* __restrict__ in, __bf16* __restrict__ out, int BG, int C) {
    int t = blockIdx.x * 256 + threadIdx.x;
    if (t >= BG * C) return;
    int c = t % C; int bg = t / C;
    const __bf16* p = in + (size_t)bg * Kc * C + c;
    float m = -INFINITY;
    for (int k = 0; k < Kc; k++) m = fmaxf(m, (float)p[(size_t)k * C]);
    out[t] = f2b(m);
}

__global__ void concat_gf_kernel(const __bf16* __restrict__ g, const __bf16* __restrict__ f,
                                 __bf16* __restrict__ cat, int BG) {
    size_t t = (size_t)blockIdx.x * 256 + threadIdx.x;
    size_t total = (size_t)BG * Kc * 512;
    if (t >= total) return;
    int c = (int)(t % 512); size_t bgk = t / 512; size_t bg = bgk / Kc;
    cat[t] = (c < 256) ? g[bg * 256 + c] : f[bgk * 256 + (c - 256)];
}

// -------------------- gather / masks --------------------
__global__ void gather_rows_kernel(const float* __restrict__ in, const int* __restrict__ idx,
                                   float* __restrict__ out, int Ni, int C, int Sin) {
    size_t t = (size_t)blockIdx.x * 256 + threadIdx.x;
    size_t total = (size_t)Bc * Ni * C;
    if (t >= total) return;
    int c = (int)(t % C); size_t bi = t / C; int i = (int)(bi % Ni); int b = (int)(bi / Ni);
    int r = idx[(size_t)b * Ni + i];
    out[t] = in[((size_t)b * Sin + r) * C + c];
}

__global__ void scatter_mask_kernel(const int* __restrict__ nidx, unsigned char* __restrict__ mask,
                                    int Q, int S, int nb) {
    int t = blockIdx.x * 256 + threadIdx.x;
    if (t >= nb * Q * Kc) return;
    int q = (t / Kc) % Q; int b = t / (Kc * Q);
    mask[((size_t)b * Q + q) * S + nidx[t]] = 1;
}

// -------------------- positional encoding (dst = base + pe) --------------------
__global__ void pe_kernel(float* __restrict__ dst, const float* __restrict__ base,
                          const float* __restrict__ xyz, size_t total) {
    size_t t = (size_t)blockIdx.x * 256 + threadIdx.x;
    if (t >= total) return;
    int d = (int)(t % Dd); size_t bs = t / Dd;
    int c = d >> 7;
    int i = d & 127;
    int j = i >> 1;
    float inv = expf(-0.1439115683121279f * (float)j);  // 10000^(-j/64)
    float val = xyz[bs * 3 + c] * inv;
    float pe = (i & 1) ? cosf(val) : sinf(val);
    dst[t] = (base ? base[t] : 0.f) + pe;
}

// -------------------- LayerNorm (no affine), row=384, bf16 out --------------------
__global__ __launch_bounds__(256) void ln_kernel(const float* __restrict__ X, __bf16* __restrict__ Y, int R) {
    int lane = threadIdx.x & 63;
    int row = blockIdx.x * 4 + (threadIdx.x >> 6);
    if (row >= R) return;
    const float* x = X + (size_t)row * Dd;
    float v[6]; float s = 0.f;
#pragma unroll
    for (int j = 0; j < 6; j++) { v[j] = x[lane + 64*j]; s += v[j]; }
#pragma unroll
    for (int o = 32; o > 0; o >>= 1) s += __shfl_xor(s, o, 64);
    float m = s * (1.f / Dd);
    float s2 = 0.f;
#pragma unroll
    for (int j = 0; j < 6; j++) { float d = v[j] - m; s2 += d * d; }
#pragma unroll
    for (int o = 32; o > 0; o >>= 1) s2 += __shfl_xor(s2, o, 64);
    float inv = rsqrtf(s2 * (1.f / Dd) + 1e-5f);
    __bf16* y = Y + (size_t)row * Dd;
#pragma unroll
    for (int j = 0; j < 6; j++) y[lane + 64*j] = f2b((v[j] - m) * inv);
}

// -------------------- MFMA bf16 GEMM, 128x128 tile --------------------
__global__ __launch_bounds__(256) void gemm_kernel(const __bf16* __restrict__ A, const __bf16* __restrict__ Wt,
                                                   const float* __restrict__ bias,
                                                   const float* __restrict__ res, void* __restrict__ Cv,
                                                   int M, int Ncols, int Kk, int relu, int obf) {
    __shared__ __bf16 As[128][72];
    __shared__ __bf16 Bs[128][72];
    const int tid = threadIdx.x;
    const int row0 = blockIdx.y * 128, col0 = blockIdx.x * 128;
    const int w = tid >> 6, lane = tid & 63, m = lane & 15, q = lane >> 4;
    const int wr = w >> 1, wc = w & 1;
    const int srow = tid >> 1, sk = (tid & 1) * 32;
    const __bf16* ap = A + (size_t)(row0 + srow) * Kk + sk;
    const __bf16* wp = Wt + (size_t)(col0 + srow) * Kk + sk;

    f4v acc[4][4];
#pragma unroll
    for (int r = 0; r < 4; r++)
#pragma unroll
        for (int n = 0; n < 4; n++) acc[r][n] = (f4v){0.f, 0.f, 0.f, 0.f};

    for (int k0 = 0; k0 < Kk; k0 += 64) {
#pragma unroll
        for (int i = 0; i < 4; i++) {
            *reinterpret_cast<uint4*>(&As[srow][sk + 8*i]) = *reinterpret_cast<const uint4*>(ap + k0 + 8*i);
            *reinterpret_cast<uint4*>(&Bs[srow][sk + 8*i]) = *reinterpret_cast<const uint4*>(wp + k0 + 8*i);
        }
        __syncthreads();
#pragma unroll
        for (int kk = 0; kk < 2; kk++) {
            bf8v bfr[4], afr[4];
#pragma unroll
            for (int n = 0; n < 4; n++) bfr[n] = *reinterpret_cast<bf8v*>(&Bs[wc*64 + n*16 + m][kk*32 + q*8]);
#pragma unroll
            for (int r = 0; r < 4; r++) afr[r] = *reinterpret_cast<bf8v*>(&As[wr*64 + r*16 + m][kk*32 + q*8]);
#pragma unroll
            for (int r = 0; r < 4; r++)
#pragma unroll
                for (int n = 0; n < 4; n++)
                    acc[r][n] = __builtin_amdgcn_mfma_f32_16x16x32_bf16(afr[r], bfr[n], acc[r][n], 0, 0, 0);
        }
        __syncthreads();
    }
#pragma unroll
    for (int n = 0; n < 4; n++) {
        const int gn = col0 + wc*64 + n*16 + m;
        float bv = bias ? bias[gn] : 0.f;
#pragma unroll
        for (int r = 0; r < 4; r++) {
#pragma unroll
            for (int j = 0; j < 4; j++) {
                int gm = row0 + wr*64 + r*16 + q*4 + j;
                float v = acc[r][n][j] + bv;
                if (relu) v = fmaxf(v, 0.f);
                if (res) v += res[(size_t)gm * Ncols + gn];
                if (obf) ((__bf16*)Cv)[(size_t)gm * Ncols + gn] = f2b(v);
                else     ((float*)Cv)[(size_t)gm * Ncols + gn] = v;
            }
        }
    }
}

// -------------------- MFMA attention: Sk=128, DH=48, no mask --------------------
// grid (rpb/128, NHh, nb). Block 256 thr = 4 waves; wave w owns q-rows w*32..w*32+31 of a 128-row tile.
// Q read directly from global (bf16, ld=ldq); K staged [128][72] zero-padded cols 48..63 (kills Q
// garbage reads past col 48); V staged transposed [48][136]; P via LDS (aliases K region).
// KV batch stride = 128*ldkv; batch index = b0 + blockIdx.z.
__global__ __launch_bounds__(256) void attn_mfma_kernel(const __bf16* __restrict__ Qb,
                                                        const __bf16* __restrict__ Kp,
                                                        const __bf16* __restrict__ Vp,
                                                        __bf16* __restrict__ O,
                                                        int ldq, int ldkv, int ldo, int rpb, int b0) {
    __shared__ char smem[128*136*2 + 48*136*2];
    __bf16 (*Ks)[72]  = (__bf16(*)[72])smem;
    __bf16 (*Pl)[136] = (__bf16(*)[136])smem;            // aliases Ks after QK
    __bf16 (*Vt)[136] = (__bf16(*)[136])(smem + 128*136*2);
    const int tid = threadIdx.x;
    const int h = blockIdx.y, z = blockIdx.z;
    const int bk = b0 + z;
    const size_t row0 = (size_t)z * rpb + (size_t)blockIdx.x * 128;
    // stage K (zero-pad 48..63) and V^T
    {
        int r = tid >> 1, c0 = (tid & 1) * 24;
        const __bf16* kp = Kp + ((size_t)bk * 128 + r) * ldkv + h * 48 + c0;
        *reinterpret_cast<bf8v*>(&Ks[r][c0])      = *reinterpret_cast<const bf8v*>(kp);
        *reinterpret_cast<bf8v*>(&Ks[r][c0 + 8])  = *reinterpret_cast<const bf8v*>(kp + 8);
        *reinterpret_cast<bf8v*>(&Ks[r][c0 + 16]) = *reinterpret_cast<const bf8v*>(kp + 16);
        if (tid & 1) {
            *reinterpret_cast<bf8v*>(&Ks[r][48]) = (bf8v){};
            *reinterpret_cast<bf8v*>(&Ks[r][56]) = (bf8v){};
        }
        const __bf16* vp = Vp + ((size_t)bk * 128 + r) * ldkv + h * 48 + c0;
        bf8v w0 = *reinterpret_cast<const bf8v*>(vp);
        bf8v w1 = *reinterpret_cast<const bf8v*>(vp + 8);
        bf8v w2 = *reinterpret_cast<const bf8v*>(vp + 16);
#pragma unroll
        for (int i = 0; i < 8; i++) {
            Vt[c0 + i][r] = w0[i]; Vt[c0 + 8 + i][r] = w1[i]; Vt[c0 + 16 + i][r] = w2[i];
        }
    }
    __syncthreads();
    const int w = tid >> 6, lane = tid & 63, m = lane & 15, q = lane >> 4;
    const __bf16* qbase = Qb + (row0 + (size_t)(w*32 + m)) * ldq + h * 48;
    f4v sc[2][8];
#pragma unroll
    for (int rt = 0; rt < 2; rt++)
#pragma unroll
        for (int nt = 0; nt < 8; nt++) sc[rt][nt] = (f4v){0.f, 0.f, 0.f, 0.f};
#pragma unroll
    for (int kk = 0; kk < 2; kk++) {
        bf8v a0 = *reinterpret_cast<const bf8v*>(qbase + kk*32 + q*8);
        bf8v a1 = *reinterpret_cast<const bf8v*>(qbase + (size_t)16*ldq + kk*32 + q*8);
#pragma unroll
        for (int nt = 0; nt < 8; nt++) {
            bf8v bf = *reinterpret_cast<bf8v*>(&Ks[nt*16 + m][kk*32 + q*8]);
            sc[0][nt] = __builtin_amdgcn_mfma_f32_16x16x32_bf16(a0, bf, sc[0][nt], 0, 0, 0);
            sc[1][nt] = __builtin_amdgcn_mfma_f32_16x16x32_bf16(a1, bf, sc[1][nt], 0, 0, 0);
        }
    }
    // softmax over 128 keys per q-row; row = w*32 + rt*16 + q*4 + j, key = nt*16 + m
    const float scale = 0.14433756729740643f;  // 1/sqrt(48)
    float inv_[2][4];
#pragma unroll
    for (int rt = 0; rt < 2; rt++) {
#pragma unroll
        for (int j = 0; j < 4; j++) {
            float mv = -INFINITY;
#pragma unroll
            for (int nt = 0; nt < 8; nt++) { sc[rt][nt][j] *= scale; mv = fmaxf(mv, sc[rt][nt][j]); }
#pragma unroll
            for (int o = 8; o > 0; o >>= 1) mv = fmaxf(mv, __shfl_xor(mv, o, 64));
            float sum = 0.f;
#pragma unroll
            for (int nt = 0; nt < 8; nt++) {
                float e = expf(sc[rt][nt][j] - mv);
                sc[rt][nt][j] = e; sum += e;
            }
#pragma unroll
            for (int o = 8; o > 0; o >>= 1) sum += __shfl_xor(sum, o, 64);
            inv_[rt][j] = 1.f / sum;
        }
    }
    __syncthreads();   // all K reads done before P overwrites
#pragma unroll
    for (int rt = 0; rt < 2; rt++)
#pragma unroll
        for (int nt = 0; nt < 8; nt++)
#pragma unroll
            for (int j = 0; j < 4; j++)
                Pl[w*32 + rt*16 + q*4 + j][nt*16 + m] = f2b(sc[rt][nt][j]);
    __syncthreads();
    f4v ov[2][3];
#pragma unroll
    for (int rt = 0; rt < 2; rt++)
#pragma unroll
        for (int nt = 0; nt < 3; nt++) ov[rt][nt] = (f4v){0.f, 0.f, 0.f, 0.f};
#pragma unroll
    for (int kk = 0; kk < 4; kk++) {
        bf8v p0 = *reinterpret_cast<bf8v*>(&Pl[w*32 + m][kk*32 + q*8]);
        bf8v p1 = *reinterpret_cast<bf8v*>(&Pl[w*32 + 16 + m][kk*32 + q*8]);
#pragma unroll
        for (int nt = 0; nt < 3; nt++) {
            bf8v bv = *reinterpret_cast<bf8v*>(&Vt[nt*16 + m][kk*32 + q*8]);
            ov[0][nt] = __builtin_amdgcn_mfma_f32_16x16x32_bf16(p0, bv, ov[0][nt], 0, 0, 0);
            ov[1][nt] = __builtin_amdgcn_mfma_f32_16x16x32_bf16(p1, bv, ov[1][nt], 0, 0, 0);
        }
    }
    __bf16* op = O + (row0 + (size_t)(w*32)) * ldo + h * 48;
#pragma unroll
    for (int rt = 0; rt < 2; rt++)
#pragma unroll
        for (int nt = 0; nt < 3; nt++)
#pragma unroll
            for (int j = 0; j < 4; j++)
                op[(size_t)(rt*16 + q*4 + j) * ldo + nt*16 + m] = f2b(ov[rt][nt][j] * inv_[rt][j]);
}

// -------------------- scalar attention (masked / small S), xor batch pairing --------------------
__global__ __launch_bounds__(64) void attn_kernel(const float* __restrict__ Q, const float* __restrict__ Kb,
                                                  const float* __restrict__ Vb,
                                                  const unsigned char* __restrict__ mask,
                                                  __bf16* __restrict__ O, int Sq, int Sk, int xorv,
                                                  int ldq, int ldkv) {
    int qi = blockIdx.x, h = blockIdx.y, bq = blockIdx.z;
    int bk = bq ^ xorv;
    int lane = threadIdx.x;
    __shared__ float qv[DHh];
    __shared__ float pv[128];
    const size_t qrow = (size_t)bq * Sq + qi;
    if (lane < DHh) qv[lane] = Q[qrow * ldq + h * DHh + lane];
    __syncthreads();
    const float scale = 0.14433756729740643f;  // 1/sqrt(48)
    float lv[2] = {-INFINITY, -INFINITY};
#pragma unroll
    for (int c = 0; c < 2; c++) {
        int s = lane + 64 * c;
        if (s < Sk) {
            const float* kr = Kb + ((size_t)bk * Sk + s) * ldkv + h * DHh;
            float d = 0.f;
#pragma unroll
            for (int t = 0; t < DHh; t++) d += qv[t] * kr[t];
            d *= scale;
            if (mask && !mask[qrow * Sk + s]) d = -1e9f;
            lv[c] = d;
        }
    }
    float mx = fmaxf(lv[0], lv[1]);
    for (int o = 32; o > 0; o >>= 1) mx = fmaxf(mx, __shfl_xor(mx, o, 64));
    float sum = 0.f;
#pragma unroll
    for (int c = 0; c < 2; c++) {
        int s = lane + 64 * c;
        if (s < Sk) { float e = expf(lv[c] - mx); pv[s] = e; sum += e; }
    }
    for (int o = 32; o > 0; o >>= 1) sum += __shfl_xor(sum, o, 64);
    float inv = 1.f / sum;
    __syncthreads();
    if (lane < DHh) {
        float acc = 0.f;
        const float* vb = Vb + ((size_t)bk * Sk) * ldkv + h * DHh + lane;
        for (int s = 0; s < Sk; s++) acc += pv[s] * vb[(size_t)s * ldkv];
        O[qrow * Dd + h * DHh + lane] = f2b(acc * inv);
    }
}

// -------------------- decoder q init --------------------
__global__ void dec_init_kernel(const float* __restrict__ mtok, const float* __restrict__ vout,
                                const float* __restrict__ cpe, const int* __restrict__ mski,
                                const int* __restrict__ visi, float* __restrict__ x) {
    size_t t = (size_t)blockIdx.x * 256 + threadIdx.x;
    size_t total = (size_t)Bc * Gc * Dd;
    if (t >= total) return;
    int d = (int)(t % Dd); size_t bi = t / Dd; int i = (int)(bi % Gc); int b = (int)(bi / Gc);
    float base; int ci;
    if (i < Mc) { base = mtok[d]; ci = mski[b * Mc + i]; }
    else        { base = vout[((size_t)b * Vc + (i - Mc)) * Dd + d]; ci = visi[b * Vc + (i - Mc)]; }
    x[t] = base + cpe[((size_t)b * Gc + ci) * Dd + d];
}

// -------------------- smooth-L1 partial reduce --------------------
__global__ __launch_bounds__(256) void sl1_kernel(const float* __restrict__ tgt, const float* __restrict__ dec,
                                                  float* __restrict__ acc, int slot) {
    __shared__ float sh[256];
    size_t t = (size_t)blockIdx.x * 256 + threadIdx.x;
    const size_t total = (size_t)Bc * Mc * Dd;
    float v = 0.f;
    if (t < total) {
        int d = (int)(t % Dd); size_t rem = t / Dd; int i = (int)(rem % Mc); int b = (int)(rem / Mc);
        float p = dec[((size_t)b * Gc + i) * Dd + d];
        float a = fabsf(p - tgt[t]);
        v = (a < 2.f) ? 0.25f * a * a : (a - 1.f);
    }
    sh[threadIdx.x] = v;
    __syncthreads();
    for (int s = 128; s > 0; s >>= 1) {
        if (threadIdx.x < s) sh[threadIdx.x] += sh[threadIdx.x + s];
        __syncthreads();
    }
    if (threadIdx.x == 0) atomicAdd(&acc[slot], sh[0]);
}

__global__ void mae_finalize_kernel(const float* __restrict__ acc, float* __restrict__ out) {
    const float inv = 1.f / (float)(Bc * Mc * Dd);
    *out = 0.5f * (acc[0] * inv) + 0.5f * (acc[1] * inv);
}

// ==================== host orchestration ====================
extern "C" void kernel_launch(void* const* d_in, const int* in_sizes, int n_in,
                              void* d_out, int out_size, void* d_ws, size_t ws_size,
                              hipStream_t stream) {
    (void)in_sizes; (void)n_in; (void)out_size;
    const void* pos_src = d_in[0];
    const void* pos_tgt = d_in[1];
    const int* vis_s = (const int*)d_in[2];
    const int* msk_s = (const int*)d_in[3];
    const int* vis_t = (const int*)d_in[4];
    const int* msk_t = (const int*)d_in[5];
    const void *tw1 = d_in[6], *tb1 = d_in[7], *tw2 = d_in[8], *tb2 = d_in[9];
    const void *tw3 = d_in[10], *tb3 = d_in[11], *tw4 = d_in[12], *tb4 = d_in[13];
    const void *mtok = d_in[14];
    const void *cxw = d_in[15], *cff1 = d_in[16], *cff2 = d_in[17];
    const void *esa = d_in[18], *eca = d_in[19], *eff1 = d_in[20], *eff2 = d_in[21];
    const void *dca = d_in[22], *dff1 = d_in[23], *dff2 = d_in[24];
    const void *uw1 = d_in[25], *ub1 = d_in[26], *uw2 = d_in[27], *ub2 = d_in[28];
    float* out = (float*)d_out;
    char* ws = (char*)d_ws;

    const size_t DD = (size_t)Dd * Dd;
    const size_t DF = (size_t)Dd * FFf;
    const size_t GD = (size_t)Gc * Dd;        // 49152
    const size_t PH = (size_t)Bc * Nn * 3;    // posf half (elements)

    // ---- bf16 transposed weight arena (element offsets) ----
    size_t wo = 0;
    auto walloc = [&](size_t e) -> size_t { size_t r = wo; wo += e; return r; };
    const size_t wt_t1 = walloc((size_t)128 * 64);
    const size_t wt_t2 = walloc((size_t)256 * 128);
    const size_t wt_t3 = walloc((size_t)512 * 512);
    const size_t wt_t4 = walloc((size_t)384 * 512);
    const size_t wt_cx = walloc((size_t)8 * DD);
    const size_t wt_cf1 = walloc(DF);
    const size_t wt_cf2 = walloc(DF);
    const size_t wt_es = walloc((size_t)16 * DD);
    const size_t wt_ec = walloc((size_t)16 * DD);
    const size_t wt_ef1 = walloc((size_t)4 * DF);
    const size_t wt_ef2 = walloc((size_t)4 * DF);
    const size_t wt_dc = walloc((size_t)8 * DD);
    const size_t wt_df1 = walloc((size_t)2 * DF);
    const size_t wt_df2 = walloc((size_t)2 * DF);
    const size_t wt_u1 = walloc((size_t)384 * 448);
    const size_t wt_u2 = walloc((size_t)384 * 384);

    // ---- persistent workspace (all 16-batch buffers: batches 0..7 = src, 8..15 = tgt) ----
    size_t o = 0;
    auto alloc = [&](size_t bytes) -> size_t { size_t r = o; o += (bytes + 255) & ~(size_t)255; return r; };
    const size_t flagO = alloc(256);
    const size_t wtO = alloc(wo * 2);
    const size_t bsO = alloc(2048 * 4);
    const size_t mtokO = alloc(Dd * 4);
    const size_t posfO = alloc(2 * PH * 4);                    // [16][Nn][3] f32
    const size_t centO = alloc((size_t)16 * Gc * 3 * 4);       // [16][Gc][3] f32
    const size_t cpeO  = alloc((size_t)16 * GD * 4);           // [16][Gc][Dd] f32
    const size_t tokO  = alloc((size_t)16 * GD * 4);           // [16][Gc][Dd] f32
    const size_t vtokO = alloc((size_t)16 * Vc * Dd * 4);      // [16][Vc][Dd] f32
    const size_t lnSO = alloc((size_t)16 * GD * 2);            // bf16 scratch (<=2048 rows)
    const size_t lnTO = alloc((size_t)16 * GD * 2);
    const size_t lnmO = alloc((size_t)16 * GD * 2);
    const size_t qbO  = alloc((size_t)16 * GD * 2);            // bf16 q (decoder ca)
    const size_t qkvbO = alloc((size_t)16 * Gc * 1152 * 4);    // fp32 (enc) / bf16 (dec) qkv
    const size_t kvbO  = alloc((size_t)16 * Gc * 768 * 2);     // bf16 decoder ca kv
    const size_t kvd0O = alloc((size_t)16 * Gc * 768 * 2);     // bf16 dense kv l0
    const size_t kvd1O = alloc((size_t)16 * Gc * 768 * 2);     // bf16 dense kv l1
    const size_t cxO   = alloc((size_t)16 * GD * 2);           // bf16 attn ctx out
    const size_t decxO = alloc((size_t)16 * GD * 4);           // f32 decoder state
    const size_t membO = alloc((size_t)16 * GD * 4);           // f32
    const size_t relbO = alloc((size_t)16 * Gc * Kc * 64 * 2); // bf16
    const size_t tbsO = alloc((size_t)Bc * Mc * Dd * 4), tbtO = alloc((size_t)Bc * Mc * Dd * 4);
    const size_t mfullO = alloc((size_t)16 * Gc * Gc);
    const size_t mvisO  = alloc((size_t)16 * Vc * Vc);
    const size_t nidxO = alloc((size_t)16 * Gc * Kc * 4);
    const size_t idx3O = alloc((size_t)16 * Nn * 3 * 4), w3O = alloc((size_t)16 * Nn * 3 * 4);
    const size_t vis3O = alloc((size_t)16 * Vc * 3 * 4);
    const size_t accbO = alloc(64);

    // ---- scratch arena ----
    const size_t arenaO = o;
    const size_t arena_bytes = (ws_size > arenaO) ? (ws_size - arenaO) : 0;
    // dense rows/pass: Acb 896 + Xc 1536 + Lc 768 + T1 1536 + QT 768 + T2 768 + Hh 3072 = 9344 B/row
    int RP = 128;
    {
        const int cands[10] = {65536, 32768, 16384, 8192, 4096, 2048, 1024, 512, 256, 128};
        for (int ci = 0; ci < 10; ci++) {
            if ((size_t)cands[ci] * 9344 + 8192 <= arena_bytes) { RP = cands[ci]; break; }
        }
    }
    size_t ao = arenaO;
    auto aalloc = [&](size_t bytes) -> size_t { size_t r = ao; ao += (bytes + 255) & ~(size_t)255; return r; };
    const size_t AcbO = aalloc((size_t)RP*448*2);
    const size_t XcO  = aalloc((size_t)RP*384*4);
    const size_t LcO  = aalloc((size_t)RP*384*2);
    const size_t T1O  = aalloc((size_t)RP*384*4);
    const size_t QTO  = aalloc((size_t)RP*384*2);
    const size_t T2O  = aalloc((size_t)RP*384*2);
    const size_t HhO  = aalloc((size_t)RP*1536*2);
    // tokenize groups/pass: 70128 B per group
    int TC = (int)(arena_bytes / 70200);
    TC &= ~7; if (TC > 2048) TC = 2048; if (TC < 8) TC = 8;
    size_t to = arenaO;
    auto talloc = [&](size_t bytes) -> size_t { size_t r = to; to += (bytes + 255) & ~(size_t)255; return r; };
    const size_t tk1O = talloc((size_t)TC*16*128*2);
    const size_t tk2O = talloc((size_t)TC*16*256*2);
    const size_t tgmO = talloc((size_t)TC*256*2);
    const size_t tcatO = talloc((size_t)TC*16*512*2);
    const size_t thbO = talloc((size_t)TC*16*512*2);
    const size_t t4oO = talloc((size_t)TC*16*384*4);

    auto F = [&](size_t off) -> float* { return (float*)(ws + off); };
    auto I = [&](size_t off) -> int* { return (int*)(ws + off); };
    auto U = [&](size_t off) -> unsigned char* { return (unsigned char*)(ws + off); };
    auto Bf = [&](size_t off) -> __bf16* { return (__bf16*)(ws + off); };
    auto ew = [](size_t n) -> dim3 { return dim3((unsigned)((n + 255) / 256)); };
    const int* flag = I(flagO);
    __bf16* WT = Bf(wtO);
    float* BF = F(bsO);
    const int b_t1 = 0, b_t2 = 128, b_t3 = 384, b_t4 = 896, b_u1 = 1280, b_u2 = 1664;

    auto gemm = [&](const __bf16* A, const __bf16* W, const float* bias, const float* res, void* C,
                    int M, int Ncol, int Kk, int relu, int obf) {
        dim3 g((unsigned)(Ncol / 128), (unsigned)(M / 128));
        gemm_kernel<<<g, 256, 0, stream>>>(A, W, bias, res, C, M, Ncol, Kk, relu, obf);
    };
    auto ln = [&](const float* X, __bf16* Y, int R) {
        ln_kernel<<<dim3((R + 3) / 4), 256, 0, stream>>>(X, Y, R);
    };
    auto attn_old = [&](const float* Qp, const float* Kp, const float* Vp, const unsigned char* mask,
                        __bf16* Op, int Sq, int Sk, int nb, int xorv, int ldq, int ldkv) {
        attn_kernel<<<dim3(Sq, NHh, nb), 64, 0, stream>>>(Qp, Kp, Vp, mask, Op, Sq, Sk, xorv, ldq, ldkv);
    };
    auto attn_mfma = [&](const __bf16* Qp, const __bf16* Kp, const __bf16* Vp, __bf16* Op,
                         int ldq, int ldkv, int ldo, int rpb, int nb, int b0) {
        attn_mfma_kernel<<<dim3(rpb/128, NHh, nb), 256, 0, stream>>>(Qp, Kp, Vp, Op, ldq, ldkv, ldo, rpb, b0);
    };
    __bf16* ctxb = Bf(cxO);

    auto ffn = [&](float* x, const __bf16* w1t, const __bf16* w2t, int R) {
        ln(x, Bf(lnSO), R);
        for (int r0 = 0; r0 < R; r0 += RP) {
            int rc = (R - r0 < RP) ? (R - r0) : RP;
            gemm(Bf(lnSO) + (size_t)r0*Dd, w1t, nullptr, nullptr, Bf(HhO), rc, FFf, Dd, 1, 1);
            gemm(Bf(HhO), w2t, nullptr, x + (size_t)r0*Dd, x + (size_t)r0*Dd, rc, Dd, FFf, 0, 0);
        }
    };
    // cross-encoder over 16 batches; ca pairs batch bq with bq^8
    auto cross_enc = [&](float* x, const unsigned char* mask, int S) {
        const int R = 16 * S;
        ln(x, Bf(lnSO), R);
        gemm(Bf(lnSO), WT + wt_cx, nullptr, nullptr, F(qkvbO), R, 1152, Dd, 0, 0);
        attn_old(F(qkvbO), F(qkvbO) + 384, F(qkvbO) + 768, mask, ctxb, S, S, 16, 0, 1152, 1152);
        gemm(ctxb, WT + wt_cx + 3*DD, nullptr, x, x, R, Dd, Dd, 0, 0);
        ln(x, Bf(lnSO), R);
        gemm(Bf(lnSO), WT + wt_cx + 4*DD, nullptr, nullptr, F(qkvbO), R, 1152, Dd, 0, 0);
        attn_old(F(qkvbO), F(qkvbO) + 384, F(qkvbO) + 768, nullptr, ctxb, S, S, 16, 8, 1152, 1152);
        gemm(ctxb, WT + wt_cx + 7*DD, nullptr, x, x, R, Dd, Dd, 0, 0);
        ffn(x, WT + wt_cf1, WT + wt_cf2, R);
    };
    // batched 4-layer decoder: x [16][Gc][Dd]; mem LN in lnm (bf16, 2048 rows)
    auto decoder4 = [&](float* x) {
        for (int l = 0; l < 4; l++) {
            ln(x, Bf(lnTO), 2048);
            gemm(Bf(lnTO), WT + wt_es + (size_t)l*4*DD, nullptr, nullptr, Bf(qkvbO), 2048, 1152, Dd, 0, 1);
            attn_mfma(Bf(qkvbO), Bf(qkvbO) + 384, Bf(qkvbO) + 768, ctxb, 1152, 1152, Dd, 128, 16, 0);
            gemm(ctxb, WT + wt_es + (size_t)l*4*DD + 3*DD, nullptr, x, x, 2048, Dd, Dd, 0, 0);
            ln(x, Bf(lnTO), 2048);
            gemm(Bf(lnTO), WT + wt_ec + (size_t)l*4*DD, nullptr, nullptr, Bf(qbO), 2048, Dd, Dd, 0, 1);
            gemm(Bf(lnmO), WT + wt_ec + (size_t)l*4*DD + DD, nullptr, nullptr, Bf(kvbO), 2048, 768, Dd, 0, 1);
            attn_mfma(Bf(qbO), Bf(kvbO), Bf(kvbO) + 384, ctxb, Dd, 768, Dd, 128, 16, 0);
            gemm(ctxb, WT + wt_ec + (size_t)l*4*DD + 3*DD, nullptr, x, x, 2048, Dd, Dd, 0, 0);
            ffn(x, WT + wt_ef1 + (size_t)l*DF, WT + wt_ef2 + (size_t)l*DF, 2048);
        }
    };

    // ---- pipeline ----
    detect_kernel<<<dim3(1), 256, 0, stream>>>((const unsigned int*)pos_src, I(flagO));
    cvtf_kernel<<<ew(PH), 256, 0, stream>>>(pos_src, F(posfO), PH, flag);
    cvtf_kernel<<<ew(PH), 256, 0, stream>>>(pos_tgt, F(posfO) + PH, PH, flag);
    cvtf_kernel<<<dim3(2), 256, 0, stream>>>(mtok, F(mtokO), (size_t)Dd, flag);

    auto wtr = [&](const void* src, size_t dstOff, int K, int N, int Kpad, int cnt) {
        wtr_kernel<<<ew((size_t)cnt * N * Kpad), 256, 0, stream>>>(src, WT + dstOff, K, N, Kpad, cnt, flag);
    };
    wtr(tw1, wt_t1, 3, 128, 64, 1);
    wtr(tw2, wt_t2, 128, 256, 128, 1);
    wtr(tw3, wt_t3, 512, 512, 512, 1);
    wtr(tw4, wt_t4, 512, 384, 512, 1);
    wtr(cxw, wt_cx, 384, 384, 384, 8);
    wtr(cff1, wt_cf1, 384, 1536, 384, 1);
    wtr(cff2, wt_cf2, 1536, 384, 1536, 1);
    wtr(esa, wt_es, 384, 384, 384, 16);
    wtr(eca, wt_ec, 384, 384, 384, 16);
    wtr(eff1, wt_ef1, 384, 1536, 384, 4);
    wtr(eff2, wt_ef2, 1536, 384, 1536, 4);
    wtr(dca, wt_dc, 384, 384, 384, 8);
    wtr(dff1, wt_df1, 384, 1536, 384, 2);
    wtr(dff2, wt_df2, 1536, 384, 1536, 2);
    wtr(uw1, wt_u1, 387, 384, 448, 1);
    wtr(uw2, wt_u2, 384, 384, 384, 1);
    cvtf_kernel<<<ew(128), 256, 0, stream>>>(tb1, BF + b_t1, 128, flag);
    cvtf_kernel<<<ew(256), 256, 0, stream>>>(tb2, BF + b_t2, 256, flag);
    cvtf_kernel<<<ew(512), 256, 0, stream>>>(tb3, BF + b_t3, 512, flag);
    cvtf_kernel<<<ew(384), 256, 0, stream>>>(tb4, BF + b_t4, 384, flag);
    cvtf_kernel<<<ew(384), 256, 0, stream>>>(ub1, BF + b_u1, 384, flag);
    cvtf_kernel<<<ew(384), 256, 0, stream>>>(ub2, BF + b_u2, 384, flag);

    fps_kernel<<<dim3(16), 256, 0, stream>>>(F(posfO), F(posfO) + PH, F(centO), F(centO) + (size_t)Bc*Gc*3);

    // tokenize both sides (16 batches)
    knn16_kernel<<<dim3(16*Gc), 64, 0, stream>>>(F(centO), F(posfO), I(nidxO), Gc, Nn);
    rel_kernel<<<ew((size_t)16*Gc*Kc*64), 256, 0, stream>>>(F(posfO), F(centO), I(nidxO), Bf(relbO), 16);
    for (int g0 = 0; g0 < 16*Gc; g0 += TC) {
        const int gc = (16*Gc - g0 < TC) ? (16*Gc - g0) : TC;
        const int RC = gc * Kc;
        gemm(Bf(relbO) + (size_t)g0*Kc*64, WT + wt_t1, BF + b_t1, nullptr, Bf(tk1O), RC, 128, 64, 1, 1);
        gemm(Bf(tk1O), WT + wt_t2, BF + b_t2, nullptr, Bf(tk2O), RC, 256, 128, 0, 1);
        maxk_bf_kernel<<<ew((size_t)gc*256), 256, 0, stream>>>(Bf(tk2O), Bf(tgmO), gc, 256);
        concat_gf_kernel<<<ew((size_t)RC*512), 256, 0, stream>>>(Bf(tgmO), Bf(tk2O), Bf(tcatO), gc);
        gemm(Bf(tcatO), WT + wt_t3, BF + b_t3, nullptr, Bf(thbO), RC, 512, 512, 1, 1);
        gemm(Bf(thbO), WT + wt_t4, BF + b_t4, nullptr, F(t4oO), RC, Dd, 512, 0, 0);
        maxk_f32_kernel<<<ew((size_t)gc*Dd), 256, 0, stream>>>(F(t4oO), F(tokO) + (size_t)g0*Dd, gc, Dd);
    }

    pe_kernel<<<ew((size_t)16*GD), 256, 0, stream>>>(F(cpeO), nullptr, F(centO), (size_t)16*GD);

    gather_rows_kernel<<<ew((size_t)Bc*Vc*Dd), 256, 0, stream>>>(F(tokO), vis_s, F(vtokO), Vc, Dd, Gc);
    gather_rows_kernel<<<ew((size_t)Bc*Vc*Dd), 256, 0, stream>>>(F(tokO) + 8*GD, vis_t, F(vtokO) + (size_t)8*Vc*Dd, Vc, Dd, Gc);
    gather_rows_kernel<<<ew((size_t)Bc*Vc*3), 256, 0, stream>>>(F(centO), vis_s, F(vis3O), Vc, 3, Gc);
    gather_rows_kernel<<<ew((size_t)Bc*Vc*3), 256, 0, stream>>>(F(centO) + (size_t)Bc*Gc*3, vis_t, F(vis3O) + (size_t)8*Vc*3, Vc, 3, Gc);

    zero_kernel<<<ew((size_t)16*Gc*Gc), 256, 0, stream>>>(U(mfullO), (size_t)16*Gc*Gc);
    knn16_kernel<<<dim3(16*Gc), 64, 0, stream>>>(F(centO), F(centO), I(nidxO), Gc, Gc);
    scatter_mask_kernel<<<ew((size_t)16*Gc*Kc), 256, 0, stream>>>(I(nidxO), U(mfullO), Gc, Gc, 16);
    zero_kernel<<<ew((size_t)16*Vc*Vc), 256, 0, stream>>>(U(mvisO), (size_t)16*Vc*Vc);
    knn16_kernel<<<dim3(16*Vc), 64, 0, stream>>>(F(vis3O), F(vis3O), I(nidxO), Vc, Vc);
    scatter_mask_kernel<<<ew((size_t)16*Vc*Kc), 256, 0, stream>>>(I(nidxO), U(mvisO), Vc, Vc, 16);

    cross_enc(F(vtokO), U(mvisO), Vc);
    cross_enc(F(tokO), U(mfullO), Gc);

    dec_init_kernel<<<ew((size_t)Bc*GD), 256, 0, stream>>>(F(mtokO), F(vtokO), F(cpeO), msk_s, vis_s, F(decxO));
    dec_init_kernel<<<ew((size_t)Bc*GD), 256, 0, stream>>>(F(mtokO), F(vtokO) + (size_t)8*Vc*Dd, F(cpeO) + 8*GD, msk_t, vis_t, F(decxO) + 8*GD);
    // decoder memory: src-decoder attends tgt tokens, tgt-decoder attends src tokens
    add_kernel<<<ew((size_t)8*GD), 256, 0, stream>>>(F(tokO) + 8*GD, F(cpeO) + 8*GD, F(membO), (size_t)8*GD);
    add_kernel<<<ew((size_t)8*GD), 256, 0, stream>>>(F(tokO), F(cpeO), F(membO) + 8*GD, (size_t)8*GD);
    ln(F(membO), Bf(lnmO), 2048);
    decoder4(F(decxO));

    zero_kernel<<<dim3(1), 256, 0, stream>>>(U(accbO), 64);
    gather_rows_kernel<<<ew((size_t)Bc*Mc*Dd), 256, 0, stream>>>(F(tokO), msk_s, F(tbsO), Mc, Dd, Gc);
    gather_rows_kernel<<<ew((size_t)Bc*Mc*Dd), 256, 0, stream>>>(F(tokO) + 8*GD, msk_t, F(tbtO), Mc, Dd, Gc);
    sl1_kernel<<<ew((size_t)Bc*Mc*Dd), 256, 0, stream>>>(F(tbsO), F(decxO), F(accbO), 0);
    sl1_kernel<<<ew((size_t)Bc*Mc*Dd), 256, 0, stream>>>(F(tbtO), F(decxO) + 8*GD, F(accbO), 1);

    // ---- dense path, both sides fused (65536 rows) ----
    knn3_kernel<<<dim3(16*Nn), 64, 0, stream>>>(F(posfO), F(centO), I(idx3O), F(w3O));
    add_kernel<<<ew((size_t)16*GD), 256, 0, stream>>>(F(tokO), F(cpeO), F(membO), (size_t)16*GD);
    ln(F(membO), Bf(lnmO), 2048);
    gemm(Bf(lnmO), WT + wt_dc + 0*4*DD + DD, nullptr, nullptr, Bf(kvd0O), 2048, 768, Dd, 0, 1);
    gemm(Bf(lnmO), WT + wt_dc + 1*4*DD + DD, nullptr, nullptr, Bf(kvd1O), 2048, 768, Dd, 0, 1);
    const size_t kvdo[2] = {kvd0O, kvd1O};
    const int RT = 16 * Nn;
    for (int r0 = 0; r0 < RT; r0 += RP) {
        const int rpb = (RP < Nn) ? RP : Nn;
        const int nb = (RP < Nn) ? 1 : RP / Nn;
        const int b0 = r0 / Nn;
        interp_kernel<<<ew((size_t)RP*448), 256, 0, stream>>>(F(tokO), F(posfO), I(idx3O), F(w3O), Bf(AcbO), r0, RP);
        gemm(Bf(AcbO), WT + wt_u1, BF + b_u1, nullptr, Bf(LcO), RP, Dd, 448, 1, 1);
        gemm(Bf(LcO), WT + wt_u2, BF + b_u2, nullptr, F(T1O), RP, Dd, Dd, 1, 0);
        pe_kernel<<<ew((size_t)RP*Dd), 256, 0, stream>>>(F(XcO), F(T1O), F(posfO) + (size_t)r0*3, (size_t)RP*Dd);
        for (int l = 0; l < 2; l++) {
            ln(F(XcO), Bf(LcO), RP);
            gemm(Bf(LcO), WT + wt_dc + (size_t)l*4*DD, nullptr, nullptr, Bf(QTO), RP, Dd, Dd, 0, 1);
            attn_mfma(Bf(QTO), Bf(kvdo[l]), Bf(kvdo[l]) + 384, Bf(T2O), Dd, 768, Dd, rpb, nb, b0);
            gemm(Bf(T2O), WT + wt_dc + (size_t)l*4*DD + 3*DD, nullptr, F(XcO), F(XcO), RP, Dd, Dd, 0, 0);
            ln(F(XcO), Bf(LcO), RP);
            gemm(Bf(LcO), WT + wt_df1 + (size_t)l*DF, nullptr, nullptr, Bf(HhO), RP, FFf, Dd, 1, 1);
            if (l == 1)
                gemm(Bf(HhO), WT + wt_df2 + DF, nullptr, F(XcO), out + (size_t)r0*Dd, RP, Dd, FFf, 0, 0);
            else
                gemm(Bf(HhO), WT + wt_df2, nullptr, F(XcO), F(XcO), RP, Dd, FFf, 0, 0);
        }
    }

    mae_finalize_kernel<<<dim3(1), 1, 0, stream>>>(F(accbO), out + (size_t)2*Bc*Nn*Dd);
}

// Round 4
// 3371.769 us; speedup vs baseline: 8.6098x; 1.0683x over previous
//
#include <hip/hip_runtime.h>
#include <hip/hip_bf16.h>
#include <math.h>

using bf16 = __hip_bfloat16;

#define DI static __device__ __forceinline__

constexpr int Bc = 8, Nn = 4096, Gc = 128, Kc = 16, Vc = 64, Mc = 64;
constexpr int Dd = 384, NHh = 8, DHh = 48, FFf = 1536;

typedef __bf16 bf8v __attribute__((ext_vector_type(8)));
typedef float f4v __attribute__((ext_vector_type(4)));

DI float b2f(bf16 h) { return __bfloat162float(h); }
DI __bf16 f2b(float f) { return (__bf16)f; }

// async global->LDS, 16B per lane; LDS dest must be wave-uniform base (+lane*16 implicit)
DI void gld16(const void* g, void* l) {
    __builtin_amdgcn_global_load_lds((const __attribute__((address_space(1))) void*)g,
                                     (__attribute__((address_space(3))) void*)l, 16, 0, 0);
}

// -------------------- dtype autodetect (inputs) --------------------
__global__ __launch_bounds__(256) void detect_kernel(const unsigned int* __restrict__ w, int* __restrict__ flag) {
    __shared__ int sh[256];
    int cnt = 0;
    for (int i = threadIdx.x; i < 16384; i += 256) {
        unsigned int lo = w[i] & 0xffffu;
        int e = (int)((lo >> 7) & 0xffu);
        if (e < 100 || e > 140) cnt++;
    }
    sh[threadIdx.x] = cnt;
    __syncthreads();
    for (int s = 128; s > 0; s >>= 1) {
        if (threadIdx.x < s) sh[threadIdx.x] += sh[threadIdx.x + s];
        __syncthreads();
    }
    if (threadIdx.x == 0) flag[0] = (sh[0] < 2048) ? 1 : 0;
}

DI float ldf(const void* p, size_t i, int isbf) {
    return isbf ? b2f(((const bf16*)p)[i]) : ((const float*)p)[i];
}

__global__ void cvtf_kernel(const void* __restrict__ src, float* __restrict__ dst, size_t n,
                            const int* __restrict__ flag) {
    size_t t = (size_t)blockIdx.x * 256 + threadIdx.x;
    if (t < n) dst[t] = ldf(src, t, flag[0]);
}

// weight transpose+round: src [cnt][K][N] -> dst [cnt][N][Kpad] bf16, zero-padded K
__global__ void wtr_kernel(const void* __restrict__ src, __bf16* __restrict__ dst,
                           int K, int N, int Kpad, int cnt, const int* __restrict__ flag) {
    size_t t = (size_t)blockIdx.x * 256 + threadIdx.x;
    size_t total = (size_t)cnt * N * Kpad;
    if (t >= total) return;
    int k = (int)(t % Kpad);
    size_t rem = t / Kpad;
    int n = (int)(rem % N);
    int mat = (int)(rem / N);
    float v = (k < K) ? ldf(src, ((size_t)mat * K + k) * N + n, flag[0]) : 0.f;
    dst[t] = f2b(v);
}

__global__ void zero_kernel(unsigned char* __restrict__ p, size_t n) {
    size_t t = (size_t)blockIdx.x * 256 + threadIdx.x;
    if (t < n) p[t] = 0;
}

__global__ void add_kernel(const float* __restrict__ a, const float* __restrict__ b,
                           float* __restrict__ o, size_t n) {
    size_t t = (size_t)blockIdx.x * 256 + threadIdx.x;
    if (t < n) o[t] = a[t] + b[t];
}

// -------------------- FPS (both sides in one dispatch: 16 blocks, 512 thr) --------------------
__global__ __launch_bounds__(512) void fps_kernel(const float* __restrict__ pos_a, const float* __restrict__ pos_b,
                                                  float* __restrict__ cent_a, float* __restrict__ cent_b) {
    __shared__ float px[Nn], py[Nn], pz[Nn];
    __shared__ float wv[8];
    __shared__ int wi[8];
    __shared__ int chosen;
    int side = blockIdx.x >> 3, b = blockIdx.x & 7, tid = threadIdx.x;
    const float* pos = side ? pos_b : pos_a;
    float* cent = side ? cent_b : cent_a;
    const float* p = pos + (size_t)b * Nn * 3;
    for (int i = tid; i < Nn; i += 512) { px[i] = p[3*i]; py[i] = p[3*i+1]; pz[i] = p[3*i+2]; }
    __syncthreads();
    float cx = px[0], cy = py[0], cz = pz[0];
    if (tid == 0) { float* c0 = cent + (size_t)b * Gc * 3; c0[0] = cx; c0[1] = cy; c0[2] = cz; }
    float mind[8];
#pragma unroll
    for (int j = 0; j < 8; j++) {
        int i = tid + 512 * j;
        float dx = px[i]-cx, dy = py[i]-cy, dz = pz[i]-cz;
        mind[j] = __fadd_rn(__fadd_rn(__fmul_rn(dx,dx), __fmul_rn(dy,dy)), __fmul_rn(dz,dz));
    }
    for (int s = 1; s < Gc; s++) {
        float bv = -1.f; int bi = 0;
#pragma unroll
        for (int j = 0; j < 8; j++) { int i = tid + 512*j; if (mind[j] > bv) { bv = mind[j]; bi = i; } }
        for (int o = 32; o > 0; o >>= 1) {
            float v2 = __shfl_down(bv, o, 64); int i2 = __shfl_down(bi, o, 64);
            if (v2 > bv || (v2 == bv && i2 < bi)) { bv = v2; bi = i2; }
        }
        if ((tid & 63) == 0) { wv[tid >> 6] = bv; wi[tid >> 6] = bi; }
        __syncthreads();
        if (tid == 0) {
            float fv = wv[0]; int fi = wi[0];
            for (int k = 1; k < 8; k++)
                if (wv[k] > fv || (wv[k] == fv && wi[k] < fi)) { fv = wv[k]; fi = wi[k]; }
            chosen = fi;
            float* cs = cent + ((size_t)b * Gc + s) * 3;
            cs[0] = px[fi]; cs[1] = py[fi]; cs[2] = pz[fi];
        }
        __syncthreads();
        int ci = chosen;
        float qx = px[ci], qy = py[ci], qz = pz[ci];
#pragma unroll
        for (int j = 0; j < 8; j++) {
            int i = tid + 512 * j;
            float dx = px[i]-qx, dy = py[i]-qy, dz = pz[i]-qz;
            float d = __fadd_rn(__fadd_rn(__fmul_rn(dx,dx), __fmul_rn(dy,dy)), __fmul_rn(dz,dz));
            if (d < mind[j]) mind[j] = d;
        }
    }
}

// -------------------- brute-force KNN (k=16), tie -> lower index --------------------
__global__ __launch_bounds__(64) void knn16_kernel(const float* __restrict__ q, const float* __restrict__ r,
                                                   int* __restrict__ nidx, int NQ, int NR) {
    __shared__ float dist[4096];
    int blk = blockIdx.x; int b = blk / NQ, qi = blk % NQ;
    int lane = threadIdx.x;
    const float* qp = q + ((size_t)b * NQ + qi) * 3;
    float qx = qp[0], qy = qp[1], qz = qp[2];
    float qq = __fadd_rn(__fadd_rn(__fmul_rn(qx,qx), __fmul_rn(qy,qy)), __fmul_rn(qz,qz));
    const float* rp = r + (size_t)b * NR * 3;
    for (int i = lane; i < NR; i += 64) {
        float rx = rp[3*i], ry = rp[3*i+1], rz = rp[3*i+2];
        float rr = __fadd_rn(__fadd_rn(__fmul_rn(rx,rx), __fmul_rn(ry,ry)), __fmul_rn(rz,rz));
        float dot = __fadd_rn(__fadd_rn(__fmul_rn(qx,rx), __fmul_rn(qy,ry)), __fmul_rn(qz,rz));
        dist[i] = __fadd_rn(__fadd_rn(qq, rr), -2.f * dot);
    }
    __syncthreads();
    int* out = nidx + ((size_t)b * NQ + qi) * Kc;
    for (int sel = 0; sel < Kc; ++sel) {
        float bv = INFINITY; int bi = 0;
        bool has = false;
        for (int i = lane; i < NR; i += 64) {
            float v = dist[i];
            if (!has || v < bv) { bv = v; bi = i; has = true; }
        }
        for (int o = 32; o > 0; o >>= 1) {
            float v2 = __shfl_xor(bv, o, 64); int i2 = __shfl_xor(bi, o, 64);
            if (v2 < bv || (v2 == bv && i2 < bi)) { bv = v2; bi = i2; }
        }
        if (lane == 0) { out[sel] = bi; dist[bi] = INFINITY; }
        __syncthreads();
    }
}

// -------------------- top-3 centers + interp weights --------------------
__global__ __launch_bounds__(64) void knn3_kernel(const float* __restrict__ pos, const float* __restrict__ cent,
                                                  int* __restrict__ idx3, float* __restrict__ w3) {
    int bn = blockIdx.x; int b = bn / Nn;
    int lane = threadIdx.x;
    const float* p = pos + (size_t)bn * 3;
    float px = p[0], py = p[1], pz = p[2];
    float pp = __fadd_rn(__fadd_rn(__fmul_rn(px,px), __fmul_rn(py,py)), __fmul_rn(pz,pz));
    float dv[2]; int di[2];
#pragma unroll
    for (int c = 0; c < 2; c++) {
        int g = lane + 64 * c;
        const float* cp = cent + ((size_t)b * Gc + g) * 3;
        float cx = cp[0], cy = cp[1], cz = cp[2];
        float cc = __fadd_rn(__fadd_rn(__fmul_rn(cx,cx), __fmul_rn(cy,cy)), __fmul_rn(cz,cz));
        float dot = __fadd_rn(__fadd_rn(__fmul_rn(px,cx), __fmul_rn(py,cy)), __fmul_rn(pz,cz));
        dv[c] = __fadd_rn(__fadd_rn(pp, cc), -2.f * dot);
        di[c] = g;
    }
    float od[3]; int oi[3];
#pragma unroll
    for (int r = 0; r < 3; r++) {
        float bv; int bi;
        if (dv[1] < dv[0]) { bv = dv[1]; bi = di[1]; } else { bv = dv[0]; bi = di[0]; }
        for (int o = 32; o > 0; o >>= 1) {
            float v2 = __shfl_xor(bv, o, 64); int i2 = __shfl_xor(bi, o, 64);
            if (v2 < bv || (v2 == bv && i2 < bi)) { bv = v2; bi = i2; }
        }
        od[r] = bv; oi[r] = bi;
        if (di[0] == bi) dv[0] = INFINITY;
        if (di[1] == bi) dv[1] = INFINITY;
    }
    if (lane == 0) {
        float w[3], s = 0.f;
        for (int r = 0; r < 3; r++) { w[r] = 1.f / (fmaxf(od[r], 0.f) + 1e-8f); s += w[r]; }
        for (int r = 0; r < 3; r++) { idx3[(size_t)bn*3 + r] = oi[r]; w3[(size_t)bn*3 + r] = w[r] / s; }
    }
}

// interp for rows [r0, r0+CH): out local (CH,448) bf16, cols 387..447 zero
__global__ void interp_kernel(const float* __restrict__ feats, const float* __restrict__ pos,
                              const int* __restrict__ idx3, const float* __restrict__ w3,
                              __bf16* __restrict__ x448, int r0, int CH) {
    size_t t = (size_t)blockIdx.x * 256 + threadIdx.x;
    size_t total = (size_t)CH * 448;
    if (t >= total) return;
    int c = (int)(t % 448); size_t i = t / 448;
    size_t r = (size_t)r0 + i; int b = (int)(r / Nn);
    float o = 0.f;
    if (c < Dd) {
        for (int k = 0; k < 3; k++)
            o += w3[r*3 + k] * feats[((size_t)b * Gc + idx3[r*3 + k]) * Dd + c];
    } else if (c < 387) {
        o = pos[r*3 + (c - Dd)];
    }
    x448[t] = f2b(o);
}

// -------------------- tokenize helpers --------------------
__global__ void rel_kernel(const float* __restrict__ pos, const float* __restrict__ cent,
                           const int* __restrict__ nidx, __bf16* __restrict__ rel, int nb) {
    int t = blockIdx.x * 256 + threadIdx.x;
    if (t >= nb * Gc * Kc * 64) return;
    int c = t & 63; int row = t >> 6;
    float v = 0.f;
    if (c < 3) {
        int g = (row / Kc) % Gc; int b = row / (Kc * Gc);
        int pi = nidx[row];
        v = pos[((size_t)b * Nn + pi) * 3 + c] - cent[((size_t)b * Gc + g) * 3 + c];
    }
    rel[t] = f2b(v);
}

__global__ void maxk_f32_kernel(const float* __restrict__ in, float* __restrict__ out, int BG, int C) {
    int t = blockIdx.x * 256 + threadIdx.x;
    if (t >= BG * C) return;
    int c = t % C; int bg = t / C;
    const float* p = in + (size_t)bg * Kc * C + c;
    float m = -INFINITY;
    for (int k = 0; k < Kc; k++) m = fmaxf(m, p[(size_t)k * C]);
    out[t] = m;
}

__global__ void maxk_bf_kernel(const __bf16* __restrict__ in, __bf16* __restrict__ out, int BG, int C) {
    int t = blockIdx.x * 256 + threadIdx.x;
    if (t >= BG * C) return;
    int c = t % C; int bg = t / C;
    const __bf16* p = in + (size_t)bg * Kc * C + c;
    float m = -INFINITY;
    for (int k = 0; k < Kc; k++) m = fmaxf(m, (float)p[(size_t)k * C]);
    out[t] = f2b(m);
}

__global__ void concat_gf_kernel(const __bf16* __restrict__ g, const __bf16* __restrict__ f,
                                 __bf16* __restrict__ cat, int BG) {
    size_t t = (size_t)blockIdx.x * 256 + threadIdx.x;
    size_t total = (size_t)BG * Kc * 512;
    if (t >= total) return;
    int c = (int)(t % 512); size_t bgk = t / 512; size_t bg = bgk / Kc;
    cat[t] = (c < 256) ? g[bg * 256 + c] : f[bgk * 256 + (c - 256)];
}

// -------------------- gather / masks --------------------
__global__ void gather_rows_kernel(const float* __restrict__ in, const int* __restrict__ idx,
                                   float* __restrict__ out, int Ni, int C, int Sin) {
    size_t t = (size_t)blockIdx.x * 256 + threadIdx.x;
    size_t total = (size_t)Bc * Ni * C;
    if (t >= total) return;
    int c = (int)(t % C); size_t bi = t / C; int i = (int)(bi % Ni); int b = (int)(bi / Ni);
    int r = idx[(size_t)b * Ni + i];
    out[t] = in[((size_t)b * Sin + r) * C + c];
}

__global__ void scatter_mask_kernel(const int* __restrict__ nidx, unsigned char* __restrict__ mask,
                                    int Q, int S, int nb) {
    int t = blockIdx.x * 256 + threadIdx.x;
    if (t >= nb * Q * Kc) return;
    int q = (t / Kc) % Q; int b = t / (Kc * Q);
    mask[((size_t)b * Q + q) * S + nidx[t]] = 1;
}

// -------------------- positional encoding (dst = base + pe), native trig --------------------
__global__ void pe_kernel(float* __restrict__ dst, const float* __restrict__ base,
                          const float* __restrict__ xyz, size_t total) {
    size_t t = (size_t)blockIdx.x * 256 + threadIdx.x;
    if (t >= total) return;
    int d = (int)(t % Dd); size_t bs = t / Dd;
    int c = d >> 7;
    int i = d & 127;
    int j = i >> 1;
    float inv = __expf(-0.1439115683121279f * (float)j);  // 10000^(-j/64)
    float val = xyz[bs * 3 + c] * inv;
    float pe = (i & 1) ? __cosf(val) : __sinf(val);
    dst[t] = (base ? base[t] : 0.f) + pe;
}

// -------------------- LayerNorm (no affine), row=384, bf16 out --------------------
__global__ __launch_bounds__(256) void ln_kernel(const float* __restrict__ X, __bf16* __restrict__ Y, int R) {
    int lane = threadIdx.x & 63;
    int row = blockIdx.x * 4 + (threadIdx.x >> 6);
    if (row >= R) return;
    const float* x = X + (size_t)row * Dd;
    float v[6]; float s = 0.f;
#pragma unroll
    for (int j = 0; j < 6; j++) { v[j] = x[lane + 64*j]; s += v[j]; }
#pragma unroll
    for (int o = 32; o > 0; o >>= 1) s += __shfl_xor(s, o, 64);
    float m = s * (1.f / Dd);
    float s2 = 0.f;
#pragma unroll
    for (int j = 0; j < 6; j++) { float d = v[j] - m; s2 += d * d; }
#pragma unroll
    for (int o = 32; o > 0; o >>= 1) s2 += __shfl_xor(s2, o, 64);
    float inv = rsqrtf(s2 * (1.f / Dd) + 1e-5f);
    __bf16* y = Y + (size_t)row * Dd;
#pragma unroll
    for (int j = 0; j < 6; j++) y[lane + 64*j] = f2b((v[j] - m) * inv);
}

// -------------------- MFMA bf16 GEMM, 128x128 tile, global_load_lds + XOR swizzle --------------------
// Linear LDS [128][64] bf16 per operand. Staging: wave w, instr i: lane l writes LDS bytes
// (32w+8i+(l>>3))*128 + 16*(l&7); global source col pre-swizzled: k0 + 8*((l&7)^(l>>3)).
// So LDS[row][slot s] = A[row][k0 + 8*(s ^ (row&7))]. Fragment reads XOR byte-col with (m&7)<<4.
__global__ __launch_bounds__(256) void gemm_kernel(const __bf16* __restrict__ A, const __bf16* __restrict__ Wt,
                                                   const float* __restrict__ bias,
                                                   const float* __restrict__ res, void* __restrict__ Cv,
                                                   int M, int Ncols, int Kk, int relu, int obf) {
    __shared__ alignas(16) __bf16 As[128*64];
    __shared__ alignas(16) __bf16 Bs[128*64];
    const int tid = threadIdx.x;
    const int row0 = blockIdx.y * 128, col0 = blockIdx.x * 128;
    const int w = tid >> 6, lane = tid & 63, m = lane & 15, q = lane >> 4;
    const int wr = w >> 1, wc = w & 1;
    const int l8 = lane >> 3, l7 = lane & 7;
    const __bf16* apg = A  + (size_t)(row0 + 32*w + l8) * Kk + 8*(l7 ^ l8);
    const __bf16* wpg = Wt + (size_t)(col0 + 32*w + l8) * Kk + 8*(l7 ^ l8);
    const int swz = (m & 7) << 4;   // byte XOR for fragment reads
    const char* asb = (const char*)As;
    const char* bsb = (const char*)Bs;

    f4v acc[4][4];
#pragma unroll
    for (int r = 0; r < 4; r++)
#pragma unroll
        for (int n = 0; n < 4; n++) acc[r][n] = (f4v){0.f, 0.f, 0.f, 0.f};

    for (int k0 = 0; k0 < Kk; k0 += 64) {
#pragma unroll
        for (int i = 0; i < 4; i++) {
            gld16(apg + k0 + (size_t)(8*i) * Kk, As + w*2048 + i*512);
            gld16(wpg + k0 + (size_t)(8*i) * Kk, Bs + w*2048 + i*512);
        }
        __syncthreads();
#pragma unroll
        for (int kk = 0; kk < 2; kk++) {
            bf8v bfr[4], afr[4];
#pragma unroll
            for (int n = 0; n < 4; n++)
                bfr[n] = *(const bf8v*)(bsb + (wc*64 + n*16 + m)*128 + ((kk*64 + q*16) ^ swz));
#pragma unroll
            for (int r = 0; r < 4; r++)
                afr[r] = *(const bf8v*)(asb + (wr*64 + r*16 + m)*128 + ((kk*64 + q*16) ^ swz));
#pragma unroll
            for (int r = 0; r < 4; r++)
#pragma unroll
                for (int n = 0; n < 4; n++)
                    acc[r][n] = __builtin_amdgcn_mfma_f32_16x16x32_bf16(afr[r], bfr[n], acc[r][n], 0, 0, 0);
        }
        __syncthreads();
    }
#pragma unroll
    for (int n = 0; n < 4; n++) {
        const int gn = col0 + wc*64 + n*16 + m;
        float bv = bias ? bias[gn] : 0.f;
#pragma unroll
        for (int r = 0; r < 4; r++) {
#pragma unroll
            for (int j = 0; j < 4; j++) {
                int gm = row0 + wr*64 + r*16 + q*4 + j;
                float v = acc[r][n][j] + bv;
                if (relu) v = fmaxf(v, 0.f);
                if (res) v += res[(size_t)gm * Ncols + gn];
                if (obf) ((__bf16*)Cv)[(size_t)gm * Ncols + gn] = f2b(v);
                else     ((float*)Cv)[(size_t)gm * Ncols + gn] = v;
            }
        }
    }
}

// -------------------- MFMA attention: Sk=128, DH=48, optional mask + kv-batch xor --------------------
// grid (rpb/128, NHh, nb). Block 256 thr = 4 waves; wave w owns q-rows w*32..w*32+31 of a 128-row tile.
// mask (if non-null): [nb][rpb][128] bytes, indexed by QUERY batch z.
__global__ __launch_bounds__(256) void attn_mfma_kernel(const __bf16* __restrict__ Qb,
                                                        const __bf16* __restrict__ Kp,
                                                        const __bf16* __restrict__ Vp,
                                                        __bf16* __restrict__ O,
                                                        int ldq, int ldkv, int ldo, int rpb, int b0,
                                                        int bxor, const unsigned char* __restrict__ Mk) {
    __shared__ alignas(16) char smem[128*136*2 + 48*136*2];
    __bf16 (*Ks)[72]  = (__bf16(*)[72])smem;
    __bf16 (*Pl)[136] = (__bf16(*)[136])smem;            // aliases Ks after QK
    __bf16 (*Vt)[136] = (__bf16(*)[136])(smem + 128*136*2);
    const int tid = threadIdx.x;
    const int h = blockIdx.y, z = blockIdx.z;
    const int bk = (b0 + z) ^ bxor;
    const size_t row0 = (size_t)z * rpb + (size_t)blockIdx.x * 128;
    {
        int r = tid >> 1, c0 = (tid & 1) * 24;
        const __bf16* kp = Kp + ((size_t)bk * 128 + r) * ldkv + h * 48 + c0;
        *reinterpret_cast<bf8v*>(&Ks[r][c0])      = *reinterpret_cast<const bf8v*>(kp);
        *reinterpret_cast<bf8v*>(&Ks[r][c0 + 8])  = *reinterpret_cast<const bf8v*>(kp + 8);
        *reinterpret_cast<bf8v*>(&Ks[r][c0 + 16]) = *reinterpret_cast<const bf8v*>(kp + 16);
        if (tid & 1) {
            *reinterpret_cast<bf8v*>(&Ks[r][48]) = (bf8v){};
            *reinterpret_cast<bf8v*>(&Ks[r][56]) = (bf8v){};
        }
        const __bf16* vp = Vp + ((size_t)bk * 128 + r) * ldkv + h * 48 + c0;
        bf8v w0 = *reinterpret_cast<const bf8v*>(vp);
        bf8v w1 = *reinterpret_cast<const bf8v*>(vp + 8);
        bf8v w2 = *reinterpret_cast<const bf8v*>(vp + 16);
#pragma unroll
        for (int i = 0; i < 8; i++) {
            Vt[c0 + i][r] = w0[i]; Vt[c0 + 8 + i][r] = w1[i]; Vt[c0 + 16 + i][r] = w2[i];
        }
    }
    __syncthreads();
    const int w = tid >> 6, lane = tid & 63, m = lane & 15, q = lane >> 4;
    const __bf16* qbase = Qb + (row0 + (size_t)(w*32 + m)) * ldq + h * 48;
    f4v sc[2][8];
#pragma unroll
    for (int rt = 0; rt < 2; rt++)
#pragma unroll
        for (int nt = 0; nt < 8; nt++) sc[rt][nt] = (f4v){0.f, 0.f, 0.f, 0.f};
#pragma unroll
    for (int kk = 0; kk < 2; kk++) {
        bf8v a0 = *reinterpret_cast<const bf8v*>(qbase + kk*32 + q*8);
        bf8v a1 = *reinterpret_cast<const bf8v*>(qbase + (size_t)16*ldq + kk*32 + q*8);
#pragma unroll
        for (int nt = 0; nt < 8; nt++) {
            bf8v bf = *reinterpret_cast<bf8v*>(&Ks[nt*16 + m][kk*32 + q*8]);
            sc[0][nt] = __builtin_amdgcn_mfma_f32_16x16x32_bf16(a0, bf, sc[0][nt], 0, 0, 0);
            sc[1][nt] = __builtin_amdgcn_mfma_f32_16x16x32_bf16(a1, bf, sc[1][nt], 0, 0, 0);
        }
    }
    const float scale = 0.14433756729740643f;  // 1/sqrt(48)
    float inv_[2][4];
#pragma unroll
    for (int rt = 0; rt < 2; rt++) {
#pragma unroll
        for (int j = 0; j < 4; j++) {
            const unsigned char* mr = Mk ?
                (Mk + ((size_t)z * rpb + (size_t)blockIdx.x*128 + (w*32 + rt*16 + q*4 + j)) * 128 + m) : nullptr;
            float mv = -INFINITY;
#pragma unroll
            for (int nt = 0; nt < 8; nt++) {
                float vs = sc[rt][nt][j] * scale;
                if (mr && !mr[nt*16]) vs = -1e9f;
                sc[rt][nt][j] = vs;
                mv = fmaxf(mv, vs);
            }
#pragma unroll
            for (int o = 8; o > 0; o >>= 1) mv = fmaxf(mv, __shfl_xor(mv, o, 64));
            float sum = 0.f;
#pragma unroll
            for (int nt = 0; nt < 8; nt++) {
                float e = __expf(sc[rt][nt][j] - mv);
                sc[rt][nt][j] = e; sum += e;
            }
#pragma unroll
            for (int o = 8; o > 0; o >>= 1) sum += __shfl_xor(sum, o, 64);
            inv_[rt][j] = 1.f / sum;
        }
    }
    __syncthreads();
#pragma unroll
    for (int rt = 0; rt < 2; rt++)
#pragma unroll
        for (int nt = 0; nt < 8; nt++)
#pragma unroll
            for (int j = 0; j < 4; j++)
                Pl[w*32 + rt*16 + q*4 + j][nt*16 + m] = f2b(sc[rt][nt][j]);
    __syncthreads();
    f4v ov[2][3];
#pragma unroll
    for (int rt = 0; rt < 2; rt++)
#pragma unroll
        for (int nt = 0; nt < 3; nt++) ov[rt][nt] = (f4v){0.f, 0.f, 0.f, 0.f};
#pragma unroll
    for (int kk = 0; kk < 4; kk++) {
        bf8v p0 = *reinterpret_cast<bf8v*>(&Pl[w*32 + m][kk*32 + q*8]);
        bf8v p1 = *reinterpret_cast<bf8v*>(&Pl[w*32 + 16 + m][kk*32 + q*8]);
#pragma unroll
        for (int nt = 0; nt < 3; nt++) {
            bf8v bv = *reinterpret_cast<bf8v*>(&Vt[nt*16 + m][kk*32 + q*8]);
            ov[0][nt] = __builtin_amdgcn_mfma_f32_16x16x32_bf16(p0, bv, ov[0][nt], 0, 0, 0);
            ov[1][nt] = __builtin_amdgcn_mfma_f32_16x16x32_bf16(p1, bv, ov[1][nt], 0, 0, 0);
        }
    }
    __bf16* op = O + (row0 + (size_t)(w*32)) * ldo + h * 48;
#pragma unroll
    for (int rt = 0; rt < 2; rt++)
#pragma unroll
        for (int nt = 0; nt < 3; nt++)
#pragma unroll
            for (int j = 0; j < 4; j++)
                op[(size_t)(rt*16 + q*4 + j) * ldo + nt*16 + m] = f2b(ov[rt][nt][j] * inv_[rt][j]);
}

// -------------------- scalar attention (S=64 vis path), xor batch pairing --------------------
__global__ __launch_bounds__(64) void attn_kernel(const float* __restrict__ Q, const float* __restrict__ Kb,
                                                  const float* __restrict__ Vb,
                                                  const unsigned char* __restrict__ mask,
                                                  __bf16* __restrict__ O, int Sq, int Sk, int xorv,
                                                  int ldq, int ldkv) {
    int qi = blockIdx.x, h = blockIdx.y, bq = blockIdx.z;
    int bk = bq ^ xorv;
    int lane = threadIdx.x;
    __shared__ float qv[DHh];
    __shared__ float pv[128];
    const size_t qrow = (size_t)bq * Sq + qi;
    if (lane < DHh) qv[lane] = Q[qrow * ldq + h * DHh + lane];
    __syncthreads();
    const float scale = 0.14433756729740643f;  // 1/sqrt(48)
    float lv[2] = {-INFINITY, -INFINITY};
#pragma unroll
    for (int c = 0; c < 2; c++) {
        int s = lane + 64 * c;
        if (s < Sk) {
            const float* kr = Kb + ((size_t)bk * Sk + s) * ldkv + h * DHh;
            float d = 0.f;
#pragma unroll
            for (int t = 0; t < DHh; t++) d += qv[t] * kr[t];
            d *= scale;
            if (mask && !mask[qrow * Sk + s]) d = -1e9f;
            lv[c] = d;
        }
    }
    float mx = fmaxf(lv[0], lv[1]);
    for (int o = 32; o > 0; o >>= 1) mx = fmaxf(mx, __shfl_xor(mx, o, 64));
    float sum = 0.f;
#pragma unroll
    for (int c = 0; c < 2; c++) {
        int s = lane + 64 * c;
        if (s < Sk) { float e = expf(lv[c] - mx); pv[s] = e; sum += e; }
    }
    for (int o = 32; o > 0; o >>= 1) sum += __shfl_xor(sum, o, 64);
    float inv = 1.f / sum;
    __syncthreads();
    if (lane < DHh) {
        float acc = 0.f;
        const float* vb = Vb + ((size_t)bk * Sk) * ldkv + h * DHh + lane;
        for (int s = 0; s < Sk; s++) acc += pv[s] * vb[(size_t)s * ldkv];
        O[qrow * Dd + h * DHh + lane] = f2b(acc * inv);
    }
}

// -------------------- decoder q init --------------------
__global__ void dec_init_kernel(const float* __restrict__ mtok, const float* __restrict__ vout,
                                const float* __restrict__ cpe, const int* __restrict__ mski,
                                const int* __restrict__ visi, float* __restrict__ x) {
    size_t t = (size_t)blockIdx.x * 256 + threadIdx.x;
    size_t total = (size_t)Bc * Gc * Dd;
    if (t >= total) return;
    int d = (int)(t % Dd); size_t bi = t / Dd; int i = (int)(bi % Gc); int b = (int)(bi / Gc);
    float base; int ci;
    if (i < Mc) { base = mtok[d]; ci = mski[b * Mc + i]; }
    else        { base = vout[((size_t)b * Vc + (i - Mc)) * Dd + d]; ci = visi[b * Vc + (i - Mc)]; }
    x[t] = base + cpe[((size_t)b * Gc + ci) * Dd + d];
}

// -------------------- smooth-L1 partial reduce --------------------
__global__ __launch_bounds__(256) void sl1_kernel(const float* __restrict__ tgt, const float* __restrict__ dec,
                                                  float* __restrict__ acc, int slot) {
    __shared__ float sh[256];
    size_t t = (size_t)blockIdx.x * 256 + threadIdx.x;
    const size_t total = (size_t)Bc * Mc * Dd;
    float v = 0.f;
    if (t < total) {
        int d = (int)(t % Dd); size_t rem = t / Dd; int i = (int)(rem % Mc); int b = (int)(rem / Mc);
        float p = dec[((size_t)b * Gc + i) * Dd + d];
        float a = fabsf(p - tgt[t]);
        v = (a < 2.f) ? 0.25f * a * a : (a - 1.f);
    }
    sh[threadIdx.x] = v;
    __syncthreads();
    for (int s = 128; s > 0; s >>= 1) {
        if (threadIdx.x < s) sh[threadIdx.x] += sh[threadIdx.x + s];
        __syncthreads();
    }
    if (threadIdx.x == 0) atomicAdd(&acc[slot], sh[0]);
}

__global__ void mae_finalize_kernel(const float* __restrict__ acc, float* __restrict__ out) {
    const float inv = 1.f / (float)(Bc * Mc * Dd);
    *out = 0.5f * (acc[0] * inv) + 0.5f * (acc[1] * inv);
}

// ==================== host orchestration ====================
extern "C" void kernel_launch(void* const* d_in, const int* in_sizes, int n_in,
                              void* d_out, int out_size, void* d_ws, size_t ws_size,
                              hipStream_t stream) {
    (void)in_sizes; (void)n_in; (void)out_size;
    const void* pos_src = d_in[0];
    const void* pos_tgt = d_in[1];
    const int* vis_s = (const int*)d_in[2];
    const int* msk_s = (const int*)d_in[3];
    const int* vis_t = (const int*)d_in[4];
    const int* msk_t = (const int*)d_in[5];
    const void *tw1 = d_in[6], *tb1 = d_in[7], *tw2 = d_in[8], *tb2 = d_in[9];
    const void *tw3 = d_in[10], *tb3 = d_in[11], *tw4 = d_in[12], *tb4 = d_in[13];
    const void *mtok = d_in[14];
    const void *cxw = d_in[15], *cff1 = d_in[16], *cff2 = d_in[17];
    const void *esa = d_in[18], *eca = d_in[19], *eff1 = d_in[20], *eff2 = d_in[21];
    const void *dca = d_in[22], *dff1 = d_in[23], *dff2 = d_in[24];
    const void *uw1 = d_in[25], *ub1 = d_in[26], *uw2 = d_in[27], *ub2 = d_in[28];
    float* out = (float*)d_out;
    char* ws = (char*)d_ws;

    const size_t DD = (size_t)Dd * Dd;
    const size_t DF = (size_t)Dd * FFf;
    const size_t GD = (size_t)Gc * Dd;        // 49152
    const size_t PH = (size_t)Bc * Nn * 3;    // posf half (elements)

    // ---- bf16 transposed weight arena (element offsets) ----
    size_t wo = 0;
    auto walloc = [&](size_t e) -> size_t { size_t r = wo; wo += e; return r; };
    const size_t wt_t1 = walloc((size_t)128 * 64);
    const size_t wt_t2 = walloc((size_t)256 * 128);
    const size_t wt_t3 = walloc((size_t)512 * 512);
    const size_t wt_t4 = walloc((size_t)384 * 512);
    const size_t wt_cx = walloc((size_t)8 * DD);
    const size_t wt_cf1 = walloc(DF);
    const size_t wt_cf2 = walloc(DF);
    const size_t wt_es = walloc((size_t)16 * DD);
    const size_t wt_ec = walloc((size_t)16 * DD);
    const size_t wt_ef1 = walloc((size_t)4 * DF);
    const size_t wt_ef2 = walloc((size_t)4 * DF);
    const size_t wt_dc = walloc((size_t)8 * DD);
    const size_t wt_df1 = walloc((size_t)2 * DF);
    const size_t wt_df2 = walloc((size_t)2 * DF);
    const size_t wt_u1 = walloc((size_t)384 * 448);
    const size_t wt_u2 = walloc((size_t)384 * 384);

    // ---- persistent workspace (batches 0..7 = src, 8..15 = tgt) ----
    size_t o = 0;
    auto alloc = [&](size_t bytes) -> size_t { size_t r = o; o += (bytes + 255) & ~(size_t)255; return r; };
    const size_t flagO = alloc(256);
    const size_t wtO = alloc(wo * 2);
    const size_t bsO = alloc(2048 * 4);
    const size_t mtokO = alloc(Dd * 4);
    const size_t posfO = alloc(2 * PH * 4);
    const size_t centO = alloc((size_t)16 * Gc * 3 * 4);
    const size_t cpeO  = alloc((size_t)16 * GD * 4);
    const size_t tokO  = alloc((size_t)16 * GD * 4);
    const size_t vtokO = alloc((size_t)16 * Vc * Dd * 4);
    const size_t lnSO = alloc((size_t)16 * GD * 2);
    const size_t lnTO = alloc((size_t)16 * GD * 2);
    const size_t lnmO = alloc((size_t)16 * GD * 2);
    const size_t qbO  = alloc((size_t)16 * GD * 2);
    const size_t qkvbO = alloc((size_t)16 * Gc * 1152 * 4);
    const size_t kvbO  = alloc((size_t)16 * Gc * 768 * 2);
    const size_t kvd0O = alloc((size_t)16 * Gc * 768 * 2);
    const size_t kvd1O = alloc((size_t)16 * Gc * 768 * 2);
    const size_t cxO   = alloc((size_t)16 * GD * 2);
    const size_t decxO = alloc((size_t)16 * GD * 4);
    const size_t membO = alloc((size_t)16 * GD * 4);
    const size_t relbO = alloc((size_t)16 * Gc * Kc * 64 * 2);
    const size_t tbsO = alloc((size_t)Bc * Mc * Dd * 4), tbtO = alloc((size_t)Bc * Mc * Dd * 4);
    const size_t mfullO = alloc((size_t)16 * Gc * Gc);
    const size_t mvisO  = alloc((size_t)16 * Vc * Vc);
    const size_t nidxO = alloc((size_t)16 * Gc * Kc * 4);
    const size_t idx3O = alloc((size_t)16 * Nn * 3 * 4), w3O = alloc((size_t)16 * Nn * 3 * 4);
    const size_t vis3O = alloc((size_t)16 * Vc * 3 * 4);
    const size_t accbO = alloc(64);

    // ---- scratch arena ----
    const size_t arenaO = o;
    const size_t arena_bytes = (ws_size > arenaO) ? (ws_size - arenaO) : 0;
    int RP = 128;
    {
        const int cands[10] = {65536, 32768, 16384, 8192, 4096, 2048, 1024, 512, 256, 128};
        for (int ci = 0; ci < 10; ci++) {
            if ((size_t)cands[ci] * 9344 + 8192 <= arena_bytes) { RP = cands[ci]; break; }
        }
    }
    size_t ao = arenaO;
    auto aalloc = [&](size_t bytes) -> size_t { size_t r = ao; ao += (bytes + 255) & ~(size_t)255; return r; };
    const size_t AcbO = aalloc((size_t)RP*448*2);
    const size_t XcO  = aalloc((size_t)RP*384*4);
    const size_t LcO  = aalloc((size_t)RP*384*2);
    const size_t T1O  = aalloc((size_t)RP*384*4);
    const size_t QTO  = aalloc((size_t)RP*384*2);
    const size_t T2O  = aalloc((size_t)RP*384*2);
    const size_t HhO  = aalloc((size_t)RP*1536*2);
    int TC = (int)(arena_bytes / 70200);
    TC &= ~7; if (TC > 2048) TC = 2048; if (TC < 8) TC = 8;
    size_t to = arenaO;
    auto talloc = [&](size_t bytes) -> size_t { size_t r = to; to += (bytes + 255) & ~(size_t)255; return r; };
    const size_t tk1O = talloc((size_t)TC*16*128*2);
    const size_t tk2O = talloc((size_t)TC*16*256*2);
    const size_t tgmO = talloc((size_t)TC*256*2);
    const size_t tcatO = talloc((size_t)TC*16*512*2);
    const size_t thbO = talloc((size_t)TC*16*512*2);
    const size_t t4oO = talloc((size_t)TC*16*384*4);

    auto F = [&](size_t off) -> float* { return (float*)(ws + off); };
    auto I = [&](size_t off) -> int* { return (int*)(ws + off); };
    auto U = [&](size_t off) -> unsigned char* { return (unsigned char*)(ws + off); };
    auto Bf = [&](size_t off) -> __bf16* { return (__bf16*)(ws + off); };
    auto ew = [](size_t n) -> dim3 { return dim3((unsigned)((n + 255) / 256)); };
    const int* flag = I(flagO);
    __bf16* WT = Bf(wtO);
    float* BF = F(bsO);
    const int b_t1 = 0, b_t2 = 128, b_t3 = 384, b_t4 = 896, b_u1 = 1280, b_u2 = 1664;

    auto gemm = [&](const __bf16* A, const __bf16* W, const float* bias, const float* res, void* C,
                    int M, int Ncol, int Kk, int relu, int obf) {
        dim3 g((unsigned)(Ncol / 128), (unsigned)(M / 128));
        gemm_kernel<<<g, 256, 0, stream>>>(A, W, bias, res, C, M, Ncol, Kk, relu, obf);
    };
    auto ln = [&](const float* X, __bf16* Y, int R) {
        ln_kernel<<<dim3((R + 3) / 4), 256, 0, stream>>>(X, Y, R);
    };
    auto attn_old = [&](const float* Qp, const float* Kp, const float* Vp, const unsigned char* mask,
                        __bf16* Op, int Sq, int Sk, int nb, int xorv, int ldq, int ldkv) {
        attn_kernel<<<dim3(Sq, NHh, nb), 64, 0, stream>>>(Qp, Kp, Vp, mask, Op, Sq, Sk, xorv, ldq, ldkv);
    };
    auto attn_mfma = [&](const __bf16* Qp, const __bf16* Kp, const __bf16* Vp, __bf16* Op,
                         int ldq, int ldkv, int ldo, int rpb, int nb, int b0,
                         int bxor, const unsigned char* mask) {
        attn_mfma_kernel<<<dim3(rpb/128, NHh, nb), 256, 0, stream>>>(Qp, Kp, Vp, Op, ldq, ldkv, ldo, rpb, b0, bxor, mask);
    };
    __bf16* ctxb = Bf(cxO);

    auto ffn = [&](float* x, const __bf16* w1t, const __bf16* w2t, int R) {
        ln(x, Bf(lnSO), R);
        for (int r0 = 0; r0 < R; r0 += RP) {
            int rc = (R - r0 < RP) ? (R - r0) : RP;
            gemm(Bf(lnSO) + (size_t)r0*Dd, w1t, nullptr, nullptr, Bf(HhO), rc, FFf, Dd, 1, 1);
            gemm(Bf(HhO), w2t, nullptr, x + (size_t)r0*Dd, x + (size_t)r0*Dd, rc, Dd, FFf, 0, 0);
        }
    };
    // cross-encoder over 16 batches; ca pairs batch bq with bq^8
    auto cross_enc = [&](float* x, const unsigned char* mask, int S) {
        const int R = 16 * S;
        if (S == 128) {
            ln(x, Bf(lnSO), R);
            gemm(Bf(lnSO), WT + wt_cx, nullptr, nullptr, Bf(qkvbO), R, 1152, Dd, 0, 1);
            attn_mfma(Bf(qkvbO), Bf(qkvbO) + 384, Bf(qkvbO) + 768, ctxb, 1152, 1152, Dd, 128, 16, 0, 0, mask);
            gemm(ctxb, WT + wt_cx + 3*DD, nullptr, x, x, R, Dd, Dd, 0, 0);
            ln(x, Bf(lnSO), R);
            gemm(Bf(lnSO), WT + wt_cx + 4*DD, nullptr, nullptr, Bf(qkvbO), R, 1152, Dd, 0, 1);
            attn_mfma(Bf(qkvbO), Bf(qkvbO) + 384, Bf(qkvbO) + 768, ctxb, 1152, 1152, Dd, 128, 16, 0, 8, nullptr);
            gemm(ctxb, WT + wt_cx + 7*DD, nullptr, x, x, R, Dd, Dd, 0, 0);
        } else {
            ln(x, Bf(lnSO), R);
            gemm(Bf(lnSO), WT + wt_cx, nullptr, nullptr, F(qkvbO), R, 1152, Dd, 0, 0);
            attn_old(F(qkvbO), F(qkvbO) + 384, F(qkvbO) + 768, mask, ctxb, S, S, 16, 0, 1152, 1152);
            gemm(ctxb, WT + wt_cx + 3*DD, nullptr, x, x, R, Dd, Dd, 0, 0);
            ln(x, Bf(lnSO), R);
            gemm(Bf(lnSO), WT + wt_cx + 4*DD, nullptr, nullptr, F(qkvbO), R, 1152, Dd, 0, 0);
            attn_old(F(qkvbO), F(qkvbO) + 384, F(qkvbO) + 768, nullptr, ctxb, S, S, 16, 8, 1152, 1152);
            gemm(ctxb, WT + wt_cx + 7*DD, nullptr, x, x, R, Dd, Dd, 0, 0);
        }
        ffn(x, WT + wt_cf1, WT + wt_cf2, R);
    };
    // batched 4-layer decoder: x [16][Gc][Dd]; mem LN in lnm (bf16, 2048 rows)
    auto decoder4 = [&](float* x) {
        for (int l = 0; l < 4; l++) {
            ln(x, Bf(lnTO), 2048);
            gemm(Bf(lnTO), WT + wt_es + (size_t)l*4*DD, nullptr, nullptr, Bf(qkvbO), 2048, 1152, Dd, 0, 1);
            attn_mfma(Bf(qkvbO), Bf(qkvbO) + 384, Bf(qkvbO) + 768, ctxb, 1152, 1152, Dd, 128, 16, 0, 0, nullptr);
            gemm(ctxb, WT + wt_es + (size_t)l*4*DD + 3*DD, nullptr, x, x, 2048, Dd, Dd, 0, 0);
            ln(x, Bf(lnTO), 2048);
            gemm(Bf(lnTO), WT + wt_ec + (size_t)l*4*DD, nullptr, nullptr, Bf(qbO), 2048, Dd, Dd, 0, 1);
            gemm(Bf(lnmO), WT + wt_ec + (size_t)l*4*DD + DD, nullptr, nullptr, Bf(kvbO), 2048, 768, Dd, 0, 1);
            attn_mfma(Bf(qbO), Bf(kvbO), Bf(kvbO) + 384, ctxb, Dd, 768, Dd, 128, 16, 0, 0, nullptr);
            gemm(ctxb, WT + wt_ec + (size_t)l*4*DD + 3*DD, nullptr, x, x, 2048, Dd, Dd, 0, 0);
            ffn(x, WT + wt_ef1 + (size_t)l*DF, WT + wt_ef2 + (size_t)l*DF, 2048);
        }
    };

    // ---- pipeline ----
    detect_kernel<<<dim3(1), 256, 0, stream>>>((const unsigned int*)pos_src, I(flagO));
    cvtf_kernel<<<ew(PH), 256, 0, stream>>>(pos_src, F(posfO), PH, flag);
    cvtf_kernel<<<ew(PH), 256, 0, stream>>>(pos_tgt, F(posfO) + PH, PH, flag);
    cvtf_kernel<<<dim3(2), 256, 0, stream>>>(mtok, F(mtokO), (size_t)Dd, flag);

    auto wtr = [&](const void* src, size_t dstOff, int K, int N, int Kpad, int cnt) {
        wtr_kernel<<<ew((size_t)cnt * N * Kpad), 256, 0, stream>>>(src, WT + dstOff, K, N, Kpad, cnt, flag);
    };
    wtr(tw1, wt_t1, 3, 128, 64, 1);
    wtr(tw2, wt_t2, 128, 256, 128, 1);
    wtr(tw3, wt_t3, 512, 512, 512, 1);
    wtr(tw4, wt_t4, 512, 384, 512, 1);
    wtr(cxw, wt_cx, 384, 384, 384, 8);
    wtr(cff1, wt_cf1, 384, 1536, 384, 1);
    wtr(cff2, wt_cf2, 1536, 384, 1536, 1);
    wtr(esa, wt_es, 384, 384, 384, 16);
    wtr(eca, wt_ec, 384, 384, 384, 16);
    wtr(eff1, wt_ef1, 384, 1536, 384, 4);
    wtr(eff2, wt_ef2, 1536, 384, 1536, 4);
    wtr(dca, wt_dc, 384, 384, 384, 8);
    wtr(dff1, wt_df1, 384, 1536, 384, 2);
    wtr(dff2, wt_df2, 1536, 384, 1536, 2);
    wtr(uw1, wt_u1, 387, 384, 448, 1);
    wtr(uw2, wt_u2, 384, 384, 384, 1);
    cvtf_kernel<<<ew(128), 256, 0, stream>>>(tb1, BF + b_t1, 128, flag);
    cvtf_kernel<<<ew(256), 256, 0, stream>>>(tb2, BF + b_t2, 256, flag);
    cvtf_kernel<<<ew(512), 256, 0, stream>>>(tb3, BF + b_t3, 512, flag);
    cvtf_kernel<<<ew(384), 256, 0, stream>>>(tb4, BF + b_t4, 384, flag);
    cvtf_kernel<<<ew(384), 256, 0, stream>>>(ub1, BF + b_u1, 384, flag);
    cvtf_kernel<<<ew(384), 256, 0, stream>>>(ub2, BF + b_u2, 384, flag);

    fps_kernel<<<dim3(16), 512, 0, stream>>>(F(posfO), F(posfO) + PH, F(centO), F(centO) + (size_t)Bc*Gc*3);

    // tokenize both sides (16 batches)
    knn16_kernel<<<dim3(16*Gc), 64, 0, stream>>>(F(centO), F(posfO), I(nidxO), Gc, Nn);
    rel_kernel<<<ew((size_t)16*Gc*Kc*64), 256, 0, stream>>>(F(posfO), F(centO), I(nidxO), Bf(relbO), 16);
    for (int g0 = 0; g0 < 16*Gc; g0 += TC) {
        const int gc = (16*Gc - g0 < TC) ? (16*Gc - g0) : TC;
        const int RC = gc * Kc;
        gemm(Bf(relbO) + (size_t)g0*Kc*64, WT + wt_t1, BF + b_t1, nullptr, Bf(tk1O), RC, 128, 64, 1, 1);
        gemm(Bf(tk1O), WT + wt_t2, BF + b_t2, nullptr, Bf(tk2O), RC, 256, 128, 0, 1);
        maxk_bf_kernel<<<ew((size_t)gc*256), 256, 0, stream>>>(Bf(tk2O), Bf(tgmO), gc, 256);
        concat_gf_kernel<<<ew((size_t)RC*512), 256, 0, stream>>>(Bf(tgmO), Bf(tk2O), Bf(tcatO), gc);
        gemm(Bf(tcatO), WT + wt_t3, BF + b_t3, nullptr, Bf(thbO), RC, 512, 512, 1, 1);
        gemm(Bf(thbO), WT + wt_t4, BF + b_t4, nullptr, F(t4oO), RC, Dd, 512, 0, 0);
        maxk_f32_kernel<<<ew((size_t)gc*Dd), 256, 0, stream>>>(F(t4oO), F(tokO) + (size_t)g0*Dd, gc, Dd);
    }

    pe_kernel<<<ew((size_t)16*GD), 256, 0, stream>>>(F(cpeO), nullptr, F(centO), (size_t)16*GD);

    gather_rows_kernel<<<ew((size_t)Bc*Vc*Dd), 256, 0, stream>>>(F(tokO), vis_s, F(vtokO), Vc, Dd, Gc);
    gather_rows_kernel<<<ew((size_t)Bc*Vc*Dd), 256, 0, stream>>>(F(tokO) + 8*GD, vis_t, F(vtokO) + (size_t)8*Vc*Dd, Vc, Dd, Gc);
    gather_rows_kernel<<<ew((size_t)Bc*Vc*3), 256, 0, stream>>>(F(centO), vis_s, F(vis3O), Vc, 3, Gc);
    gather_rows_kernel<<<ew((size_t)Bc*Vc*3), 256, 0, stream>>>(F(centO) + (size_t)Bc*Gc*3, vis_t, F(vis3O) + (size_t)8*Vc*3, Vc, 3, Gc);

    zero_kernel<<<ew((size_t)16*Gc*Gc), 256, 0, stream>>>(U(mfullO), (size_t)16*Gc*Gc);
    knn16_kernel<<<dim3(16*Gc), 64, 0, stream>>>(F(centO), F(centO), I(nidxO), Gc, Gc);
    scatter_mask_kernel<<<ew((size_t)16*Gc*Kc), 256, 0, stream>>>(I(nidxO), U(mfullO), Gc, Gc, 16);
    zero_kernel<<<ew((size_t)16*Vc*Vc), 256, 0, stream>>>(U(mvisO), (size_t)16*Vc*Vc);
    knn16_kernel<<<dim3(16*Vc), 64, 0, stream>>>(F(vis3O), F(vis3O), I(nidxO), Vc, Vc);
    scatter_mask_kernel<<<ew((size_t)16*Vc*Kc), 256, 0, stream>>>(I(nidxO), U(mvisO), Vc, Vc, 16);

    cross_enc(F(vtokO), U(mvisO), Vc);
    cross_enc(F(tokO), U(mfullO), Gc);

    dec_init_kernel<<<ew((size_t)Bc*GD), 256, 0, stream>>>(F(mtokO), F(vtokO), F(cpeO), msk_s, vis_s, F(decxO));
    dec_init_kernel<<<ew((size_t)Bc*GD), 256, 0, stream>>>(F(mtokO), F(vtokO) + (size_t)8*Vc*Dd, F(cpeO) + 8*GD, msk_t, vis_t, F(decxO) + 8*GD);
    add_kernel<<<ew((size_t)8*GD), 256, 0, stream>>>(F(tokO) + 8*GD, F(cpeO) + 8*GD, F(membO), (size_t)8*GD);
    add_kernel<<<ew((size_t)8*GD), 256, 0, stream>>>(F(tokO), F(cpeO), F(membO) + 8*GD, (size_t)8*GD);
    ln(F(membO), Bf(lnmO), 2048);
    decoder4(F(decxO));

    zero_kernel<<<dim3(1), 256, 0, stream>>>(U(accbO), 64);
    gather_rows_kernel<<<ew((size_t)Bc*Mc*Dd), 256, 0, stream>>>(F(tokO), msk_s, F(tbsO), Mc, Dd, Gc);
    gather_rows_kernel<<<ew((size_t)Bc*Mc*Dd), 256, 0, stream>>>(F(tokO) + 8*GD, msk_t, F(tbtO), Mc, Dd, Gc);
    sl1_kernel<<<ew((size_t)Bc*Mc*Dd), 256, 0, stream>>>(F(tbsO), F(decxO), F(accbO), 0);
    sl1_kernel<<<ew((size_t)Bc*Mc*Dd), 256, 0, stream>>>(F(tbtO), F(decxO) + 8*GD, F(accbO), 1);

    // ---- dense path, both sides fused ----
    knn3_kernel<<<dim3(16*Nn), 64, 0, stream>>>(F(posfO), F(centO), I(idx3O), F(w3O));
    add_kernel<<<ew((size_t)16*GD), 256, 0, stream>>>(F(tokO), F(cpeO), F(membO), (size_t)16*GD);
    ln(F(membO), Bf(lnmO), 2048);
    gemm(Bf(lnmO), WT + wt_dc + 0*4*DD + DD, nullptr, nullptr, Bf(kvd0O), 2048, 768, Dd, 0, 1);
    gemm(Bf(lnmO), WT + wt_dc + 1*4*DD + DD, nullptr, nullptr, Bf(kvd1O), 2048, 768, Dd, 0, 1);
    const size_t kvdo[2] = {kvd0O, kvd1O};
    const int RT = 16 * Nn;
    for (int r0 = 0; r0 < RT; r0 += RP) {
        const int rpb = (RP < Nn) ? RP : Nn;
        const int nb = (RP < Nn) ? 1 : RP / Nn;
        const int b0 = r0 / Nn;
        interp_kernel<<<ew((size_t)RP*448), 256, 0, stream>>>(F(tokO), F(posfO), I(idx3O), F(w3O), Bf(AcbO), r0, RP);
        gemm(Bf(AcbO), WT + wt_u1, BF + b_u1, nullptr, Bf(LcO), RP, Dd, 448, 1, 1);
        gemm(Bf(LcO), WT + wt_u2, BF + b_u2, nullptr, F(T1O), RP, Dd, Dd, 1, 0);
        pe_kernel<<<ew((size_t)RP*Dd), 256, 0, stream>>>(F(XcO), F(T1O), F(posfO) + (size_t)r0*3, (size_t)RP*Dd);
        for (int l = 0; l < 2; l++) {
            ln(F(XcO), Bf(LcO), RP);
            gemm(Bf(LcO), WT + wt_dc + (size_t)l*4*DD, nullptr, nullptr, Bf(QTO), RP, Dd, Dd, 0, 1);
            attn_mfma(Bf(QTO), Bf(kvdo[l]), Bf(kvdo[l]) + 384, Bf(T2O), Dd, 768, Dd, rpb, nb, b0, 0, nullptr);
            gemm(Bf(T2O), WT + wt_dc + (size_t)l*4*DD + 3*DD, nullptr, F(XcO), F(XcO), RP, Dd, Dd, 0, 0);
            ln(F(XcO), Bf(LcO), RP);
            gemm(Bf(LcO), WT + wt_df1 + (size_t)l*DF, nullptr, nullptr, Bf(HhO), RP, FFf, Dd, 1, 1);
            if (l == 1)
                gemm(Bf(HhO), WT + wt_df2 + DF, nullptr, F(XcO), out + (size_t)r0*Dd, RP, Dd, FFf, 0, 0);
            else
                gemm(Bf(HhO), WT + wt_df2, nullptr, F(XcO), F(XcO), RP, Dd, FFf, 0, 0);
        }
    }

    mae_finalize_kernel<<<dim3(1), 1, 0, stream>>>(F(accbO), out + (size_t)2*Bc*Nn*Dd);
}